// Round 2
// baseline (3090.645 us; speedup 1.0000x reference)
//
#include <hip/hip_runtime.h>
#include <hip/hip_bf16.h>

typedef __hip_bfloat16 bf16;

static constexpr int Nn = 25000;   // nodes
static constexpr int Ne = 400000;  // edges
static constexpr int Bg = 64;      // graphs

// flag-aware element load: b16 ? bf16[i] : f32[i]
__device__ __forceinline__ float ldf(const void* p, size_t i, bool b16) {
  return b16 ? __bfloat162float(((const bf16*)p)[i]) : ((const float*)p)[i];
}

// ---------------- dtype detection ----------------
// bf16 data: every uint16 half is a real bf16 (|x|<~30 -> exp field <= ~131).
// fp32 data: low halves are random mantissa bits -> ~45% have exp field >= 140.
__global__ void detect_kernel(const unsigned short* a, int n,
                              const unsigned short* b, int m, int* flags) {
  __shared__ int c0, c1;
  if (threadIdx.x == 0) { c0 = 0; c1 = 0; }
  __syncthreads();
  int t = threadIdx.x;
  int l0 = 0, l1 = 0;
  for (int i = t; i < n; i += 256) {
    unsigned e = (a[i] >> 7) & 0xFF;
    if (e >= 140) l0++;
  }
  for (int i = t; i < m; i += 256) {
    unsigned e = (b[i] >> 7) & 0xFF;
    if (e >= 140) l1++;
  }
  atomicAdd(&c0, l0);
  atomicAdd(&c1, l1);
  __syncthreads();
  if (t == 0) {
    flags[0] = (c0 < n / 16) ? 1 : 0;  // 1 = features are bf16
    flags[1] = (c1 < m / 16) ? 1 : 0;  // 1 = params are bf16
  }
}

// ---------------- generic tiled GEMM: C = act(A[M,K] @ W[K,N] + bias) ----------------
// ACT: 0 none, 1 relu
template <int ACT>
__global__ __launch_bounds__(256) void gemm_kernel(const void* __restrict__ A,
                                                   const int* __restrict__ aflag,
                                                   const void* __restrict__ W, size_t woff,
                                                   const void* __restrict__ bias, size_t boff,
                                                   const int* __restrict__ pflag,
                                                   float* __restrict__ C,
                                                   int M, int K, int N) {
  const bool ab = aflag ? (*aflag != 0) : false;
  const bool pb = (*pflag != 0);
  __shared__ float As[16][65];
  __shared__ float Bs[16][68];
  const int bm = blockIdx.x * 64;
  const int bn = blockIdx.y * 64;
  const int tid = threadIdx.x;
  const int tx = tid & 15, ty = tid >> 4;
  const int arow = tid >> 2, acol = (tid & 3) * 4;
  const int brow = tid >> 4, bcol = (tid & 15) * 4;
  float acc[4][4] = {};
  for (int k0 = 0; k0 < K; k0 += 16) {
    int gr = bm + arow;
#pragma unroll
    for (int q = 0; q < 4; q++) {
      int gk = k0 + acol + q;
      float v = 0.f;
      if (gr < M && gk < K) v = ldf(A, (size_t)gr * K + gk, ab);
      As[acol + q][arow] = v;
    }
    int gk = k0 + brow;
#pragma unroll
    for (int q = 0; q < 4; q++) {
      int gn = bn + bcol + q;
      float v = 0.f;
      if (gk < K && gn < N) v = ldf(W, woff + (size_t)gk * N + gn, pb);
      Bs[brow][bcol + q] = v;
    }
    __syncthreads();
#pragma unroll
    for (int k = 0; k < 16; k++) {
      float a[4], b[4];
#pragma unroll
      for (int i = 0; i < 4; i++) a[i] = As[k][ty * 4 + i];
#pragma unroll
      for (int j = 0; j < 4; j++) b[j] = Bs[k][tx * 4 + j];
#pragma unroll
      for (int i = 0; i < 4; i++)
#pragma unroll
        for (int j = 0; j < 4; j++) acc[i][j] += a[i] * b[j];
    }
    __syncthreads();
  }
#pragma unroll
  for (int i = 0; i < 4; i++) {
    int row = bm + ty * 4 + i;
    if (row >= M) continue;
#pragma unroll
    for (int j = 0; j < 4; j++) {
      int col = bn + tx * 4 + j;
      if (col >= N) continue;
      float v = acc[i][j];
      if (bias) v += ldf(bias, boff + col, pb);
      if (ACT == 1) v = v > 0.f ? v : 0.f;
      C[(size_t)row * N + col] = v;
    }
  }
}

// ---------------- CSR build ----------------
__global__ void count_kernel(const int* __restrict__ dst, int* __restrict__ cnt, int E) {
  int e = blockIdx.x * blockDim.x + threadIdx.x;
  if (e < E) atomicAdd(&cnt[dst[e]], 1);
}

__global__ void scan_kernel(const int* __restrict__ cnt, int* __restrict__ off, int n) {
  __shared__ int buf[256];
  __shared__ int running;
  int t = threadIdx.x;
  if (t == 0) running = 0;
  __syncthreads();
  for (int base = 0; base < n; base += 256) {
    int i = base + t;
    int v = (i < n) ? cnt[i] : 0;
    buf[t] = v;
    __syncthreads();
    for (int d = 1; d < 256; d <<= 1) {
      int add = (t >= d) ? buf[t - d] : 0;
      __syncthreads();
      buf[t] += add;
      __syncthreads();
    }
    int excl = running + buf[t] - v;
    __syncthreads();
    if (t == 0) running += buf[255];
    __syncthreads();
    if (i < n) off[i] = excl;
  }
  if (t == 0) off[n] = running;
}

__global__ void copy_int_kernel(const int* __restrict__ a, int* __restrict__ b, int n) {
  int i = blockIdx.x * blockDim.x + threadIdx.x;
  if (i < n) b[i] = a[i];
}

__global__ void fill_kernel(const int* __restrict__ dst, int* __restrict__ cursor,
                            int* __restrict__ perm, int E) {
  int e = blockIdx.x * blockDim.x + threadIdx.x;
  if (e < E) {
    int p = atomicAdd(&cursor[dst[e]], 1);
    perm[p] = e;
  }
}

// ---------------- EdgeGraphConv gather-sum ----------------
__global__ __launch_bounds__(128) void edgeconv_kernel(const int* __restrict__ off,
                                                       const int* __restrict__ perm,
                                                       const int* __restrict__ src,
                                                       const float* __restrict__ hn,
                                                       const float* __restrict__ he,
                                                       float* __restrict__ xsum, int N) {
  int n = blockIdx.x;
  int f = threadIdx.x;
  if (n >= N || f >= 80) return;
  float acc = 0.f;
  int e0 = off[n], e1 = off[n + 1];
  for (int eg = e0; eg < e1; eg++) {
    int e = perm[eg];
    if (f < 64) {
      int sv = src[e];
      acc += hn[(size_t)sv * 64 + f];
    } else {
      acc += he[(size_t)e * 16 + (f - 64)];
    }
  }
  xsum[(size_t)n * 80 + f] = acc;
}

// ---------------- attention el/er ----------------
__global__ __launch_bounds__(256) void attn_lr_kernel(const float* __restrict__ z,
                                                      const void* __restrict__ al,
                                                      const void* __restrict__ ar, size_t off,
                                                      const int* __restrict__ pflag,
                                                      float* __restrict__ el,
                                                      float* __restrict__ er, int N) {
  const bool pb = (*pflag != 0);
  int n = (blockIdx.x * blockDim.x + threadIdx.x) >> 6;
  int lane = threadIdx.x & 63;
  if (n >= N) return;
  const float* zr = z + (size_t)n * 512 + lane * 8;
  float sl = 0.f, sr = 0.f;
#pragma unroll
  for (int q = 0; q < 8; q++) {
    int idx = lane * 8 + q;
    float zv = zr[q];
    sl += zv * ldf(al, off + idx, pb);
    sr += zv * ldf(ar, off + idx, pb);
  }
#pragma unroll
  for (int o = 1; o < 16; o <<= 1) {
    sl += __shfl_xor(sl, o);
    sr += __shfl_xor(sr, o);
  }
  if ((lane & 15) == 0) {
    int h = lane >> 4;
    el[n * 4 + h] = sl;
    er[n * 4 + h] = sr;
  }
}

// ---------------- edge softmax pass ----------------
__global__ void edge_softmax_kernel(const int* __restrict__ src, const int* __restrict__ dst,
                                    const float* __restrict__ el, const float* __restrict__ er,
                                    float* __restrict__ exe, float* __restrict__ sden, int E) {
  int e = blockIdx.x * blockDim.x + threadIdx.x;
  if (e >= E) return;
  int sv = src[e], dv = dst[e];
#pragma unroll
  for (int h = 0; h < 4; h++) {
    float v = el[sv * 4 + h] + er[dv * 4 + h];
    v = v > 0.f ? v : 0.2f * v;
    v = fminf(v, 60.f);
    float ev = expf(v);
    exe[e * 4 + h] = ev;
    atomicAdd(&sden[dv * 4 + h], ev);
  }
}

// ---------------- GAT gather ----------------
__global__ __launch_bounds__(256) void gat_gather_kernel(const int* __restrict__ off,
                                                         const int* __restrict__ perm,
                                                         const int* __restrict__ src,
                                                         const float* __restrict__ z,
                                                         const float* __restrict__ exe,
                                                         const float* __restrict__ sden,
                                                         const void* __restrict__ gb, size_t goff,
                                                         const int* __restrict__ pflag,
                                                         float* __restrict__ out, int N) {
  const bool pb = (*pflag != 0);
  int n = (blockIdx.x * blockDim.x + threadIdx.x) >> 6;
  int lane = threadIdx.x & 63;
  if (n >= N) return;
  int h = lane >> 4;
  float sd = sden[n * 4 + h];
  float sinv = sd > 0.f ? 1.f / sd : 0.f;
  float acc[8] = {0.f, 0.f, 0.f, 0.f, 0.f, 0.f, 0.f, 0.f};
  int e0 = off[n], e1 = off[n + 1];
  for (int eg = e0; eg < e1; eg++) {
    int e = perm[eg];
    int sv = src[e];
    float a = exe[e * 4 + h] * sinv;
    const float4* zr = reinterpret_cast<const float4*>(z + (size_t)sv * 512 + lane * 8);
    float4 u = zr[0], v = zr[1];
    acc[0] += a * u.x; acc[1] += a * u.y; acc[2] += a * u.z; acc[3] += a * u.w;
    acc[4] += a * v.x; acc[5] += a * v.y; acc[6] += a * v.z; acc[7] += a * v.w;
  }
  float* o = out + (size_t)n * 512 + lane * 8;
#pragma unroll
  for (int q = 0; q < 8; q++) {
    float v = acc[q] + ldf(gb, goff + lane * 8 + q, pb);
    o[q] = v > 0.f ? v : 0.01f * v;
  }
}

// ---------------- node weight ----------------
__global__ __launch_bounds__(256) void wnode_kernel(const float* __restrict__ x,
                                                    const void* __restrict__ wsw, size_t woff,
                                                    const void* __restrict__ wsb, size_t boff,
                                                    const int* __restrict__ pflag,
                                                    float* __restrict__ w, int N) {
  const bool pb = (*pflag != 0);
  int n = (blockIdx.x * blockDim.x + threadIdx.x) >> 6;
  int lane = threadIdx.x & 63;
  if (n >= N) return;
  float s = x[(size_t)n * 128 + lane] * ldf(wsw, woff + lane, pb) +
            x[(size_t)n * 128 + 64 + lane] * ldf(wsw, woff + 64 + lane, pb);
#pragma unroll
  for (int o = 1; o < 64; o <<= 1) s += __shfl_xor(s, o);
  if (lane == 0) {
    float t = s + ldf(wsb, boff, pb);
    t = fmaxf(fminf(t, 60.f), -60.f);
    w[n] = 1.f / (1.f + expf(-t));
  }
}

__device__ __forceinline__ int lower_bound_dev(const int* a, int n, int v) {
  int lo = 0, hi = n;
  while (lo < hi) {
    int mid = (lo + hi) >> 1;
    if (a[mid] < v) lo = mid + 1; else hi = mid;
  }
  return lo;
}

// ---------------- readout ----------------
__global__ __launch_bounds__(128) void readout_kernel(const float* __restrict__ x,
                                                      const float* __restrict__ w,
                                                      const int* __restrict__ gid, int N,
                                                      float* __restrict__ hs,
                                                      float* __restrict__ hm) {
  int g = blockIdx.x;
  int d = threadIdx.x;
  __shared__ int ss, se;
  if (d == 0) {
    ss = lower_bound_dev(gid, N, g);
    se = lower_bound_dev(gid, N, g + 1);
  }
  __syncthreads();
  double s = 0.0;
  float m = -1e30f;
  for (int n = ss; n < se; n++) {
    float v = x[(size_t)n * 128 + d];
    s += (double)v * (double)w[n];
    m = fmaxf(m, v);
  }
  hs[g * 128 + d] = (float)s;
  hm[g * 128 + d] = m;
}

// ---------------- pool linear ----------------
__global__ __launch_bounds__(128) void pool_kernel(const float* __restrict__ hs,
                                                   const float* __restrict__ hm,
                                                   const void* __restrict__ Wp, size_t woff,
                                                   const void* __restrict__ bp, size_t boff,
                                                   const int* __restrict__ pflag,
                                                   float* __restrict__ bout) {
  const bool pb = (*pflag != 0);
  int g = blockIdx.x, j = threadIdx.x;
  __shared__ float hg[256];
  hg[j] = hs[g * 128 + j];
  hg[128 + j] = hm[g * 128 + j];
  __syncthreads();
  double acc = (double)ldf(bp, boff + j, pb);
  for (int k = 0; k < 256; k++) acc += (double)hg[k] * (double)ldf(Wp, woff + (size_t)k * 128 + j, pb);
  bout[g * 128 + j] = (float)acc;
}

// ---------------- final head ----------------
__global__ __launch_bounds__(128) void head_kernel(const float* __restrict__ bA,
                                                   const float* __restrict__ bB,
                                                   const void* __restrict__ Wo1,
                                                   const void* __restrict__ bo1,
                                                   const void* __restrict__ Wo2,
                                                   const void* __restrict__ bo2,
                                                   const int* __restrict__ pflag,
                                                   const int* __restrict__ oflag,
                                                   void* __restrict__ out) {
  const bool pb = (*pflag != 0);
  int g = blockIdx.x, j = threadIdx.x;
  __shared__ float zr[256];
  __shared__ double t[128];
  zr[j] = bA[g * 128 + j];
  zr[128 + j] = bB[g * 128 + j];
  __syncthreads();
  double acc = (double)ldf(bo1, j, pb);
  for (int k = 0; k < 256; k++) acc += (double)zr[k] * (double)ldf(Wo1, (size_t)k * 128 + j, pb);
  if (acc < 0.0) acc *= 0.01;
  t[j] = acc * (double)ldf(Wo2, j, pb);
  __syncthreads();
  for (int sdt = 64; sdt > 0; sdt >>= 1) {
    if (j < sdt) t[j] += t[j + sdt];
    __syncthreads();
  }
  if (j == 0) {
    float v = (float)(t[0] + (double)ldf(bo2, 0, pb));
    if (*oflag) ((bf16*)out)[g] = __float2bfloat16(v);
    else ((float*)out)[g] = v;
  }
}

extern "C" void kernel_launch(void* const* d_in, const int* in_sizes, int n_in,
                              void* d_out, int out_size, void* d_ws, size_t ws_size,
                              hipStream_t stream) {
  const int* srcA = (const int*)d_in[0];
  const int* dstA = (const int*)d_in[1];
  const int* gidA = (const int*)d_in[2];
  const void* nfA = d_in[3];
  const void* efA = d_in[4];
  const int* srcB = (const int*)d_in[5];
  const int* dstB = (const int*)d_in[6];
  const int* gidB = (const int*)d_in[7];
  const void* nfB = d_in[8];
  const void* efB = d_in[9];
  const void* p_Wn = d_in[10];
  const void* p_bn = d_in[11];
  const void* p_We = d_in[12];
  const void* p_be = d_in[13];
  const void* p_Wc = d_in[14];
  const void* p_bc = d_in[15];
  const void* p_fc1 = d_in[16];
  const void* p_al1 = d_in[17];
  const void* p_ar1 = d_in[18];
  const void* p_gb1 = d_in[19];
  const void* p_Wl1 = d_in[20];
  const void* p_bl1 = d_in[21];
  const void* p_fc2 = d_in[22];
  const void* p_al2 = d_in[23];
  const void* p_ar2 = d_in[24];
  const void* p_gb2 = d_in[25];
  const void* p_Wl2 = d_in[26];
  const void* p_bl2 = d_in[27];
  const void* p_ws_w = d_in[28];
  const void* p_ws_b = d_in[29];
  const void* p_Wp = d_in[30];
  const void* p_bp = d_in[31];
  const void* Wo1 = d_in[32];
  const void* bo1 = d_in[33];
  const void* Wo2 = d_in[34];
  const void* bo2 = d_in[35];

  // workspace carve-up (~125 MB total)
  char* wp = (char*)d_ws;
  auto alloc = [&](size_t bytes) -> char* {
    char* p = wp;
    wp += (bytes + 255) & ~(size_t)255;
    return p;
  };
  int* flags = (int*)alloc(2 * 4);
  int* cnt = (int*)alloc((size_t)Nn * 4);
  int* offs = (int*)alloc((size_t)(Nn + 1) * 4);
  int* cursor = (int*)alloc((size_t)Nn * 4);
  int* perm = (int*)alloc((size_t)Ne * 4);
  float* sden = (float*)alloc((size_t)Nn * 4 * 4);
  float* exe = (float*)alloc((size_t)Ne * 4 * 4);
  float* el = (float*)alloc((size_t)Nn * 4 * 4);
  float* er = (float*)alloc((size_t)Nn * 4 * 4);
  float* wn = (float*)alloc((size_t)Nn * 4);
  float* hsb = (float*)alloc((size_t)Bg * 128 * 4);
  float* hmb = (float*)alloc((size_t)Bg * 128 * 4);
  float* bout = (float*)alloc((size_t)2 * Bg * 128 * 4);
  float* zb = (float*)alloc((size_t)Nn * 512 * 4);    // z; overlays hn/he/xsum early, x2 late
  float* hb = (float*)alloc((size_t)Nn * 512 * 4);    // GAT output
  float* xcx1 = (float*)alloc((size_t)Nn * 128 * 4);  // xc early, x1 later
  // overlays
  float* hn = zb;                                          // Nn*64
  float* he = zb + (size_t)Nn * 64;                        // Ne*16
  float* xsum = zb + (size_t)Nn * 64 + (size_t)Ne * 16;    // Nn*80 (ends at 10.0M < 12.8M)
  float* xc = xcx1;
  float* x1 = xcx1;
  float* x2 = zb;

  auto cdiv = [](int a, int b) { return (a + b - 1) / b; };

  detect_kernel<<<1, 256, 0, stream>>>((const unsigned short*)nfA, 8192,
                                       (const unsigned short*)p_fc1, 8192, flags);
  int* fflag = &flags[0];
  int* pflag = &flags[1];

  auto run_branch = [&](int i, const int* src, const int* dst, const int* gid,
                        const void* nf, const void* ef, float* bout_i) {
    // CSR by dst
    hipMemsetAsync(cnt, 0, (size_t)Nn * 4, stream);
    count_kernel<<<cdiv(Ne, 256), 256, 0, stream>>>(dst, cnt, Ne);
    scan_kernel<<<1, 256, 0, stream>>>(cnt, offs, Nn);
    copy_int_kernel<<<cdiv(Nn, 256), 256, 0, stream>>>(offs, cursor, Nn);
    fill_kernel<<<cdiv(Ne, 256), 256, 0, stream>>>(dst, cursor, perm, Ne);
    // input projections
    gemm_kernel<0><<<dim3(cdiv(Nn, 64), 1), 256, 0, stream>>>(
        nf, fflag, p_Wn, (size_t)i * 64 * 64, p_bn, (size_t)i * 64, pflag, hn, Nn, 64, 64);
    gemm_kernel<0><<<dim3(cdiv(Ne, 64), 1), 256, 0, stream>>>(
        ef, fflag, p_We, (size_t)i * 16 * 16, p_be, (size_t)i * 16, pflag, he, Ne, 16, 16);
    // EdgeGraphConv
    edgeconv_kernel<<<Nn, 128, 0, stream>>>(offs, perm, src, hn, he, xsum, Nn);
    gemm_kernel<1><<<dim3(cdiv(Nn, 64), 2), 256, 0, stream>>>(
        xsum, nullptr, p_Wc, (size_t)i * 80 * 80, p_bc, (size_t)i * 80, pflag, xc, Nn, 80, 80);
    // GAT 1
    gemm_kernel<0><<<dim3(cdiv(Nn, 64), 8), 256, 0, stream>>>(
        xc, nullptr, p_fc1, (size_t)i * 80 * 512, nullptr, 0, pflag, zb, Nn, 80, 512);
    attn_lr_kernel<<<cdiv(Nn * 64, 256), 256, 0, stream>>>(
        zb, p_al1, p_ar1, (size_t)i * 512, pflag, el, er, Nn);
    hipMemsetAsync(sden, 0, (size_t)Nn * 16, stream);
    edge_softmax_kernel<<<cdiv(Ne, 256), 256, 0, stream>>>(src, dst, el, er, exe, sden, Ne);
    gat_gather_kernel<<<cdiv(Nn * 64, 256), 256, 0, stream>>>(
        offs, perm, src, zb, exe, sden, p_gb1, (size_t)i * 512, pflag, hb, Nn);
    gemm_kernel<0><<<dim3(cdiv(Nn, 64), 2), 256, 0, stream>>>(
        hb, nullptr, p_Wl1, (size_t)i * 512 * 128, p_bl1, (size_t)i * 128, pflag, x1, Nn, 512, 128);
    // GAT 2
    gemm_kernel<0><<<dim3(cdiv(Nn, 64), 8), 256, 0, stream>>>(
        x1, nullptr, p_fc2, (size_t)i * 128 * 512, nullptr, 0, pflag, zb, Nn, 128, 512);
    attn_lr_kernel<<<cdiv(Nn * 64, 256), 256, 0, stream>>>(
        zb, p_al2, p_ar2, (size_t)i * 512, pflag, el, er, Nn);
    hipMemsetAsync(sden, 0, (size_t)Nn * 16, stream);
    edge_softmax_kernel<<<cdiv(Ne, 256), 256, 0, stream>>>(src, dst, el, er, exe, sden, Ne);
    gat_gather_kernel<<<cdiv(Nn * 64, 256), 256, 0, stream>>>(
        offs, perm, src, zb, exe, sden, p_gb2, (size_t)i * 512, pflag, hb, Nn);
    gemm_kernel<0><<<dim3(cdiv(Nn, 64), 2), 256, 0, stream>>>(
        hb, nullptr, p_Wl2, (size_t)i * 512 * 128, p_bl2, (size_t)i * 128, pflag, x2, Nn, 512, 128);
    // readout
    wnode_kernel<<<cdiv(Nn * 64, 256), 256, 0, stream>>>(
        x2, p_ws_w, (size_t)i * 128, p_ws_b, (size_t)i, pflag, wn, Nn);
    readout_kernel<<<Bg, 128, 0, stream>>>(x2, wn, gid, Nn, hsb, hmb);
    pool_kernel<<<Bg, 128, 0, stream>>>(
        hsb, hmb, p_Wp, (size_t)i * 256 * 128, p_bp, (size_t)i * 128, pflag, bout_i);
  };

  run_branch(0, srcA, dstA, gidA, nfA, efA, bout);
  run_branch(1, srcB, dstB, gidB, nfB, efB, bout + (size_t)Bg * 128);

  head_kernel<<<Bg, 128, 0, stream>>>(bout, bout + (size_t)Bg * 128, Wo1, bo1, Wo2, bo2,
                                      pflag, fflag, d_out);
}

// Round 5
// 2401.038 us; speedup vs baseline: 1.2872x; 1.2872x over previous
//
#include <hip/hip_runtime.h>
#include <hip/hip_bf16.h>

typedef __hip_bfloat16 bf16;
typedef unsigned short u16;
typedef __attribute__((ext_vector_type(8))) short short8;
typedef __attribute__((ext_vector_type(4))) float floatx4;

static constexpr int Nn = 25000;   // nodes
static constexpr int Ne = 400000;  // edges
static constexpr int Bg = 64;      // graphs

// flag-aware element load: b16 ? bf16[i] : f32[i]
__device__ __forceinline__ float ldf(const void* p, size_t i, bool b16) {
  return b16 ? __bfloat162float(((const bf16*)p)[i]) : ((const float*)p)[i];
}

// ---------------- dtype detection ----------------
__global__ void detect_kernel(const u16* a, int n, const u16* b, int m, int* flags) {
  __shared__ int c0, c1;
  if (threadIdx.x == 0) { c0 = 0; c1 = 0; }
  __syncthreads();
  int t = threadIdx.x;
  int l0 = 0, l1 = 0;
  for (int i = t; i < n; i += 256) {
    unsigned e = (a[i] >> 7) & 0xFF;
    if (e >= 140) l0++;
  }
  for (int i = t; i < m; i += 256) {
    unsigned e = (b[i] >> 7) & 0xFF;
    if (e >= 140) l1++;
  }
  atomicAdd(&c0, l0);
  atomicAdd(&c1, l1);
  __syncthreads();
  if (t == 0) {
    flags[0] = (c0 < n / 16) ? 1 : 0;  // 1 = features are bf16
    flags[1] = (c1 < m / 16) ? 1 : 0;  // 1 = params are bf16
  }
}

// ------- transpose+convert weight: W[K][N] (flag dtype) -> hi/lo bf16 planes [N][K] -----
__global__ void transconv_kernel(const void* __restrict__ W, size_t off,
                                 const int* __restrict__ pflag,
                                 bf16* __restrict__ Wh, bf16* __restrict__ Wl,
                                 int K, int N) {
  const bool pb = (*pflag != 0);
  int idx = blockIdx.x * 256 + threadIdx.x;
  if (idx >= K * N) return;
  int k = idx / N, n = idx - k * N;
  float w = ldf(W, off + idx, pb);
  bf16 h = __float2bfloat16(w);
  float hf = __bfloat162float(h);
  Wh[(size_t)n * K + k] = h;
  Wl[(size_t)n * K + k] = __float2bfloat16(w - hf);
}

// ---------------- split-precision MFMA GEMM: C = act(A[M,K]f32 @ B^T + bias) -----------
// A and B both decomposed into bf16 hi+lo planes; 3 MFMAs per fragment:
// ah*bh + ah*bl + al*bh (al*bl ~2^-18 dropped). 128x128 tile, 4 waves of 64x64.
template <int ACT>
__global__ __launch_bounds__(256) void mfma_split_gemm(const float* __restrict__ A,
                                                       const u16* __restrict__ Bh,
                                                       const u16* __restrict__ Bl,
                                                       const void* __restrict__ bias, size_t boff,
                                                       const int* __restrict__ pflag,
                                                       float* __restrict__ C,
                                                       int M, int K, int N) {
  __shared__ short Ahs[128 * 40];
  __shared__ short Als[128 * 40];
  __shared__ short Bhs[128 * 40];
  __shared__ short Bls[128 * 40];
  const int bm = blockIdx.x * 128;
  const int bn = blockIdx.y * 128;
  const int tid = threadIdx.x;
  const int lane = tid & 63;
  const int wave = tid >> 6;
  const int wm = wave >> 1, wn = wave & 1;
  const int lm = lane & 15, quad = lane >> 4;
  const int srow = tid >> 1;   // 0..127
  const int sseg = tid & 1;    // 16-elem half of the 32-k chunk
  floatx4 acc[4][4] = {};
  for (int k0 = 0; k0 < K; k0 += 32) {
    bool kv = (k0 + sseg * 16) < K;
    // ---- stage A tile [128 x 32] fp32 -> hi/lo bf16 planes ----
    {
      int gr = bm + srow;
      short hv[16], lv[16];
      if (gr < M && kv) {
        const float4* gp = (const float4*)(A + (size_t)gr * K + k0 + sseg * 16);
#pragma unroll
        for (int v = 0; v < 4; v++) {
          float4 f = gp[v];
          float xs[4] = {f.x, f.y, f.z, f.w};
#pragma unroll
          for (int q = 0; q < 4; q++) {
            bf16 h = __float2bfloat16(xs[q]);
            float hf = __bfloat162float(h);
            bf16 l = __float2bfloat16(xs[q] - hf);
            hv[v * 4 + q] = *(short*)&h;
            lv[v * 4 + q] = *(short*)&l;
          }
        }
      } else {
#pragma unroll
        for (int q = 0; q < 16; q++) { hv[q] = 0; lv[q] = 0; }
      }
      *(short8*)&Ahs[srow * 40 + sseg * 16] = *(short8*)&hv[0];
      *(short8*)&Ahs[srow * 40 + sseg * 16 + 8] = *(short8*)&hv[8];
      *(short8*)&Als[srow * 40 + sseg * 16] = *(short8*)&lv[0];
      *(short8*)&Als[srow * 40 + sseg * 16 + 8] = *(short8*)&lv[8];
    }
    // ---- stage B hi/lo tiles (rows of B* = output cols) ----
    {
      int gc = bn + srow;
      short8 h0 = {}, h1 = {}, l0 = {}, l1 = {};
      if (gc < N && kv) {
        const short8* hp = (const short8*)(Bh + (size_t)gc * K + k0 + sseg * 16);
        const short8* lp = (const short8*)(Bl + (size_t)gc * K + k0 + sseg * 16);
        h0 = hp[0]; h1 = hp[1];
        l0 = lp[0]; l1 = lp[1];
      }
      *(short8*)&Bhs[srow * 40 + sseg * 16] = h0;
      *(short8*)&Bhs[srow * 40 + sseg * 16 + 8] = h1;
      *(short8*)&Bls[srow * 40 + sseg * 16] = l0;
      *(short8*)&Bls[srow * 40 + sseg * 16 + 8] = l1;
    }
    __syncthreads();
    short8 ah[4], al[4], bh[4], bl[4];
#pragma unroll
    for (int f = 0; f < 4; f++) {
      ah[f] = *(const short8*)&Ahs[(wm * 64 + f * 16 + lm) * 40 + quad * 8];
      al[f] = *(const short8*)&Als[(wm * 64 + f * 16 + lm) * 40 + quad * 8];
      bh[f] = *(const short8*)&Bhs[(wn * 64 + f * 16 + lm) * 40 + quad * 8];
      bl[f] = *(const short8*)&Bls[(wn * 64 + f * 16 + lm) * 40 + quad * 8];
    }
#pragma unroll
    for (int i = 0; i < 4; i++)
#pragma unroll
      for (int j = 0; j < 4; j++) {
        acc[i][j] = __builtin_amdgcn_mfma_f32_16x16x32_bf16(al[i], bh[j], acc[i][j], 0, 0, 0);
        acc[i][j] = __builtin_amdgcn_mfma_f32_16x16x32_bf16(ah[i], bl[j], acc[i][j], 0, 0, 0);
        acc[i][j] = __builtin_amdgcn_mfma_f32_16x16x32_bf16(ah[i], bh[j], acc[i][j], 0, 0, 0);
      }
    __syncthreads();
  }
  // ---- epilogue: C/D layout col=lane&15, row=quad*4+reg ----
  const bool pb = (*pflag != 0);
#pragma unroll
  for (int i = 0; i < 4; i++) {
#pragma unroll
    for (int j = 0; j < 4; j++) {
      int col = bn + wn * 64 + j * 16 + lm;
      if (col >= N) continue;
#pragma unroll
      for (int r = 0; r < 4; r++) {
        int row = bm + wm * 64 + i * 16 + quad * 4 + r;
        if (row >= M) continue;
        float v = acc[i][j][r];
        if (bias) v += ldf(bias, boff + col, pb);
        if (ACT == 1) v = v > 0.f ? v : 0.f;
        C[(size_t)row * N + col] = v;
      }
    }
  }
}

// ---------------- generic tiled GEMM (input projections): C = A@W + bias, fp32 out -----
__global__ __launch_bounds__(256) void gemm_kernel(const void* __restrict__ A,
                                                   const int* __restrict__ aflag,
                                                   const void* __restrict__ W, size_t woff,
                                                   const void* __restrict__ bias, size_t boff,
                                                   const int* __restrict__ pflag,
                                                   float* __restrict__ C,
                                                   int M, int K, int N) {
  const bool ab = aflag ? (*aflag != 0) : false;
  const bool pb = (*pflag != 0);
  __shared__ float As[16][65];
  __shared__ float Bs[16][68];
  const int bm = blockIdx.x * 64;
  const int bn = blockIdx.y * 64;
  const int tid = threadIdx.x;
  const int tx = tid & 15, ty = tid >> 4;
  const int arow = tid >> 2, acol = (tid & 3) * 4;
  const int brow = tid >> 4, bcol = (tid & 15) * 4;
  float acc[4][4] = {};
  for (int k0 = 0; k0 < K; k0 += 16) {
    int gr = bm + arow;
#pragma unroll
    for (int q = 0; q < 4; q++) {
      int gk = k0 + acol + q;
      float v = 0.f;
      if (gr < M && gk < K) v = ldf(A, (size_t)gr * K + gk, ab);
      As[acol + q][arow] = v;
    }
    int gk = k0 + brow;
#pragma unroll
    for (int q = 0; q < 4; q++) {
      int gn = bn + bcol + q;
      float v = 0.f;
      if (gk < K && gn < N) v = ldf(W, woff + (size_t)gk * N + gn, pb);
      Bs[brow][bcol + q] = v;
    }
    __syncthreads();
#pragma unroll
    for (int k = 0; k < 16; k++) {
      float a[4], b[4];
#pragma unroll
      for (int i = 0; i < 4; i++) a[i] = As[k][ty * 4 + i];
#pragma unroll
      for (int j = 0; j < 4; j++) b[j] = Bs[k][tx * 4 + j];
#pragma unroll
      for (int i = 0; i < 4; i++)
#pragma unroll
        for (int j = 0; j < 4; j++) acc[i][j] += a[i] * b[j];
    }
    __syncthreads();
  }
#pragma unroll
  for (int i = 0; i < 4; i++) {
    int row = bm + ty * 4 + i;
    if (row >= M) continue;
#pragma unroll
    for (int j = 0; j < 4; j++) {
      int col = bn + tx * 4 + j;
      if (col >= N) continue;
      float v = acc[i][j];
      if (bias) v += ldf(bias, boff + col, pb);
      C[(size_t)row * N + col] = v;
    }
  }
}

// ---------------- CSR build ----------------
__global__ void count_kernel(const int* __restrict__ dst, int* __restrict__ cnt, int E) {
  int e = blockIdx.x * blockDim.x + threadIdx.x;
  if (e < E) atomicAdd(&cnt[dst[e]], 1);
}

__global__ void scan_kernel(const int* __restrict__ cnt, int* __restrict__ off, int n) {
  __shared__ int buf[256];
  __shared__ int running;
  int t = threadIdx.x;
  if (t == 0) running = 0;
  __syncthreads();
  for (int base = 0; base < n; base += 256) {
    int i = base + t;
    int v = (i < n) ? cnt[i] : 0;
    buf[t] = v;
    __syncthreads();
    for (int d = 1; d < 256; d <<= 1) {
      int add = (t >= d) ? buf[t - d] : 0;
      __syncthreads();
      buf[t] += add;
      __syncthreads();
    }
    int excl = running + buf[t] - v;
    __syncthreads();
    if (t == 0) running += buf[255];
    __syncthreads();
    if (i < n) off[i] = excl;
  }
  if (t == 0) off[n] = running;
}

__global__ void copy_int_kernel(const int* __restrict__ a, int* __restrict__ b, int n) {
  int i = blockIdx.x * blockDim.x + threadIdx.x;
  if (i < n) b[i] = a[i];
}

__global__ void fill_kernel(const int* __restrict__ dst, int* __restrict__ cursor,
                            int* __restrict__ perm, int E) {
  int e = blockIdx.x * blockDim.x + threadIdx.x;
  if (e < E) {
    int p = atomicAdd(&cursor[dst[e]], 1);
    perm[p] = e;
  }
}

// ---------------- sort each node's segment by edge id -> deterministic sums ------------
__global__ void sortseg_kernel(const int* __restrict__ off, int* __restrict__ perm, int N) {
  int n = blockIdx.x * blockDim.x + threadIdx.x;
  if (n >= N) return;
  int e0 = off[n], e1 = off[n + 1];
  int d = e1 - e0;
  if (d <= 1) return;
  if (d <= 96) {
    int loc[96];
    for (int i = 0; i < d; i++) loc[i] = perm[e0 + i];
    for (int i = 1; i < d; i++) {
      int v = loc[i];
      int j = i - 1;
      while (j >= 0 && loc[j] > v) { loc[j + 1] = loc[j]; j--; }
      loc[j + 1] = v;
    }
    for (int i = 0; i < d; i++) perm[e0 + i] = loc[i];
  } else {
    for (int i = 0; i < d - 1; i++) {
      int mi = i;
      for (int j = i + 1; j < d; j++)
        if (perm[e0 + j] < perm[e0 + mi]) mi = j;
      int t = perm[e0 + i];
      perm[e0 + i] = perm[e0 + mi];
      perm[e0 + mi] = t;
    }
  }
}

// ---------------- EdgeGraphConv gather-sum (fp32) ----------------
__global__ __launch_bounds__(128) void edgeconv_kernel(const int* __restrict__ off,
                                                       const int* __restrict__ perm,
                                                       const int* __restrict__ src,
                                                       const float* __restrict__ hn,
                                                       const float* __restrict__ he,
                                                       float* __restrict__ xsum, int N) {
  int n = blockIdx.x;
  int f = threadIdx.x;
  if (n >= N || f >= 80) return;
  float acc = 0.f;
  int e0 = off[n], e1 = off[n + 1];
  for (int eg = e0; eg < e1; eg++) {
    int e = perm[eg];
    if (f < 64) {
      int sv = src[e];
      acc += hn[(size_t)sv * 64 + f];
    } else {
      acc += he[(size_t)e * 16 + (f - 64)];
    }
  }
  xsum[(size_t)n * 80 + f] = acc;
}

// ---------------- attention el/er (fp32 z) ----------------
__global__ __launch_bounds__(256) void attn_lr_kernel(const float* __restrict__ z,
                                                      const void* __restrict__ al,
                                                      const void* __restrict__ ar, size_t off,
                                                      const int* __restrict__ pflag,
                                                      float* __restrict__ el,
                                                      float* __restrict__ er, int N) {
  const bool pb = (*pflag != 0);
  int n = (blockIdx.x * blockDim.x + threadIdx.x) >> 6;
  int lane = threadIdx.x & 63;
  if (n >= N) return;
  const float* zr = z + (size_t)n * 512 + lane * 8;
  float sl = 0.f, sr = 0.f;
#pragma unroll
  for (int q = 0; q < 8; q++) {
    int idx = lane * 8 + q;
    float zv = zr[q];
    sl += zv * ldf(al, off + idx, pb);
    sr += zv * ldf(ar, off + idx, pb);
  }
#pragma unroll
  for (int o = 1; o < 16; o <<= 1) {
    sl += __shfl_xor(sl, o);
    sr += __shfl_xor(sr, o);
  }
  if ((lane & 15) == 0) {
    int h = lane >> 4;
    el[n * 4 + h] = sl;
    er[n * 4 + h] = sr;
  }
}

// ---------------- edge softmax numerator (no atomics) ----------------
__global__ void edge_softmax_kernel(const int* __restrict__ src, const int* __restrict__ dst,
                                    const float* __restrict__ el, const float* __restrict__ er,
                                    float* __restrict__ exe, int E) {
  int e = blockIdx.x * blockDim.x + threadIdx.x;
  if (e >= E) return;
  int sv = src[e], dv = dst[e];
#pragma unroll
  for (int h = 0; h < 4; h++) {
    float v = el[sv * 4 + h] + er[dv * 4 + h];
    v = v > 0.f ? v : 0.2f * v;
    v = fminf(v, 60.f);
    exe[e * 4 + h] = expf(v);
  }
}

// ---------------- softmax denominator via CSR (deterministic) ----------------
__global__ void sden_kernel(const int* __restrict__ off, const int* __restrict__ perm,
                            const float* __restrict__ exe, float* __restrict__ sden, int N) {
  int idx = blockIdx.x * blockDim.x + threadIdx.x;
  int n = idx >> 2, h = idx & 3;
  if (n >= N) return;
  int e0 = off[n], e1 = off[n + 1];
  float s = 0.f;
  for (int eg = e0; eg < e1; eg++) s += exe[perm[eg] * 4 + h];
  sden[n * 4 + h] = s;
}

// ---------------- GAT gather (fp32 z in, fp32 out) ----------------
__global__ __launch_bounds__(256) void gat_gather_kernel(const int* __restrict__ off,
                                                         const int* __restrict__ perm,
                                                         const int* __restrict__ src,
                                                         const float* __restrict__ z,
                                                         const float* __restrict__ exe,
                                                         const float* __restrict__ sden,
                                                         const void* __restrict__ gb, size_t goff,
                                                         const int* __restrict__ pflag,
                                                         float* __restrict__ out, int N) {
  const bool pb = (*pflag != 0);
  int n = (blockIdx.x * blockDim.x + threadIdx.x) >> 6;
  int lane = threadIdx.x & 63;
  if (n >= N) return;
  int h = lane >> 4;
  float sd = sden[n * 4 + h];
  float sinv = sd > 0.f ? 1.f / sd : 0.f;
  float acc[8] = {0.f, 0.f, 0.f, 0.f, 0.f, 0.f, 0.f, 0.f};
  int e0 = off[n], e1 = off[n + 1];
  for (int eg = e0; eg < e1; eg++) {
    int e = perm[eg];
    int sv = src[e];
    float a = exe[e * 4 + h] * sinv;
    const float4* zr = reinterpret_cast<const float4*>(z + (size_t)sv * 512 + lane * 8);
    float4 u = zr[0], v = zr[1];
    acc[0] += a * u.x; acc[1] += a * u.y; acc[2] += a * u.z; acc[3] += a * u.w;
    acc[4] += a * v.x; acc[5] += a * v.y; acc[6] += a * v.z; acc[7] += a * v.w;
  }
  float* o = out + (size_t)n * 512 + lane * 8;
#pragma unroll
  for (int q = 0; q < 8; q++) {
    float v = acc[q] + ldf(gb, goff + lane * 8 + q, pb);
    o[q] = v > 0.f ? v : 0.01f * v;
  }
}

// ---------------- node weight ----------------
__global__ __launch_bounds__(256) void wnode_kernel(const float* __restrict__ x,
                                                    const void* __restrict__ wsw, size_t woff,
                                                    const void* __restrict__ wsb, size_t boff,
                                                    const int* __restrict__ pflag,
                                                    float* __restrict__ w, int N) {
  const bool pb = (*pflag != 0);
  int n = (blockIdx.x * blockDim.x + threadIdx.x) >> 6;
  int lane = threadIdx.x & 63;
  if (n >= N) return;
  float s = x[(size_t)n * 128 + lane] * ldf(wsw, woff + lane, pb) +
            x[(size_t)n * 128 + 64 + lane] * ldf(wsw, woff + 64 + lane, pb);
#pragma unroll
  for (int o = 1; o < 64; o <<= 1) s += __shfl_xor(s, o);
  if (lane == 0) {
    float t = s + ldf(wsb, boff, pb);
    t = fmaxf(fminf(t, 60.f), -60.f);
    w[n] = 1.f / (1.f + expf(-t));
  }
}

__device__ __forceinline__ int lower_bound_dev(const int* a, int n, int v) {
  int lo = 0, hi = n;
  while (lo < hi) {
    int mid = (lo + hi) >> 1;
    if (a[mid] < v) lo = mid + 1; else hi = mid;
  }
  return lo;
}

// ---------------- readout ----------------
__global__ __launch_bounds__(128) void readout_kernel(const float* __restrict__ x,
                                                      const float* __restrict__ w,
                                                      const int* __restrict__ gid, int N,
                                                      float* __restrict__ hs,
                                                      float* __restrict__ hm) {
  int g = blockIdx.x;
  int d = threadIdx.x;
  __shared__ int ss, se;
  if (d == 0) {
    ss = lower_bound_dev(gid, N, g);
    se = lower_bound_dev(gid, N, g + 1);
  }
  __syncthreads();
  double s = 0.0;
  float m = -1e30f;
  for (int n = ss; n < se; n++) {
    float v = x[(size_t)n * 128 + d];
    s += (double)v * (double)w[n];
    m = fmaxf(m, v);
  }
  hs[g * 128 + d] = (float)s;
  hm[g * 128 + d] = m;
}

// ---------------- pool linear ----------------
__global__ __launch_bounds__(128) void pool_kernel(const float* __restrict__ hs,
                                                   const float* __restrict__ hm,
                                                   const void* __restrict__ Wp, size_t woff,
                                                   const void* __restrict__ bp, size_t boff,
                                                   const int* __restrict__ pflag,
                                                   float* __restrict__ bout) {
  const bool pb = (*pflag != 0);
  int g = blockIdx.x, j = threadIdx.x;
  __shared__ float hg[256];
  hg[j] = hs[g * 128 + j];
  hg[128 + j] = hm[g * 128 + j];
  __syncthreads();
  double acc = (double)ldf(bp, boff + j, pb);
  for (int k = 0; k < 256; k++) acc += (double)hg[k] * (double)ldf(Wp, woff + (size_t)k * 128 + j, pb);
  bout[g * 128 + j] = (float)acc;
}

// ---------------- final head ----------------
__global__ __launch_bounds__(128) void head_kernel(const float* __restrict__ bA,
                                                   const float* __restrict__ bB,
                                                   const void* __restrict__ Wo1,
                                                   const void* __restrict__ bo1,
                                                   const void* __restrict__ Wo2,
                                                   const void* __restrict__ bo2,
                                                   const int* __restrict__ pflag,
                                                   const int* __restrict__ oflag,
                                                   void* __restrict__ out) {
  const bool pb = (*pflag != 0);
  int g = blockIdx.x, j = threadIdx.x;
  __shared__ float zr[256];
  __shared__ double t[128];
  zr[j] = bA[g * 128 + j];
  zr[128 + j] = bB[g * 128 + j];
  __syncthreads();
  double acc = (double)ldf(bo1, j, pb);
  for (int k = 0; k < 256; k++) acc += (double)zr[k] * (double)ldf(Wo1, (size_t)k * 128 + j, pb);
  if (acc < 0.0) acc *= 0.01;
  t[j] = acc * (double)ldf(Wo2, j, pb);
  __syncthreads();
  for (int sdt = 64; sdt > 0; sdt >>= 1) {
    if (j < sdt) t[j] += t[j + sdt];
    __syncthreads();
  }
  if (j == 0) {
    float v = (float)(t[0] + (double)ldf(bo2, 0, pb));
    if (*oflag) ((bf16*)out)[g] = __float2bfloat16(v);
    else ((float*)out)[g] = v;
  }
}

extern "C" void kernel_launch(void* const* d_in, const int* in_sizes, int n_in,
                              void* d_out, int out_size, void* d_ws, size_t ws_size,
                              hipStream_t stream) {
  const int* srcA = (const int*)d_in[0];
  const int* dstA = (const int*)d_in[1];
  const int* gidA = (const int*)d_in[2];
  const void* nfA = d_in[3];
  const void* efA = d_in[4];
  const int* srcB = (const int*)d_in[5];
  const int* dstB = (const int*)d_in[6];
  const int* gidB = (const int*)d_in[7];
  const void* nfB = d_in[8];
  const void* efB = d_in[9];
  const void* p_Wn = d_in[10];
  const void* p_bn = d_in[11];
  const void* p_We = d_in[12];
  const void* p_be = d_in[13];
  const void* p_Wc = d_in[14];
  const void* p_bc = d_in[15];
  const void* p_fc1 = d_in[16];
  const void* p_al1 = d_in[17];
  const void* p_ar1 = d_in[18];
  const void* p_gb1 = d_in[19];
  const void* p_Wl1 = d_in[20];
  const void* p_bl1 = d_in[21];
  const void* p_fc2 = d_in[22];
  const void* p_al2 = d_in[23];
  const void* p_ar2 = d_in[24];
  const void* p_gb2 = d_in[25];
  const void* p_Wl2 = d_in[26];
  const void* p_bl2 = d_in[27];
  const void* p_ws_w = d_in[28];
  const void* p_ws_b = d_in[29];
  const void* p_Wp = d_in[30];
  const void* p_bp = d_in[31];
  const void* Wo1 = d_in[32];
  const void* bo1 = d_in[33];
  const void* Wo2 = d_in[34];
  const void* bo2 = d_in[35];

  // workspace carve-up (~128 MB)
  char* wp = (char*)d_ws;
  auto alloc = [&](size_t bytes) -> char* {
    char* p = wp;
    wp += (bytes + 255) & ~(size_t)255;
    return p;
  };
  int* flags = (int*)alloc(2 * 4);
  int* cnt = (int*)alloc((size_t)Nn * 4);
  int* offs = (int*)alloc((size_t)(Nn + 1) * 4);
  int* cursor = (int*)alloc((size_t)Nn * 4);
  int* perm = (int*)alloc((size_t)Ne * 4);
  float* sden = (float*)alloc((size_t)Nn * 4 * 4);
  float* exe = (float*)alloc((size_t)Ne * 4 * 4);
  float* el = (float*)alloc((size_t)Nn * 4 * 4);
  float* er = (float*)alloc((size_t)Nn * 4 * 4);
  float* wn = (float*)alloc((size_t)Nn * 4);
  float* hsb = (float*)alloc((size_t)Bg * 128 * 4);
  float* hmb = (float*)alloc((size_t)Bg * 128 * 4);
  float* bout = (float*)alloc((size_t)2 * Bg * 128 * 4);
  // transposed bf16 hi/lo weight planes
  bf16* WctH = (bf16*)alloc((size_t)2 * 80 * 80 * 2);
  bf16* WctL = (bf16*)alloc((size_t)2 * 80 * 80 * 2);
  bf16* fc1tH = (bf16*)alloc((size_t)2 * 512 * 80 * 2);
  bf16* fc1tL = (bf16*)alloc((size_t)2 * 512 * 80 * 2);
  bf16* Wl1tH = (bf16*)alloc((size_t)2 * 128 * 512 * 2);
  bf16* Wl1tL = (bf16*)alloc((size_t)2 * 128 * 512 * 2);
  bf16* fc2tH = (bf16*)alloc((size_t)2 * 512 * 128 * 2);
  bf16* fc2tL = (bf16*)alloc((size_t)2 * 512 * 128 * 2);
  bf16* Wl2tH = (bf16*)alloc((size_t)2 * 128 * 512 * 2);
  bf16* Wl2tL = (bf16*)alloc((size_t)2 * 128 * 512 * 2);
  float* zb = (float*)alloc((size_t)Nn * 512 * 4);    // hn/he/xsum early -> z -> x2
  float* hb = (float*)alloc((size_t)Nn * 512 * 4);    // GAT gather output
  float* xcx1 = (float*)alloc((size_t)Nn * 128 * 4);  // xc early, x1 later
  // overlays
  float* hn = zb;                                        // Nn*64 f32
  float* he = zb + (size_t)Nn * 64;                      // Ne*16 f32
  float* xsum = zb + (size_t)Nn * 64 + (size_t)Ne * 16;  // Nn*80 f32 (40 MB < 51.2 MB)
  float* z = zb;                                         // Nn*512 f32 (after xsum consumed)
  float* x2 = zb;                                        // Nn*128 f32 (after z consumed)
  float* xc = xcx1;
  float* x1 = xcx1;

  auto cdiv = [](int a, int b) { return (a + b - 1) / b; };

  detect_kernel<<<1, 256, 0, stream>>>((const u16*)nfA, 8192, (const u16*)p_fc1, 8192, flags);
  int* fflag = &flags[0];
  int* pflag = &flags[1];

  // prep: transpose+convert hi/lo weight planes (both branches)
  for (int i = 0; i < 2; i++) {
    transconv_kernel<<<cdiv(80 * 80, 256), 256, 0, stream>>>(
        p_Wc, (size_t)i * 80 * 80, pflag,
        WctH + (size_t)i * 80 * 80, WctL + (size_t)i * 80 * 80, 80, 80);
    transconv_kernel<<<cdiv(80 * 512, 256), 256, 0, stream>>>(
        p_fc1, (size_t)i * 80 * 512, pflag,
        fc1tH + (size_t)i * 512 * 80, fc1tL + (size_t)i * 512 * 80, 80, 512);
    transconv_kernel<<<cdiv(512 * 128, 256), 256, 0, stream>>>(
        p_Wl1, (size_t)i * 512 * 128, pflag,
        Wl1tH + (size_t)i * 128 * 512, Wl1tL + (size_t)i * 128 * 512, 512, 128);
    transconv_kernel<<<cdiv(128 * 512, 256), 256, 0, stream>>>(
        p_fc2, (size_t)i * 128 * 512, pflag,
        fc2tH + (size_t)i * 512 * 128, fc2tL + (size_t)i * 512 * 128, 128, 512);
    transconv_kernel<<<cdiv(512 * 128, 256), 256, 0, stream>>>(
        p_Wl2, (size_t)i * 512 * 128, pflag,
        Wl2tH + (size_t)i * 128 * 512, Wl2tL + (size_t)i * 128 * 512, 512, 128);
  }

  auto run_branch = [&](int i, const int* src, const int* dst, const int* gid,
                        const void* nf, const void* ef, float* bout_i) {
    // CSR by dst (deterministic after sortseg)
    hipMemsetAsync(cnt, 0, (size_t)Nn * 4, stream);
    count_kernel<<<cdiv(Ne, 256), 256, 0, stream>>>(dst, cnt, Ne);
    scan_kernel<<<1, 256, 0, stream>>>(cnt, offs, Nn);
    copy_int_kernel<<<cdiv(Nn, 256), 256, 0, stream>>>(offs, cursor, Nn);
    fill_kernel<<<cdiv(Ne, 256), 256, 0, stream>>>(dst, cursor, perm, Ne);
    sortseg_kernel<<<cdiv(Nn, 256), 256, 0, stream>>>(offs, perm, Nn);
    // input projections (fp32 out)
    gemm_kernel<<<dim3(cdiv(Nn, 64), 1), 256, 0, stream>>>(
        nf, fflag, p_Wn, (size_t)i * 64 * 64, p_bn, (size_t)i * 64, pflag, hn, Nn, 64, 64);
    gemm_kernel<<<dim3(cdiv(Ne, 64), 1), 256, 0, stream>>>(
        ef, fflag, p_We, (size_t)i * 16 * 16, p_be, (size_t)i * 16, pflag, he, Ne, 16, 16);
    // EdgeGraphConv
    edgeconv_kernel<<<Nn, 128, 0, stream>>>(offs, perm, src, hn, he, xsum, Nn);
    mfma_split_gemm<1><<<dim3(cdiv(Nn, 128), 1), 256, 0, stream>>>(
        xsum, (const u16*)(WctH + (size_t)i * 80 * 80), (const u16*)(WctL + (size_t)i * 80 * 80),
        p_bc, (size_t)i * 80, pflag, xc, Nn, 80, 80);
    // GAT 1
    mfma_split_gemm<0><<<dim3(cdiv(Nn, 128), 4), 256, 0, stream>>>(
        xc, (const u16*)(fc1tH + (size_t)i * 512 * 80), (const u16*)(fc1tL + (size_t)i * 512 * 80),
        nullptr, 0, pflag, z, Nn, 80, 512);
    attn_lr_kernel<<<cdiv(Nn * 64, 256), 256, 0, stream>>>(
        z, p_al1, p_ar1, (size_t)i * 512, pflag, el, er, Nn);
    edge_softmax_kernel<<<cdiv(Ne, 256), 256, 0, stream>>>(src, dst, el, er, exe, Ne);
    sden_kernel<<<cdiv(Nn * 4, 256), 256, 0, stream>>>(offs, perm, exe, sden, Nn);
    gat_gather_kernel<<<cdiv(Nn * 64, 256), 256, 0, stream>>>(
        offs, perm, src, z, exe, sden, p_gb1, (size_t)i * 512, pflag, hb, Nn);
    mfma_split_gemm<0><<<dim3(cdiv(Nn, 128), 1), 256, 0, stream>>>(
        hb, (const u16*)(Wl1tH + (size_t)i * 128 * 512), (const u16*)(Wl1tL + (size_t)i * 128 * 512),
        p_bl1, (size_t)i * 128, pflag, x1, Nn, 512, 128);
    // GAT 2
    mfma_split_gemm<0><<<dim3(cdiv(Nn, 128), 4), 256, 0, stream>>>(
        x1, (const u16*)(fc2tH + (size_t)i * 512 * 128), (const u16*)(fc2tL + (size_t)i * 512 * 128),
        nullptr, 0, pflag, z, Nn, 128, 512);
    attn_lr_kernel<<<cdiv(Nn * 64, 256), 256, 0, stream>>>(
        z, p_al2, p_ar2, (size_t)i * 512, pflag, el, er, Nn);
    edge_softmax_kernel<<<cdiv(Ne, 256), 256, 0, stream>>>(src, dst, el, er, exe, Ne);
    sden_kernel<<<cdiv(Nn * 4, 256), 256, 0, stream>>>(offs, perm, exe, sden, Nn);
    gat_gather_kernel<<<cdiv(Nn * 64, 256), 256, 0, stream>>>(
        offs, perm, src, z, exe, sden, p_gb2, (size_t)i * 512, pflag, hb, Nn);
    mfma_split_gemm<0><<<dim3(cdiv(Nn, 128), 1), 256, 0, stream>>>(
        hb, (const u16*)(Wl2tH + (size_t)i * 128 * 512), (const u16*)(Wl2tL + (size_t)i * 128 * 512),
        p_bl2, (size_t)i * 128, pflag, x2, Nn, 512, 128);
    // readout
    wnode_kernel<<<cdiv(Nn * 64, 256), 256, 0, stream>>>(
        x2, p_ws_w, (size_t)i * 128, p_ws_b, (size_t)i, pflag, wn, Nn);
    readout_kernel<<<Bg, 128, 0, stream>>>(x2, wn, gid, Nn, hsb, hmb);
    pool_kernel<<<Bg, 128, 0, stream>>>(
        hsb, hmb, p_Wp, (size_t)i * 256 * 128, p_bp, (size_t)i * 128, pflag, bout_i);
  };

  run_branch(0, srcA, dstA, gidA, nfA, efA, bout);
  run_branch(1, srcB, dstB, gidB, nfB, efB, bout + (size_t)Bg * 128);

  head_kernel<<<Bg, 128, 0, stream>>>(bout, bout + (size_t)Bg * 128, Wo1, bo1, Wo2, bo2,
                                      pflag, fflag, d_out);
}

// Round 6
// 1863.768 us; speedup vs baseline: 1.6583x; 1.2883x over previous
//
#include <hip/hip_runtime.h>
#include <hip/hip_bf16.h>
#include <hip/hip_fp16.h>

typedef __hip_bfloat16 bf16;
typedef unsigned short u16;
typedef __attribute__((ext_vector_type(8))) short short8;
typedef __attribute__((ext_vector_type(4))) float floatx4;

static constexpr int Nn = 25000;   // nodes
static constexpr int Ne = 400000;  // edges
static constexpr int Bg = 64;      // graphs

// flag-aware element load: b16 ? bf16[i] : f32[i]
__device__ __forceinline__ float ldf(const void* p, size_t i, bool b16) {
  return b16 ? __bfloat162float(((const bf16*)p)[i]) : ((const float*)p)[i];
}

// ---------------- dtype detection ----------------
__global__ void detect_kernel(const u16* a, int n, const u16* b, int m, int* flags) {
  __shared__ int c0, c1;
  if (threadIdx.x == 0) { c0 = 0; c1 = 0; }
  __syncthreads();
  int t = threadIdx.x;
  int l0 = 0, l1 = 0;
  for (int i = t; i < n; i += 256) {
    unsigned e = (a[i] >> 7) & 0xFF;
    if (e >= 140) l0++;
  }
  for (int i = t; i < m; i += 256) {
    unsigned e = (b[i] >> 7) & 0xFF;
    if (e >= 140) l1++;
  }
  atomicAdd(&c0, l0);
  atomicAdd(&c1, l1);
  __syncthreads();
  if (t == 0) {
    flags[0] = (c0 < n / 16) ? 1 : 0;  // 1 = features are bf16
    flags[1] = (c1 < m / 16) ? 1 : 0;  // 1 = params are bf16
  }
}

// ------- fused transpose+convert: all big weights -> hi/lo bf16 planes [N][K] ----------
struct TC { const void* W; size_t off; bf16* H; bf16* L; int K; int N; int start; };
struct TCAll { TC t[10]; int total; };

__global__ void transconv_all_kernel(TCAll a, const int* __restrict__ pflag) {
  const bool pb = (*pflag != 0);
  int idx = blockIdx.x * 256 + threadIdx.x;
  if (idx >= a.total) return;
  int s = 0;
  while (s + 1 < 10 && idx >= a.t[s + 1].start) s++;
  int li = idx - a.t[s].start;
  int K = a.t[s].K, N = a.t[s].N;
  int k = li / N, n = li - k * N;
  float w = ldf(a.t[s].W, a.t[s].off + li, pb);
  bf16 h = __float2bfloat16(w);
  a.t[s].H[(size_t)n * K + k] = h;
  a.t[s].L[(size_t)n * K + k] = __float2bfloat16(w - __bfloat162float(h));
}

// ---------------- split-precision MFMA GEMM: C = act(A[M,K]f32 @ B^T + bias) -----------
// A and B both decomposed into bf16 hi+lo planes; 3 MFMAs per fragment.
// OUT: 0 -> fp32 C, 2 -> fp16 C. ACT: 0 none, 1 relu.
template <int ACT, int OUT>
__global__ __launch_bounds__(256) void mfma_split_gemm(const float* __restrict__ A,
                                                       const u16* __restrict__ Bh,
                                                       const u16* __restrict__ Bl,
                                                       const void* __restrict__ bias, size_t boff,
                                                       const int* __restrict__ pflag,
                                                       void* __restrict__ C,
                                                       int M, int K, int N) {
  __shared__ short Ahs[128 * 40];
  __shared__ short Als[128 * 40];
  __shared__ short Bhs[128 * 40];
  __shared__ short Bls[128 * 40];
  const int bm = blockIdx.x * 128;
  const int bn = blockIdx.y * 128;
  const int tid = threadIdx.x;
  const int lane = tid & 63;
  const int wave = tid >> 6;
  const int wm = wave >> 1, wn = wave & 1;
  const int lm = lane & 15, quad = lane >> 4;
  const int srow = tid >> 1;   // 0..127
  const int sseg = tid & 1;    // 16-elem half of the 32-k chunk
  floatx4 acc[4][4] = {};
  for (int k0 = 0; k0 < K; k0 += 32) {
    bool kv = (k0 + sseg * 16) < K;
    // ---- stage A tile [128 x 32] fp32 -> hi/lo bf16 planes ----
    {
      int gr = bm + srow;
      short hv[16], lv[16];
      if (gr < M && kv) {
        const float4* gp = (const float4*)(A + (size_t)gr * K + k0 + sseg * 16);
#pragma unroll
        for (int v = 0; v < 4; v++) {
          float4 f = gp[v];
          float xs[4] = {f.x, f.y, f.z, f.w};
#pragma unroll
          for (int q = 0; q < 4; q++) {
            bf16 h = __float2bfloat16(xs[q]);
            float hf = __bfloat162float(h);
            bf16 l = __float2bfloat16(xs[q] - hf);
            hv[v * 4 + q] = *(short*)&h;
            lv[v * 4 + q] = *(short*)&l;
          }
        }
      } else {
#pragma unroll
        for (int q = 0; q < 16; q++) { hv[q] = 0; lv[q] = 0; }
      }
      *(short8*)&Ahs[srow * 40 + sseg * 16] = *(short8*)&hv[0];
      *(short8*)&Ahs[srow * 40 + sseg * 16 + 8] = *(short8*)&hv[8];
      *(short8*)&Als[srow * 40 + sseg * 16] = *(short8*)&lv[0];
      *(short8*)&Als[srow * 40 + sseg * 16 + 8] = *(short8*)&lv[8];
    }
    // ---- stage B hi/lo tiles (rows of B* = output cols) ----
    {
      int gc = bn + srow;
      short8 h0 = {}, h1 = {}, l0 = {}, l1 = {};
      if (gc < N && kv) {
        const short8* hp = (const short8*)(Bh + (size_t)gc * K + k0 + sseg * 16);
        const short8* lp = (const short8*)(Bl + (size_t)gc * K + k0 + sseg * 16);
        h0 = hp[0]; h1 = hp[1];
        l0 = lp[0]; l1 = lp[1];
      }
      *(short8*)&Bhs[srow * 40 + sseg * 16] = h0;
      *(short8*)&Bhs[srow * 40 + sseg * 16 + 8] = h1;
      *(short8*)&Bls[srow * 40 + sseg * 16] = l0;
      *(short8*)&Bls[srow * 40 + sseg * 16 + 8] = l1;
    }
    __syncthreads();
    short8 ah[4], al[4], bh[4], bl[4];
#pragma unroll
    for (int f = 0; f < 4; f++) {
      ah[f] = *(const short8*)&Ahs[(wm * 64 + f * 16 + lm) * 40 + quad * 8];
      al[f] = *(const short8*)&Als[(wm * 64 + f * 16 + lm) * 40 + quad * 8];
      bh[f] = *(const short8*)&Bhs[(wn * 64 + f * 16 + lm) * 40 + quad * 8];
      bl[f] = *(const short8*)&Bls[(wn * 64 + f * 16 + lm) * 40 + quad * 8];
    }
#pragma unroll
    for (int i = 0; i < 4; i++)
#pragma unroll
      for (int j = 0; j < 4; j++) {
        acc[i][j] = __builtin_amdgcn_mfma_f32_16x16x32_bf16(al[i], bh[j], acc[i][j], 0, 0, 0);
        acc[i][j] = __builtin_amdgcn_mfma_f32_16x16x32_bf16(ah[i], bl[j], acc[i][j], 0, 0, 0);
        acc[i][j] = __builtin_amdgcn_mfma_f32_16x16x32_bf16(ah[i], bh[j], acc[i][j], 0, 0, 0);
      }
    __syncthreads();
  }
  // ---- epilogue: C/D layout col=lane&15, row=quad*4+reg ----
  const bool pb = (*pflag != 0);
#pragma unroll
  for (int i = 0; i < 4; i++) {
#pragma unroll
    for (int j = 0; j < 4; j++) {
      int col = bn + wn * 64 + j * 16 + lm;
      if (col >= N) continue;
#pragma unroll
      for (int r = 0; r < 4; r++) {
        int row = bm + wm * 64 + i * 16 + quad * 4 + r;
        if (row >= M) continue;
        float v = acc[i][j][r];
        if (bias) v += ldf(bias, boff + col, pb);
        if (ACT == 1) v = v > 0.f ? v : 0.f;
        if (OUT == 0)
          ((float*)C)[(size_t)row * N + col] = v;
        else
          ((__half*)C)[(size_t)row * N + col] = __float2half(v);
      }
    }
  }
}

// ---------------- input projection: hn[n][64] fp16 = nf[n]·Wn + bn ----------------
__global__ __launch_bounds__(256) void proj_nf_kernel(const void* __restrict__ nf,
                                                      const int* __restrict__ fflag,
                                                      const void* __restrict__ Wn, size_t woff,
                                                      const void* __restrict__ bn, size_t boff,
                                                      const int* __restrict__ pflag,
                                                      __half* __restrict__ hn, int N) {
  __shared__ float Ws[64 * 65];
  __shared__ float bs[64];
  __shared__ float rowbuf[4][64];
  const bool fb = (*fflag != 0), pb = (*pflag != 0);
  int t = threadIdx.x;
  for (int i = t; i < 4096; i += 256) {
    int k = i >> 6, c = i & 63;
    Ws[k * 65 + c] = ldf(Wn, woff + i, pb);
  }
  if (t < 64) bs[t] = ldf(bn, boff + t, pb);
  __syncthreads();
  int wave = t >> 6, lane = t & 63;
  int n = blockIdx.x * 4 + wave;
  if (n >= N) return;
  rowbuf[wave][lane] = ldf(nf, (size_t)n * 64 + lane, fb);
  float acc = bs[lane];
#pragma unroll 8
  for (int k = 0; k < 64; k++) acc += rowbuf[wave][k] * Ws[k * 65 + lane];
  hn[(size_t)n * 64 + lane] = __float2half(acc);
}

// ---------------- input projection: he[e][16] fp32 = ef[e]·We + be ----------------
__global__ __launch_bounds__(256) void proj_ef_kernel(const void* __restrict__ ef,
                                                      const int* __restrict__ fflag,
                                                      const void* __restrict__ We, size_t woff,
                                                      const void* __restrict__ be, size_t boff,
                                                      const int* __restrict__ pflag,
                                                      float* __restrict__ he, int E) {
  __shared__ float Ws[16 * 17];
  __shared__ float bs[16];
  __shared__ float efs[16][17];
  const bool fb = (*fflag != 0), pb = (*pflag != 0);
  int t = threadIdx.x;
  Ws[(t >> 4) * 17 + (t & 15)] = ldf(We, woff + t, pb);
  if (t < 16) bs[t] = ldf(be, boff + t, pb);
  int el = t >> 4, k = t & 15;
  int e = blockIdx.x * 16 + el;
  float v = 0.f;
  if (e < E) v = ldf(ef, (size_t)e * 16 + k, fb);
  efs[el][k] = v;
  __syncthreads();
  if (e < E) {
    float acc = bs[k];
#pragma unroll
    for (int kk = 0; kk < 16; kk++) acc += efs[el][kk] * Ws[kk * 17 + k];
    he[(size_t)e * 16 + k] = acc;
  }
}

// ---------------- CSR build ----------------
__global__ void count_kernel(const int* __restrict__ dst, int* __restrict__ cnt, int E) {
  int e = blockIdx.x * blockDim.x + threadIdx.x;
  if (e < E) atomicAdd(&cnt[dst[e]], 1);
}

// per-256-chunk inclusive scan + block sums
__global__ void scan1_kernel(const int* __restrict__ cnt, int* __restrict__ incl,
                             int* __restrict__ bsum, int n) {
  __shared__ int buf[256];
  int t = threadIdx.x;
  int i = blockIdx.x * 256 + t;
  int v = (i < n) ? cnt[i] : 0;
  buf[t] = v;
  __syncthreads();
  for (int d = 1; d < 256; d <<= 1) {
    int add = (t >= d) ? buf[t - d] : 0;
    __syncthreads();
    buf[t] += add;
    __syncthreads();
  }
  if (i < n) incl[i] = buf[t];
  if (t == 255) bsum[blockIdx.x] = buf[255];
}

// single-block exclusive scan over block sums (nb <= 256)
__global__ void scan2_kernel(int* __restrict__ bsum, int nb) {
  __shared__ int buf[256];
  int t = threadIdx.x;
  int v = (t < nb) ? bsum[t] : 0;
  buf[t] = v;
  __syncthreads();
  for (int d = 1; d < 256; d <<= 1) {
    int add = (t >= d) ? buf[t - d] : 0;
    __syncthreads();
    buf[t] += add;
    __syncthreads();
  }
  if (t < nb) bsum[t] = buf[t] - v;
}

// offs[i] = exclusive scan; cursor = copy; offs[n] = total
__global__ void scan3_kernel(const int* __restrict__ cnt, const int* __restrict__ incl,
                             const int* __restrict__ bsum, int* __restrict__ offs,
                             int* __restrict__ cursor, int n) {
  int i = blockIdx.x * 256 + threadIdx.x;
  if (i < n) {
    int e = incl[i] - cnt[i] + bsum[blockIdx.x];
    offs[i] = e;
    cursor[i] = e;
    if (i == n - 1) offs[n] = incl[i] + bsum[blockIdx.x];
  }
}

__global__ void fill_kernel(const int* __restrict__ dst, int* __restrict__ cursor,
                            int* __restrict__ perm, int E) {
  int e = blockIdx.x * blockDim.x + threadIdx.x;
  if (e < E) {
    int p = atomicAdd(&cursor[dst[e]], 1);
    perm[p] = e;
  }
}

// ---------------- sort each node's segment by edge id -> deterministic sums ------------
__global__ void sortseg_kernel(const int* __restrict__ off, int* __restrict__ perm, int N) {
  int n = blockIdx.x * blockDim.x + threadIdx.x;
  if (n >= N) return;
  int e0 = off[n], e1 = off[n + 1];
  int d = e1 - e0;
  if (d <= 1) return;
  if (d <= 96) {
    int loc[96];
    for (int i = 0; i < d; i++) loc[i] = perm[e0 + i];
    for (int i = 1; i < d; i++) {
      int v = loc[i];
      int j = i - 1;
      while (j >= 0 && loc[j] > v) { loc[j + 1] = loc[j]; j--; }
      loc[j + 1] = v;
    }
    for (int i = 0; i < d; i++) perm[e0 + i] = loc[i];
  } else {
    for (int i = 0; i < d - 1; i++) {
      int mi = i;
      for (int j = i + 1; j < d; j++)
        if (perm[e0 + j] < perm[e0 + mi]) mi = j;
      int t = perm[e0 + i];
      perm[e0 + i] = perm[e0 + mi];
      perm[e0 + mi] = t;
    }
  }
}

// ---------------- EdgeGraphConv gather-sum (fp16 hn, fp32 he/out) ----------------
__global__ __launch_bounds__(128) void edgeconv_kernel(const int* __restrict__ off,
                                                       const int* __restrict__ perm,
                                                       const int* __restrict__ src,
                                                       const __half* __restrict__ hn,
                                                       const float* __restrict__ he,
                                                       float* __restrict__ xsum, int N) {
  int n = blockIdx.x;
  int f = threadIdx.x;
  if (n >= N || f >= 80) return;
  int e0 = off[n], e1 = off[n + 1];
  float acc = 0.f;
  if (f < 64) {
    int eg = e0;
    for (; eg + 2 <= e1; eg += 2) {
      int ea = perm[eg], eb = perm[eg + 1];
      int sa = src[ea], sb = src[eb];
      float va = __half2float(hn[(size_t)sa * 64 + f]);
      float vb = __half2float(hn[(size_t)sb * 64 + f]);
      acc += va;
      acc += vb;
    }
    if (eg < e1) acc += __half2float(hn[(size_t)src[perm[eg]] * 64 + f]);
  } else {
    int c = f - 64;
    for (int eg = e0; eg < e1; eg++) acc += he[(size_t)perm[eg] * 16 + c];
  }
  xsum[(size_t)n * 80 + f] = acc;
}

// ---------------- attention el/er (fp16 z) ----------------
__global__ __launch_bounds__(256) void attn_lr_kernel(const __half* __restrict__ z,
                                                      const void* __restrict__ al,
                                                      const void* __restrict__ ar, size_t off,
                                                      const int* __restrict__ pflag,
                                                      float* __restrict__ el,
                                                      float* __restrict__ er, int N) {
  const bool pb = (*pflag != 0);
  int n = (blockIdx.x * blockDim.x + threadIdx.x) >> 6;
  int lane = threadIdx.x & 63;
  if (n >= N) return;
  union { uint4 q; __half s[8]; } u;
  u.q = *(const uint4*)(z + (size_t)n * 512 + lane * 8);
  float sl = 0.f, sr = 0.f;
#pragma unroll
  for (int q = 0; q < 8; q++) {
    int idx = lane * 8 + q;
    float zv = __half2float(u.s[q]);
    sl += zv * ldf(al, off + idx, pb);
    sr += zv * ldf(ar, off + idx, pb);
  }
#pragma unroll
  for (int o = 1; o < 16; o <<= 1) {
    sl += __shfl_xor(sl, o);
    sr += __shfl_xor(sr, o);
  }
  if ((lane & 15) == 0) {
    int h = lane >> 4;
    el[n * 4 + h] = sl;
    er[n * 4 + h] = sr;
  }
}

// ---------------- edge softmax numerator (no atomics) ----------------
__global__ void edge_softmax_kernel(const int* __restrict__ src, const int* __restrict__ dst,
                                    const float* __restrict__ el, const float* __restrict__ er,
                                    float* __restrict__ exe, int E) {
  int e = blockIdx.x * blockDim.x + threadIdx.x;
  if (e >= E) return;
  int sv = src[e], dv = dst[e];
#pragma unroll
  for (int h = 0; h < 4; h++) {
    float v = el[sv * 4 + h] + er[dv * 4 + h];
    v = v > 0.f ? v : 0.2f * v;
    v = fminf(v, 60.f);
    exe[e * 4 + h] = expf(v);
  }
}

// ---------------- softmax denominator via CSR (deterministic) ----------------
__global__ void sden_kernel(const int* __restrict__ off, const int* __restrict__ perm,
                            const float* __restrict__ exe, float* __restrict__ sden, int N) {
  int idx = blockIdx.x * blockDim.x + threadIdx.x;
  int n = idx >> 2, h = idx & 3;
  if (n >= N) return;
  int e0 = off[n], e1 = off[n + 1];
  float s = 0.f;
  for (int eg = e0; eg < e1; eg++) s += exe[perm[eg] * 4 + h];
  sden[n * 4 + h] = s;
}

// ---------------- GAT gather (fp16 z in, fp32 out), pair-unrolled ----------------
__global__ __launch_bounds__(256) void gat_gather_kernel(const int* __restrict__ off,
                                                         const int* __restrict__ perm,
                                                         const int* __restrict__ src,
                                                         const __half* __restrict__ z,
                                                         const float* __restrict__ exe,
                                                         const float* __restrict__ sden,
                                                         const void* __restrict__ gb, size_t goff,
                                                         const int* __restrict__ pflag,
                                                         float* __restrict__ out, int N) {
  const bool pb = (*pflag != 0);
  int n = (blockIdx.x * blockDim.x + threadIdx.x) >> 6;
  int lane = threadIdx.x & 63;
  if (n >= N) return;
  int h = lane >> 4;
  float sd = sden[n * 4 + h];
  float sinv = sd > 0.f ? 1.f / sd : 0.f;
  float acc[8] = {0.f, 0.f, 0.f, 0.f, 0.f, 0.f, 0.f, 0.f};
  int e0 = off[n], e1 = off[n + 1];
  int eg = e0;
  for (; eg + 2 <= e1; eg += 2) {
    int ea = perm[eg], eb = perm[eg + 1];
    int sa = src[ea], sb = src[eb];
    float aa = exe[ea * 4 + h] * sinv;
    float ab = exe[eb * 4 + h] * sinv;
    union { uint4 q; __half s[8]; } ua, ub;
    ua.q = *(const uint4*)(z + (size_t)sa * 512 + lane * 8);
    ub.q = *(const uint4*)(z + (size_t)sb * 512 + lane * 8);
#pragma unroll
    for (int q = 0; q < 8; q++) acc[q] += aa * __half2float(ua.s[q]);
#pragma unroll
    for (int q = 0; q < 8; q++) acc[q] += ab * __half2float(ub.s[q]);
  }
  if (eg < e1) {
    int ea = perm[eg];
    int sa = src[ea];
    float aa = exe[ea * 4 + h] * sinv;
    union { uint4 q; __half s[8]; } ua;
    ua.q = *(const uint4*)(z + (size_t)sa * 512 + lane * 8);
#pragma unroll
    for (int q = 0; q < 8; q++) acc[q] += aa * __half2float(ua.s[q]);
  }
  float* o = out + (size_t)n * 512 + lane * 8;
#pragma unroll
  for (int q = 0; q < 8; q++) {
    float v = acc[q] + ldf(gb, goff + lane * 8 + q, pb);
    o[q] = v > 0.f ? v : 0.01f * v;
  }
}

// ---------------- node weight ----------------
__global__ __launch_bounds__(256) void wnode_kernel(const float* __restrict__ x,
                                                    const void* __restrict__ wsw, size_t woff,
                                                    const void* __restrict__ wsb, size_t boff,
                                                    const int* __restrict__ pflag,
                                                    float* __restrict__ w, int N) {
  const bool pb = (*pflag != 0);
  int n = (blockIdx.x * blockDim.x + threadIdx.x) >> 6;
  int lane = threadIdx.x & 63;
  if (n >= N) return;
  float s = x[(size_t)n * 128 + lane] * ldf(wsw, woff + lane, pb) +
            x[(size_t)n * 128 + 64 + lane] * ldf(wsw, woff + 64 + lane, pb);
#pragma unroll
  for (int o = 1; o < 64; o <<= 1) s += __shfl_xor(s, o);
  if (lane == 0) {
    float t = s + ldf(wsb, boff, pb);
    t = fmaxf(fminf(t, 60.f), -60.f);
    w[n] = 1.f / (1.f + expf(-t));
  }
}

__device__ __forceinline__ int lower_bound_dev(const int* a, int n, int v) {
  int lo = 0, hi = n;
  while (lo < hi) {
    int mid = (lo + hi) >> 1;
    if (a[mid] < v) lo = mid + 1; else hi = mid;
  }
  return lo;
}

// ---------------- readout ----------------
__global__ __launch_bounds__(128) void readout_kernel(const float* __restrict__ x,
                                                      const float* __restrict__ w,
                                                      const int* __restrict__ gid, int N,
                                                      float* __restrict__ hs,
                                                      float* __restrict__ hm) {
  int g = blockIdx.x;
  int d = threadIdx.x;
  __shared__ int ss, se;
  if (d == 0) {
    ss = lower_bound_dev(gid, N, g);
    se = lower_bound_dev(gid, N, g + 1);
  }
  __syncthreads();
  double s = 0.0;
  float m = -1e30f;
  for (int n = ss; n < se; n++) {
    float v = x[(size_t)n * 128 + d];
    s += (double)v * (double)w[n];
    m = fmaxf(m, v);
  }
  hs[g * 128 + d] = (float)s;
  hm[g * 128 + d] = m;
}

// ---------------- pool linear ----------------
__global__ __launch_bounds__(128) void pool_kernel(const float* __restrict__ hs,
                                                   const float* __restrict__ hm,
                                                   const void* __restrict__ Wp, size_t woff,
                                                   const void* __restrict__ bp, size_t boff,
                                                   const int* __restrict__ pflag,
                                                   float* __restrict__ bout) {
  const bool pb = (*pflag != 0);
  int g = blockIdx.x, j = threadIdx.x;
  __shared__ float hg[256];
  hg[j] = hs[g * 128 + j];
  hg[128 + j] = hm[g * 128 + j];
  __syncthreads();
  double acc = (double)ldf(bp, boff + j, pb);
  for (int k = 0; k < 256; k++) acc += (double)hg[k] * (double)ldf(Wp, woff + (size_t)k * 128 + j, pb);
  bout[g * 128 + j] = (float)acc;
}

// ---------------- final head ----------------
__global__ __launch_bounds__(128) void head_kernel(const float* __restrict__ bA,
                                                   const float* __restrict__ bB,
                                                   const void* __restrict__ Wo1,
                                                   const void* __restrict__ bo1,
                                                   const void* __restrict__ Wo2,
                                                   const void* __restrict__ bo2,
                                                   const int* __restrict__ pflag,
                                                   const int* __restrict__ oflag,
                                                   void* __restrict__ out) {
  const bool pb = (*pflag != 0);
  int g = blockIdx.x, j = threadIdx.x;
  __shared__ float zr[256];
  __shared__ double t[128];
  zr[j] = bA[g * 128 + j];
  zr[128 + j] = bB[g * 128 + j];
  __syncthreads();
  double acc = (double)ldf(bo1, j, pb);
  for (int k = 0; k < 256; k++) acc += (double)zr[k] * (double)ldf(Wo1, (size_t)k * 128 + j, pb);
  if (acc < 0.0) acc *= 0.01;
  t[j] = acc * (double)ldf(Wo2, j, pb);
  __syncthreads();
  for (int sdt = 64; sdt > 0; sdt >>= 1) {
    if (j < sdt) t[j] += t[j + sdt];
    __syncthreads();
  }
  if (j == 0) {
    float v = (float)(t[0] + (double)ldf(bo2, 0, pb));
    if (*oflag) ((bf16*)out)[g] = __float2bfloat16(v);
    else ((float*)out)[g] = v;
  }
}

extern "C" void kernel_launch(void* const* d_in, const int* in_sizes, int n_in,
                              void* d_out, int out_size, void* d_ws, size_t ws_size,
                              hipStream_t stream) {
  const int* srcA = (const int*)d_in[0];
  const int* dstA = (const int*)d_in[1];
  const int* gidA = (const int*)d_in[2];
  const void* nfA = d_in[3];
  const void* efA = d_in[4];
  const int* srcB = (const int*)d_in[5];
  const int* dstB = (const int*)d_in[6];
  const int* gidB = (const int*)d_in[7];
  const void* nfB = d_in[8];
  const void* efB = d_in[9];
  const void* p_Wn = d_in[10];
  const void* p_bn = d_in[11];
  const void* p_We = d_in[12];
  const void* p_be = d_in[13];
  const void* p_Wc = d_in[14];
  const void* p_bc = d_in[15];
  const void* p_fc1 = d_in[16];
  const void* p_al1 = d_in[17];
  const void* p_ar1 = d_in[18];
  const void* p_gb1 = d_in[19];
  const void* p_Wl1 = d_in[20];
  const void* p_bl1 = d_in[21];
  const void* p_fc2 = d_in[22];
  const void* p_al2 = d_in[23];
  const void* p_ar2 = d_in[24];
  const void* p_gb2 = d_in[25];
  const void* p_Wl2 = d_in[26];
  const void* p_bl2 = d_in[27];
  const void* p_ws_w = d_in[28];
  const void* p_ws_b = d_in[29];
  const void* p_Wp = d_in[30];
  const void* p_bp = d_in[31];
  const void* Wo1 = d_in[32];
  const void* bo1 = d_in[33];
  const void* Wo2 = d_in[34];
  const void* bo2 = d_in[35];

  // workspace carve-up (~127 MB)
  char* wp = (char*)d_ws;
  auto alloc = [&](size_t bytes) -> char* {
    char* p = wp;
    wp += (bytes + 255) & ~(size_t)255;
    return p;
  };
  int* flags = (int*)alloc(2 * 4);
  int* cnt = (int*)alloc((size_t)Nn * 4);
  int* incl = (int*)alloc((size_t)Nn * 4);
  int* bsum = (int*)alloc(256 * 4);
  int* offs = (int*)alloc((size_t)(Nn + 1) * 4);
  int* cursor = (int*)alloc((size_t)Nn * 4);
  int* perm = (int*)alloc((size_t)Ne * 4);
  float* sden = (float*)alloc((size_t)Nn * 4 * 4);
  float* exe = (float*)alloc((size_t)Ne * 4 * 4);
  float* el = (float*)alloc((size_t)Nn * 4 * 4);
  float* er = (float*)alloc((size_t)Nn * 4 * 4);
  float* wn = (float*)alloc((size_t)Nn * 4);
  float* hsb = (float*)alloc((size_t)Bg * 128 * 4);
  float* hmb = (float*)alloc((size_t)Bg * 128 * 4);
  float* bout = (float*)alloc((size_t)2 * Bg * 128 * 4);
  // transposed bf16 hi/lo weight planes
  bf16* WctH = (bf16*)alloc((size_t)2 * 80 * 80 * 2);
  bf16* WctL = (bf16*)alloc((size_t)2 * 80 * 80 * 2);
  bf16* fc1tH = (bf16*)alloc((size_t)2 * 512 * 80 * 2);
  bf16* fc1tL = (bf16*)alloc((size_t)2 * 512 * 80 * 2);
  bf16* Wl1tH = (bf16*)alloc((size_t)2 * 128 * 512 * 2);
  bf16* Wl1tL = (bf16*)alloc((size_t)2 * 128 * 512 * 2);
  bf16* fc2tH = (bf16*)alloc((size_t)2 * 512 * 128 * 2);
  bf16* fc2tL = (bf16*)alloc((size_t)2 * 512 * 128 * 2);
  bf16* Wl2tH = (bf16*)alloc((size_t)2 * 128 * 512 * 2);
  bf16* Wl2tL = (bf16*)alloc((size_t)2 * 128 * 512 * 2);
  char* zreg = alloc((size_t)Nn * 512 * 4);           // hn/he/xsum early -> z(half) -> x2(f32)
  float* hb = (float*)alloc((size_t)Nn * 512 * 4);    // GAT gather output
  float* xcx1 = (float*)alloc((size_t)Nn * 128 * 4);  // xc early, x1 later
  // overlays inside zreg
  __half* hn = (__half*)zreg;                                          // Nn*64 fp16 = 3.2 MB
  float* he = (float*)(zreg + (size_t)Nn * 64 * 2);                    // Ne*16 f32 = 25.6 MB
  float* xsum = (float*)(zreg + (size_t)Nn * 64 * 2 + (size_t)Ne * 16 * 4);  // Nn*80 f32
  __half* z = (__half*)zreg;                                           // Nn*512 fp16 (25.6 MB)
  float* x2 = (float*)zreg;                                            // Nn*128 f32
  float* xc = xcx1;
  float* x1 = xcx1;

  auto cdiv = [](int a, int b) { return (a + b - 1) / b; };

  detect_kernel<<<1, 256, 0, stream>>>((const u16*)nfA, 8192, (const u16*)p_fc1, 8192, flags);
  int* fflag = &flags[0];
  int* pflag = &flags[1];

  // prep: fused transpose+convert of all hi/lo weight planes (both branches)
  {
    TCAll tc;
    int segK[5] = {80, 80, 512, 128, 512};
    int segN[5] = {80, 512, 128, 512, 128};
    const void* segW[5] = {p_Wc, p_fc1, p_Wl1, p_fc2, p_Wl2};
    bf16* segH[5] = {WctH, fc1tH, Wl1tH, fc2tH, Wl2tH};
    bf16* segL[5] = {WctL, fc1tL, Wl1tL, fc2tL, Wl2tL};
    int start = 0, s = 0;
    for (int i = 0; i < 2; i++)
      for (int m = 0; m < 5; m++) {
        int sz = segK[m] * segN[m];
        tc.t[s].W = segW[m];
        tc.t[s].off = (size_t)i * sz;
        tc.t[s].H = segH[m] + (size_t)i * sz;
        tc.t[s].L = segL[m] + (size_t)i * sz;
        tc.t[s].K = segK[m];
        tc.t[s].N = segN[m];
        tc.t[s].start = start;
        start += sz;
        s++;
      }
    tc.total = start;
    transconv_all_kernel<<<cdiv(start, 256), 256, 0, stream>>>(tc, pflag);
  }

  const int nb = cdiv(Nn, 256);  // 98 scan blocks

  auto run_branch = [&](int i, const int* src, const int* dst, const int* gid,
                        const void* nf, const void* ef, float* bout_i) {
    // CSR by dst (deterministic after sortseg)
    hipMemsetAsync(cnt, 0, (size_t)Nn * 4, stream);
    count_kernel<<<cdiv(Ne, 256), 256, 0, stream>>>(dst, cnt, Ne);
    scan1_kernel<<<nb, 256, 0, stream>>>(cnt, incl, bsum, Nn);
    scan2_kernel<<<1, 256, 0, stream>>>(bsum, nb);
    scan3_kernel<<<nb, 256, 0, stream>>>(cnt, incl, bsum, offs, cursor, Nn);
    fill_kernel<<<cdiv(Ne, 256), 256, 0, stream>>>(dst, cursor, perm, Ne);
    sortseg_kernel<<<cdiv(Nn, 256), 256, 0, stream>>>(offs, perm, Nn);
    // input projections
    proj_nf_kernel<<<cdiv(Nn, 4), 256, 0, stream>>>(
        nf, fflag, p_Wn, (size_t)i * 64 * 64, p_bn, (size_t)i * 64, pflag, hn, Nn);
    proj_ef_kernel<<<cdiv(Ne, 16), 256, 0, stream>>>(
        ef, fflag, p_We, (size_t)i * 16 * 16, p_be, (size_t)i * 16, pflag, he, Ne);
    // EdgeGraphConv
    edgeconv_kernel<<<Nn, 128, 0, stream>>>(offs, perm, src, hn, he, xsum, Nn);
    mfma_split_gemm<1, 0><<<dim3(cdiv(Nn, 128), 1), 256, 0, stream>>>(
        xsum, (const u16*)(WctH + (size_t)i * 80 * 80), (const u16*)(WctL + (size_t)i * 80 * 80),
        p_bc, (size_t)i * 80, pflag, xc, Nn, 80, 80);
    // GAT 1
    mfma_split_gemm<0, 2><<<dim3(cdiv(Nn, 128), 4), 256, 0, stream>>>(
        xc, (const u16*)(fc1tH + (size_t)i * 512 * 80), (const u16*)(fc1tL + (size_t)i * 512 * 80),
        nullptr, 0, pflag, z, Nn, 80, 512);
    attn_lr_kernel<<<cdiv(Nn * 64, 256), 256, 0, stream>>>(
        z, p_al1, p_ar1, (size_t)i * 512, pflag, el, er, Nn);
    edge_softmax_kernel<<<cdiv(Ne, 256), 256, 0, stream>>>(src, dst, el, er, exe, Ne);
    sden_kernel<<<cdiv(Nn * 4, 256), 256, 0, stream>>>(offs, perm, exe, sden, Nn);
    gat_gather_kernel<<<cdiv(Nn * 64, 256), 256, 0, stream>>>(
        offs, perm, src, z, exe, sden, p_gb1, (size_t)i * 512, pflag, hb, Nn);
    mfma_split_gemm<0, 0><<<dim3(cdiv(Nn, 128), 1), 256, 0, stream>>>(
        hb, (const u16*)(Wl1tH + (size_t)i * 128 * 512), (const u16*)(Wl1tL + (size_t)i * 128 * 512),
        p_bl1, (size_t)i * 128, pflag, x1, Nn, 512, 128);
    // GAT 2
    mfma_split_gemm<0, 2><<<dim3(cdiv(Nn, 128), 4), 256, 0, stream>>>(
        x1, (const u16*)(fc2tH + (size_t)i * 512 * 128), (const u16*)(fc2tL + (size_t)i * 512 * 128),
        nullptr, 0, pflag, z, Nn, 128, 512);
    attn_lr_kernel<<<cdiv(Nn * 64, 256), 256, 0, stream>>>(
        z, p_al2, p_ar2, (size_t)i * 512, pflag, el, er, Nn);
    edge_softmax_kernel<<<cdiv(Ne, 256), 256, 0, stream>>>(src, dst, el, er, exe, Ne);
    sden_kernel<<<cdiv(Nn * 4, 256), 256, 0, stream>>>(offs, perm, exe, sden, Nn);
    gat_gather_kernel<<<cdiv(Nn * 64, 256), 256, 0, stream>>>(
        offs, perm, src, z, exe, sden, p_gb2, (size_t)i * 512, pflag, hb, Nn);
    mfma_split_gemm<0, 0><<<dim3(cdiv(Nn, 128), 1), 256, 0, stream>>>(
        hb, (const u16*)(Wl2tH + (size_t)i * 128 * 512), (const u16*)(Wl2tL + (size_t)i * 128 * 512),
        p_bl2, (size_t)i * 128, pflag, x2, Nn, 512, 128);
    // readout
    wnode_kernel<<<cdiv(Nn * 64, 256), 256, 0, stream>>>(
        x2, p_ws_w, (size_t)i * 128, p_ws_b, (size_t)i, pflag, wn, Nn);
    readout_kernel<<<Bg, 128, 0, stream>>>(x2, wn, gid, Nn, hsb, hmb);
    pool_kernel<<<Bg, 128, 0, stream>>>(
        hsb, hmb, p_Wp, (size_t)i * 256 * 128, p_bp, (size_t)i * 128, pflag, bout_i);
  };

  run_branch(0, srcA, dstA, gidA, nfA, efA, bout);
  run_branch(1, srcB, dstB, gidB, nfB, efB, bout + (size_t)Bg * 128);

  head_kernel<<<Bg, 128, 0, stream>>>(bout, bout + (size_t)Bg * 128, Wo1, bo1, Wo2, bo2,
                                      pflag, fflag, d_out);
}

// Round 7
// 1689.398 us; speedup vs baseline: 1.8294x; 1.1032x over previous
//
#include <hip/hip_runtime.h>
#include <hip/hip_bf16.h>
#include <hip/hip_fp16.h>

typedef __hip_bfloat16 bf16;
typedef unsigned short u16;
typedef __attribute__((ext_vector_type(8))) short short8;
typedef __attribute__((ext_vector_type(4))) float floatx4;

static constexpr int Nn = 25000;   // nodes
static constexpr int Ne = 400000;  // edges
static constexpr int Bg = 64;      // graphs

// flag-aware element load: b16 ? bf16[i] : f32[i]
__device__ __forceinline__ float ldf(const void* p, size_t i, bool b16) {
  return b16 ? __bfloat162float(((const bf16*)p)[i]) : ((const float*)p)[i];
}

// ---------------- dtype detection ----------------
__global__ void detect_kernel(const u16* a, int n, const u16* b, int m, int* flags) {
  __shared__ int c0, c1;
  if (threadIdx.x == 0) { c0 = 0; c1 = 0; }
  __syncthreads();
  int t = threadIdx.x;
  int l0 = 0, l1 = 0;
  for (int i = t; i < n; i += 256) {
    unsigned e = (a[i] >> 7) & 0xFF;
    if (e >= 140) l0++;
  }
  for (int i = t; i < m; i += 256) {
    unsigned e = (b[i] >> 7) & 0xFF;
    if (e >= 140) l1++;
  }
  atomicAdd(&c0, l0);
  atomicAdd(&c1, l1);
  __syncthreads();
  if (t == 0) {
    flags[0] = (c0 < n / 16) ? 1 : 0;  // 1 = features are bf16
    flags[1] = (c1 < m / 16) ? 1 : 0;  // 1 = params are bf16
  }
}

// ------- fused transpose+convert: all big weights -> hi/lo bf16 planes [N][K] ----------
struct TC { const void* W; size_t off; bf16* H; bf16* L; int K; int N; int start; };
struct TCAll { TC t[10]; int total; };

__global__ void transconv_all_kernel(TCAll a, const int* __restrict__ pflag) {
  const bool pb = (*pflag != 0);
  int idx = blockIdx.x * 256 + threadIdx.x;
  if (idx >= a.total) return;
  int s = 0;
  while (s + 1 < 10 && idx >= a.t[s + 1].start) s++;
  int li = idx - a.t[s].start;
  int K = a.t[s].K, N = a.t[s].N;
  int k = li / N, n = li - k * N;
  float w = ldf(a.t[s].W, a.t[s].off + li, pb);
  bf16 h = __float2bfloat16(w);
  a.t[s].H[(size_t)n * K + k] = h;
  a.t[s].L[(size_t)n * K + k] = __float2bfloat16(w - __bfloat162float(h));
}

// ---------------- split-precision MFMA GEMM: C = act(A[M,K]f32 @ B^T + bias) -----------
// A and B both decomposed into bf16 hi+lo planes; 3 MFMAs per fragment.
// OUT: 0 -> fp32 C, 2 -> fp16 C. ACT: 0 none, 1 relu.
template <int ACT, int OUT>
__global__ __launch_bounds__(256) void mfma_split_gemm(const float* __restrict__ A,
                                                       const u16* __restrict__ Bh,
                                                       const u16* __restrict__ Bl,
                                                       const void* __restrict__ bias, size_t boff,
                                                       const int* __restrict__ pflag,
                                                       void* __restrict__ C,
                                                       int M, int K, int N) {
  __shared__ short Ahs[128 * 40];
  __shared__ short Als[128 * 40];
  __shared__ short Bhs[128 * 40];
  __shared__ short Bls[128 * 40];
  const int bm = blockIdx.x * 128;
  const int bn = blockIdx.y * 128;
  const int tid = threadIdx.x;
  const int lane = tid & 63;
  const int wave = tid >> 6;
  const int wm = wave >> 1, wn = wave & 1;
  const int lm = lane & 15, quad = lane >> 4;
  const int srow = tid >> 1;   // 0..127
  const int sseg = tid & 1;    // 16-elem half of the 32-k chunk
  floatx4 acc[4][4] = {};
  for (int k0 = 0; k0 < K; k0 += 32) {
    bool kv = (k0 + sseg * 16) < K;
    // ---- stage A tile [128 x 32] fp32 -> hi/lo bf16 planes ----
    {
      int gr = bm + srow;
      short hv[16], lv[16];
      if (gr < M && kv) {
        const float4* gp = (const float4*)(A + (size_t)gr * K + k0 + sseg * 16);
#pragma unroll
        for (int v = 0; v < 4; v++) {
          float4 f = gp[v];
          float xs[4] = {f.x, f.y, f.z, f.w};
#pragma unroll
          for (int q = 0; q < 4; q++) {
            bf16 h = __float2bfloat16(xs[q]);
            float hf = __bfloat162float(h);
            bf16 l = __float2bfloat16(xs[q] - hf);
            hv[v * 4 + q] = *(short*)&h;
            lv[v * 4 + q] = *(short*)&l;
          }
        }
      } else {
#pragma unroll
        for (int q = 0; q < 16; q++) { hv[q] = 0; lv[q] = 0; }
      }
      *(short8*)&Ahs[srow * 40 + sseg * 16] = *(short8*)&hv[0];
      *(short8*)&Ahs[srow * 40 + sseg * 16 + 8] = *(short8*)&hv[8];
      *(short8*)&Als[srow * 40 + sseg * 16] = *(short8*)&lv[0];
      *(short8*)&Als[srow * 40 + sseg * 16 + 8] = *(short8*)&lv[8];
    }
    // ---- stage B hi/lo tiles (rows of B* = output cols) ----
    {
      int gc = bn + srow;
      short8 h0 = {}, h1 = {}, l0 = {}, l1 = {};
      if (gc < N && kv) {
        const short8* hp = (const short8*)(Bh + (size_t)gc * K + k0 + sseg * 16);
        const short8* lp = (const short8*)(Bl + (size_t)gc * K + k0 + sseg * 16);
        h0 = hp[0]; h1 = hp[1];
        l0 = lp[0]; l1 = lp[1];
      }
      *(short8*)&Bhs[srow * 40 + sseg * 16] = h0;
      *(short8*)&Bhs[srow * 40 + sseg * 16 + 8] = h1;
      *(short8*)&Bls[srow * 40 + sseg * 16] = l0;
      *(short8*)&Bls[srow * 40 + sseg * 16 + 8] = l1;
    }
    __syncthreads();
    short8 ah[4], al[4], bh[4], bl[4];
#pragma unroll
    for (int f = 0; f < 4; f++) {
      ah[f] = *(const short8*)&Ahs[(wm * 64 + f * 16 + lm) * 40 + quad * 8];
      al[f] = *(const short8*)&Als[(wm * 64 + f * 16 + lm) * 40 + quad * 8];
      bh[f] = *(const short8*)&Bhs[(wn * 64 + f * 16 + lm) * 40 + quad * 8];
      bl[f] = *(const short8*)&Bls[(wn * 64 + f * 16 + lm) * 40 + quad * 8];
    }
#pragma unroll
    for (int i = 0; i < 4; i++)
#pragma unroll
      for (int j = 0; j < 4; j++) {
        acc[i][j] = __builtin_amdgcn_mfma_f32_16x16x32_bf16(al[i], bh[j], acc[i][j], 0, 0, 0);
        acc[i][j] = __builtin_amdgcn_mfma_f32_16x16x32_bf16(ah[i], bl[j], acc[i][j], 0, 0, 0);
        acc[i][j] = __builtin_amdgcn_mfma_f32_16x16x32_bf16(ah[i], bh[j], acc[i][j], 0, 0, 0);
      }
    __syncthreads();
  }
  // ---- epilogue: C/D layout col=lane&15, row=quad*4+reg ----
  const bool pb = (*pflag != 0);
#pragma unroll
  for (int i = 0; i < 4; i++) {
#pragma unroll
    for (int j = 0; j < 4; j++) {
      int col = bn + wn * 64 + j * 16 + lm;
      if (col >= N) continue;
#pragma unroll
      for (int r = 0; r < 4; r++) {
        int row = bm + wm * 64 + i * 16 + quad * 4 + r;
        if (row >= M) continue;
        float v = acc[i][j][r];
        if (bias) v += ldf(bias, boff + col, pb);
        if (ACT == 1) v = v > 0.f ? v : 0.f;
        if (OUT == 0)
          ((float*)C)[(size_t)row * N + col] = v;
        else
          ((__half*)C)[(size_t)row * N + col] = __float2half(v);
      }
    }
  }
}

// ---------------- input projection: hn[n][64] fp16 = nf[n]·Wn + bn ----------------
__global__ __launch_bounds__(256) void proj_nf_kernel(const void* __restrict__ nf,
                                                      const int* __restrict__ fflag,
                                                      const void* __restrict__ Wn, size_t woff,
                                                      const void* __restrict__ bn, size_t boff,
                                                      const int* __restrict__ pflag,
                                                      __half* __restrict__ hn, int N) {
  __shared__ float Ws[64 * 65];
  __shared__ float bs[64];
  __shared__ float rowbuf[4][64];
  const bool fb = (*fflag != 0), pb = (*pflag != 0);
  int t = threadIdx.x;
  for (int i = t; i < 4096; i += 256) {
    int k = i >> 6, c = i & 63;
    Ws[k * 65 + c] = ldf(Wn, woff + i, pb);
  }
  if (t < 64) bs[t] = ldf(bn, boff + t, pb);
  __syncthreads();
  int wave = t >> 6, lane = t & 63;
  int n = blockIdx.x * 4 + wave;
  if (n >= N) return;
  rowbuf[wave][lane] = ldf(nf, (size_t)n * 64 + lane, fb);
  float acc = bs[lane];
#pragma unroll 8
  for (int k = 0; k < 64; k++) acc += rowbuf[wave][k] * Ws[k * 65 + lane];
  hn[(size_t)n * 64 + lane] = __float2half(acc);
}

// ---------------- input projection: he[e][16] fp16 = ef[e]·We + be ----------------
__global__ __launch_bounds__(256) void proj_ef_kernel(const void* __restrict__ ef,
                                                      const int* __restrict__ fflag,
                                                      const void* __restrict__ We, size_t woff,
                                                      const void* __restrict__ be, size_t boff,
                                                      const int* __restrict__ pflag,
                                                      __half* __restrict__ he, int E) {
  __shared__ float Ws[16 * 17];
  __shared__ float bs[16];
  __shared__ float efs[16][17];
  const bool fb = (*fflag != 0), pb = (*pflag != 0);
  int t = threadIdx.x;
  Ws[(t >> 4) * 17 + (t & 15)] = ldf(We, woff + t, pb);
  if (t < 16) bs[t] = ldf(be, boff + t, pb);
  int el = t >> 4, k = t & 15;
  int e = blockIdx.x * 16 + el;
  float v = 0.f;
  if (e < E) v = ldf(ef, (size_t)e * 16 + k, fb);
  efs[el][k] = v;
  __syncthreads();
  if (e < E) {
    float acc = bs[k];
#pragma unroll
    for (int kk = 0; kk < 16; kk++) acc += efs[el][kk] * Ws[kk * 17 + k];
    he[(size_t)e * 16 + k] = __float2half(acc);
  }
}

// ---------------- CSR build ----------------
__global__ void count_kernel(const int* __restrict__ dst, int* __restrict__ cnt, int E) {
  int e = blockIdx.x * blockDim.x + threadIdx.x;
  if (e < E) atomicAdd(&cnt[dst[e]], 1);
}

// per-256-chunk inclusive scan + block sums
__global__ void scan1_kernel(const int* __restrict__ cnt, int* __restrict__ incl,
                             int* __restrict__ bsum, int n) {
  __shared__ int buf[256];
  int t = threadIdx.x;
  int i = blockIdx.x * 256 + t;
  int v = (i < n) ? cnt[i] : 0;
  buf[t] = v;
  __syncthreads();
  for (int d = 1; d < 256; d <<= 1) {
    int add = (t >= d) ? buf[t - d] : 0;
    __syncthreads();
    buf[t] += add;
    __syncthreads();
  }
  if (i < n) incl[i] = buf[t];
  if (t == 255) bsum[blockIdx.x] = buf[255];
}

// single-block exclusive scan over block sums (nb <= 256)
__global__ void scan2_kernel(int* __restrict__ bsum, int nb) {
  __shared__ int buf[256];
  int t = threadIdx.x;
  int v = (t < nb) ? bsum[t] : 0;
  buf[t] = v;
  __syncthreads();
  for (int d = 1; d < 256; d <<= 1) {
    int add = (t >= d) ? buf[t - d] : 0;
    __syncthreads();
    buf[t] += add;
    __syncthreads();
  }
  if (t < nb) bsum[t] = buf[t] - v;
}

// offs[i] = exclusive scan; cursor = copy; offs[n] = total
__global__ void scan3_kernel(const int* __restrict__ cnt, const int* __restrict__ incl,
                             const int* __restrict__ bsum, int* __restrict__ offs,
                             int* __restrict__ cursor, int n) {
  int i = blockIdx.x * 256 + threadIdx.x;
  if (i < n) {
    int e = incl[i] - cnt[i] + bsum[blockIdx.x];
    offs[i] = e;
    cursor[i] = e;
    if (i == n - 1) offs[n] = incl[i] + bsum[blockIdx.x];
  }
}

__global__ void fill_kernel(const int* __restrict__ dst, int* __restrict__ cursor,
                            int* __restrict__ perm, int E) {
  int e = blockIdx.x * blockDim.x + threadIdx.x;
  if (e < E) {
    int p = atomicAdd(&cursor[dst[e]], 1);
    perm[p] = e;
  }
}

// ------- sort each node's segment by edge id (LDS scratch) -> deterministic sums -------
__global__ __launch_bounds__(64) void sortseg_kernel(const int* __restrict__ off,
                                                     int* __restrict__ perm, int N) {
  __shared__ int loc[64 * 64];  // 16 KB: column t, rows i -> loc[i*64+t]
  int t = threadIdx.x;
  int n = blockIdx.x * 64 + t;
  if (n >= N) return;
  int e0 = off[n], e1 = off[n + 1];
  int d = e1 - e0;
  if (d <= 1) return;
  if (d <= 64) {
    for (int i = 0; i < d; i++) loc[i * 64 + t] = perm[e0 + i];
    for (int i = 1; i < d; i++) {
      int v = loc[i * 64 + t];
      int j = i - 1;
      while (j >= 0 && loc[j * 64 + t] > v) { loc[(j + 1) * 64 + t] = loc[j * 64 + t]; j--; }
      loc[(j + 1) * 64 + t] = v;
    }
    for (int i = 0; i < d; i++) perm[e0 + i] = loc[i * 64 + t];
  } else {
    for (int i = 0; i < d - 1; i++) {
      int mi = i;
      for (int j = i + 1; j < d; j++)
        if (perm[e0 + j] < perm[e0 + mi]) mi = j;
      int tmp = perm[e0 + i];
      perm[e0 + i] = perm[e0 + mi];
      perm[e0 + mi] = tmp;
    }
  }
}

// ---------------- EdgeGraphConv gather-sum (fp16 hn/he, fp32 out) ----------------
__global__ __launch_bounds__(128) void edgeconv_kernel(const int* __restrict__ off,
                                                       const int* __restrict__ perm,
                                                       const int* __restrict__ src,
                                                       const __half* __restrict__ hn,
                                                       const __half* __restrict__ he,
                                                       float* __restrict__ xsum, int N) {
  int n = blockIdx.x;
  int f = threadIdx.x;
  if (n >= N || f >= 80) return;
  int e0 = off[n], e1 = off[n + 1];
  float acc = 0.f;
  if (f < 64) {
    int eg = e0;
    for (; eg + 2 <= e1; eg += 2) {
      int ea = perm[eg], eb = perm[eg + 1];
      int sa = src[ea], sb = src[eb];
      float va = __half2float(hn[(size_t)sa * 64 + f]);
      float vb = __half2float(hn[(size_t)sb * 64 + f]);
      acc += va;
      acc += vb;
    }
    if (eg < e1) acc += __half2float(hn[(size_t)src[perm[eg]] * 64 + f]);
  } else {
    int c = f - 64;
    for (int eg = e0; eg < e1; eg++) acc += __half2float(he[(size_t)perm[eg] * 16 + c]);
  }
  xsum[(size_t)n * 80 + f] = acc;
}

// ---------------- attention el/er (fp16 z) ----------------
__global__ __launch_bounds__(256) void attn_lr_kernel(const __half* __restrict__ z,
                                                      const void* __restrict__ al,
                                                      const void* __restrict__ ar, size_t off,
                                                      const int* __restrict__ pflag,
                                                      float* __restrict__ el,
                                                      float* __restrict__ er, int N) {
  const bool pb = (*pflag != 0);
  int n = (blockIdx.x * blockDim.x + threadIdx.x) >> 6;
  int lane = threadIdx.x & 63;
  if (n >= N) return;
  union { uint4 q; __half s[8]; } u;
  u.q = *(const uint4*)(z + (size_t)n * 512 + lane * 8);
  float sl = 0.f, sr = 0.f;
#pragma unroll
  for (int q = 0; q < 8; q++) {
    int idx = lane * 8 + q;
    float zv = __half2float(u.s[q]);
    sl += zv * ldf(al, off + idx, pb);
    sr += zv * ldf(ar, off + idx, pb);
  }
#pragma unroll
  for (int o = 1; o < 16; o <<= 1) {
    sl += __shfl_xor(sl, o);
    sr += __shfl_xor(sr, o);
  }
  if ((lane & 15) == 0) {
    int h = lane >> 4;
    el[n * 4 + h] = sl;
    er[n * 4 + h] = sr;
  }
}

// ------- fused GAT: per-node softmax (2-pass, inline exp) + weighted gather -----------
__device__ __forceinline__ float lrelu02_exp(float v) {
  v = v > 0.f ? v : 0.2f * v;
  v = fminf(v, 60.f);
  return expf(v);
}

__global__ __launch_bounds__(256) void gat_fused_kernel(const int* __restrict__ off,
                                                        const int* __restrict__ perm,
                                                        const int* __restrict__ src,
                                                        const __half* __restrict__ z,
                                                        const float* __restrict__ el,
                                                        const float* __restrict__ er,
                                                        const void* __restrict__ gb, size_t goff,
                                                        const int* __restrict__ pflag,
                                                        float* __restrict__ out, int N) {
  const bool pb = (*pflag != 0);
  int n = (blockIdx.x * blockDim.x + threadIdx.x) >> 6;
  int lane = threadIdx.x & 63;
  if (n >= N) return;
  int h = lane >> 4;
  int e0 = off[n], e1 = off[n + 1];
  float ern = er[n * 4 + h];
  // pass 1: denominator (in perm order, deterministic)
  float s = 0.f;
  for (int eg = e0; eg < e1; eg++) {
    int e = perm[eg];
    int sv = src[e];
    s += lrelu02_exp(el[sv * 4 + h] + ern);
  }
  float sinv = s > 0.f ? 1.f / s : 0.f;
  // pass 2: weighted gather
  float acc[8] = {0.f, 0.f, 0.f, 0.f, 0.f, 0.f, 0.f, 0.f};
  int eg = e0;
  for (; eg + 2 <= e1; eg += 2) {
    int ea = perm[eg], eb = perm[eg + 1];
    int sa = src[ea], sb = src[eb];
    float aa = lrelu02_exp(el[sa * 4 + h] + ern) * sinv;
    float ab = lrelu02_exp(el[sb * 4 + h] + ern) * sinv;
    union { uint4 q; __half s[8]; } ua, ub;
    ua.q = *(const uint4*)(z + (size_t)sa * 512 + lane * 8);
    ub.q = *(const uint4*)(z + (size_t)sb * 512 + lane * 8);
#pragma unroll
    for (int q = 0; q < 8; q++) acc[q] += aa * __half2float(ua.s[q]);
#pragma unroll
    for (int q = 0; q < 8; q++) acc[q] += ab * __half2float(ub.s[q]);
  }
  if (eg < e1) {
    int ea = perm[eg];
    int sa = src[ea];
    float aa = lrelu02_exp(el[sa * 4 + h] + ern) * sinv;
    union { uint4 q; __half s[8]; } ua;
    ua.q = *(const uint4*)(z + (size_t)sa * 512 + lane * 8);
#pragma unroll
    for (int q = 0; q < 8; q++) acc[q] += aa * __half2float(ua.s[q]);
  }
  float* o = out + (size_t)n * 512 + lane * 8;
#pragma unroll
  for (int q = 0; q < 8; q++) {
    float v = acc[q] + ldf(gb, goff + lane * 8 + q, pb);
    o[q] = v > 0.f ? v : 0.01f * v;
  }
}

// ---------------- node weight ----------------
__global__ __launch_bounds__(256) void wnode_kernel(const float* __restrict__ x,
                                                    const void* __restrict__ wsw, size_t woff,
                                                    const void* __restrict__ wsb, size_t boff,
                                                    const int* __restrict__ pflag,
                                                    float* __restrict__ w, int N) {
  const bool pb = (*pflag != 0);
  int n = (blockIdx.x * blockDim.x + threadIdx.x) >> 6;
  int lane = threadIdx.x & 63;
  if (n >= N) return;
  float s = x[(size_t)n * 128 + lane] * ldf(wsw, woff + lane, pb) +
            x[(size_t)n * 128 + 64 + lane] * ldf(wsw, woff + 64 + lane, pb);
#pragma unroll
  for (int o = 1; o < 64; o <<= 1) s += __shfl_xor(s, o);
  if (lane == 0) {
    float t = s + ldf(wsb, boff, pb);
    t = fmaxf(fminf(t, 60.f), -60.f);
    w[n] = 1.f / (1.f + expf(-t));
  }
}

__device__ __forceinline__ int lower_bound_dev(const int* a, int n, int v) {
  int lo = 0, hi = n;
  while (lo < hi) {
    int mid = (lo + hi) >> 1;
    if (a[mid] < v) lo = mid + 1; else hi = mid;
  }
  return lo;
}

// ---------------- readout phase 1: 16 chunks per graph, double partials ----------------
__global__ __launch_bounds__(128) void readout_p1_kernel(const float* __restrict__ x,
                                                         const float* __restrict__ w,
                                                         const int* __restrict__ gid, int N,
                                                         double* __restrict__ psum,
                                                         float* __restrict__ pmax) {
  int g = blockIdx.x >> 4;
  int c = blockIdx.x & 15;
  int d = threadIdx.x;
  __shared__ int ss, se;
  if (d == 0) {
    ss = lower_bound_dev(gid, N, g);
    se = lower_bound_dev(gid, N, g + 1);
  }
  __syncthreads();
  int len = se - ss;
  int a = ss + (int)(((long)len * c) >> 4);
  int b = ss + (int)(((long)len * (c + 1)) >> 4);
  double s = 0.0;
  float m = -1e30f;
  for (int n = a; n < b; n++) {
    float v = x[(size_t)n * 128 + d];
    s += (double)v * (double)w[n];
    m = fmaxf(m, v);
  }
  psum[(size_t)blockIdx.x * 128 + d] = s;
  pmax[(size_t)blockIdx.x * 128 + d] = m;
}

// ---------------- readout phase 2: combine 16 partials ----------------
__global__ __launch_bounds__(128) void readout_p2_kernel(const double* __restrict__ psum,
                                                         const float* __restrict__ pmax,
                                                         float* __restrict__ hs,
                                                         float* __restrict__ hm) {
  int g = blockIdx.x, d = threadIdx.x;
  double s = 0.0;
  float m = -1e30f;
#pragma unroll
  for (int c = 0; c < 16; c++) {
    s += psum[(size_t)(g * 16 + c) * 128 + d];
    m = fmaxf(m, pmax[(size_t)(g * 16 + c) * 128 + d]);
  }
  hs[g * 128 + d] = (float)s;
  hm[g * 128 + d] = m;
}

// ---------------- pool linear ----------------
__global__ __launch_bounds__(128) void pool_kernel(const float* __restrict__ hs,
                                                   const float* __restrict__ hm,
                                                   const void* __restrict__ Wp, size_t woff,
                                                   const void* __restrict__ bp, size_t boff,
                                                   const int* __restrict__ pflag,
                                                   float* __restrict__ bout) {
  const bool pb = (*pflag != 0);
  int g = blockIdx.x, j = threadIdx.x;
  __shared__ float hg[256];
  hg[j] = hs[g * 128 + j];
  hg[128 + j] = hm[g * 128 + j];
  __syncthreads();
  double acc = (double)ldf(bp, boff + j, pb);
  for (int k = 0; k < 256; k++) acc += (double)hg[k] * (double)ldf(Wp, woff + (size_t)k * 128 + j, pb);
  bout[g * 128 + j] = (float)acc;
}

// ---------------- final head ----------------
__global__ __launch_bounds__(128) void head_kernel(const float* __restrict__ bA,
                                                   const float* __restrict__ bB,
                                                   const void* __restrict__ Wo1,
                                                   const void* __restrict__ bo1,
                                                   const void* __restrict__ Wo2,
                                                   const void* __restrict__ bo2,
                                                   const int* __restrict__ pflag,
                                                   const int* __restrict__ oflag,
                                                   void* __restrict__ out) {
  const bool pb = (*pflag != 0);
  int g = blockIdx.x, j = threadIdx.x;
  __shared__ float zr[256];
  __shared__ double t[128];
  zr[j] = bA[g * 128 + j];
  zr[128 + j] = bB[g * 128 + j];
  __syncthreads();
  double acc = (double)ldf(bo1, j, pb);
  for (int k = 0; k < 256; k++) acc += (double)zr[k] * (double)ldf(Wo1, (size_t)k * 128 + j, pb);
  if (acc < 0.0) acc *= 0.01;
  t[j] = acc * (double)ldf(Wo2, j, pb);
  __syncthreads();
  for (int sdt = 64; sdt > 0; sdt >>= 1) {
    if (j < sdt) t[j] += t[j + sdt];
    __syncthreads();
  }
  if (j == 0) {
    float v = (float)(t[0] + (double)ldf(bo2, 0, pb));
    if (*oflag) ((bf16*)out)[g] = __float2bfloat16(v);
    else ((float*)out)[g] = v;
  }
}

extern "C" void kernel_launch(void* const* d_in, const int* in_sizes, int n_in,
                              void* d_out, int out_size, void* d_ws, size_t ws_size,
                              hipStream_t stream) {
  const int* srcA = (const int*)d_in[0];
  const int* dstA = (const int*)d_in[1];
  const int* gidA = (const int*)d_in[2];
  const void* nfA = d_in[3];
  const void* efA = d_in[4];
  const int* srcB = (const int*)d_in[5];
  const int* dstB = (const int*)d_in[6];
  const int* gidB = (const int*)d_in[7];
  const void* nfB = d_in[8];
  const void* efB = d_in[9];
  const void* p_Wn = d_in[10];
  const void* p_bn = d_in[11];
  const void* p_We = d_in[12];
  const void* p_be = d_in[13];
  const void* p_Wc = d_in[14];
  const void* p_bc = d_in[15];
  const void* p_fc1 = d_in[16];
  const void* p_al1 = d_in[17];
  const void* p_ar1 = d_in[18];
  const void* p_gb1 = d_in[19];
  const void* p_Wl1 = d_in[20];
  const void* p_bl1 = d_in[21];
  const void* p_fc2 = d_in[22];
  const void* p_al2 = d_in[23];
  const void* p_ar2 = d_in[24];
  const void* p_gb2 = d_in[25];
  const void* p_Wl2 = d_in[26];
  const void* p_bl2 = d_in[27];
  const void* p_ws_w = d_in[28];
  const void* p_ws_b = d_in[29];
  const void* p_Wp = d_in[30];
  const void* p_bp = d_in[31];
  const void* Wo1 = d_in[32];
  const void* bo1 = d_in[33];
  const void* Wo2 = d_in[34];
  const void* bo2 = d_in[35];

  // workspace carve-up
  char* wp = (char*)d_ws;
  auto alloc = [&](size_t bytes) -> char* {
    char* p = wp;
    wp += (bytes + 255) & ~(size_t)255;
    return p;
  };
  int* flags = (int*)alloc(2 * 4);
  int* cnt = (int*)alloc((size_t)Nn * 4);
  int* incl = (int*)alloc((size_t)Nn * 4);
  int* bsum = (int*)alloc(256 * 4);
  int* offs = (int*)alloc((size_t)(Nn + 1) * 4);
  int* cursor = (int*)alloc((size_t)Nn * 4);
  int* perm = (int*)alloc((size_t)Ne * 4);
  float* el = (float*)alloc((size_t)Nn * 4 * 4);
  float* er = (float*)alloc((size_t)Nn * 4 * 4);
  float* wn = (float*)alloc((size_t)Nn * 4);
  double* psum = (double*)alloc((size_t)Bg * 16 * 128 * 8);
  float* pmax = (float*)alloc((size_t)Bg * 16 * 128 * 4);
  float* hsb = (float*)alloc((size_t)Bg * 128 * 4);
  float* hmb = (float*)alloc((size_t)Bg * 128 * 4);
  float* bout = (float*)alloc((size_t)2 * Bg * 128 * 4);
  // transposed bf16 hi/lo weight planes
  bf16* WctH = (bf16*)alloc((size_t)2 * 80 * 80 * 2);
  bf16* WctL = (bf16*)alloc((size_t)2 * 80 * 80 * 2);
  bf16* fc1tH = (bf16*)alloc((size_t)2 * 512 * 80 * 2);
  bf16* fc1tL = (bf16*)alloc((size_t)2 * 512 * 80 * 2);
  bf16* Wl1tH = (bf16*)alloc((size_t)2 * 128 * 512 * 2);
  bf16* Wl1tL = (bf16*)alloc((size_t)2 * 128 * 512 * 2);
  bf16* fc2tH = (bf16*)alloc((size_t)2 * 512 * 128 * 2);
  bf16* fc2tL = (bf16*)alloc((size_t)2 * 512 * 128 * 2);
  bf16* Wl2tH = (bf16*)alloc((size_t)2 * 128 * 512 * 2);
  bf16* Wl2tL = (bf16*)alloc((size_t)2 * 128 * 512 * 2);
  char* zreg = alloc((size_t)Nn * 512 * 4);           // hn/he/xsum early -> z(half) -> x2(f32)
  float* hb = (float*)alloc((size_t)Nn * 512 * 4);    // GAT gather output
  float* xcx1 = (float*)alloc((size_t)Nn * 128 * 4);  // xc early, x1 later
  // overlays inside zreg
  __half* hn = (__half*)zreg;                                             // Nn*64 fp16
  __half* he = (__half*)(zreg + (size_t)Nn * 64 * 2);                     // Ne*16 fp16
  float* xsum = (float*)(zreg + (size_t)Nn * 64 * 2 + (size_t)Ne * 16 * 2);  // Nn*80 f32
  __half* z = (__half*)zreg;                                              // Nn*512 fp16
  float* x2 = (float*)zreg;                                               // Nn*128 f32
  float* xc = xcx1;
  float* x1 = xcx1;

  auto cdiv = [](int a, int b) { return (a + b - 1) / b; };

  detect_kernel<<<1, 256, 0, stream>>>((const u16*)nfA, 8192, (const u16*)p_fc1, 8192, flags);
  int* fflag = &flags[0];
  int* pflag = &flags[1];

  // prep: fused transpose+convert of all hi/lo weight planes (both branches)
  {
    TCAll tc;
    int segK[5] = {80, 80, 512, 128, 512};
    int segN[5] = {80, 512, 128, 512, 128};
    const void* segW[5] = {p_Wc, p_fc1, p_Wl1, p_fc2, p_Wl2};
    bf16* segH[5] = {WctH, fc1tH, Wl1tH, fc2tH, Wl2tH};
    bf16* segL[5] = {WctL, fc1tL, Wl1tL, fc2tL, Wl2tL};
    int start = 0, s = 0;
    for (int i = 0; i < 2; i++)
      for (int m = 0; m < 5; m++) {
        int sz = segK[m] * segN[m];
        tc.t[s].W = segW[m];
        tc.t[s].off = (size_t)i * sz;
        tc.t[s].H = segH[m] + (size_t)i * sz;
        tc.t[s].L = segL[m] + (size_t)i * sz;
        tc.t[s].K = segK[m];
        tc.t[s].N = segN[m];
        tc.t[s].start = start;
        start += sz;
        s++;
      }
    tc.total = start;
    transconv_all_kernel<<<cdiv(start, 256), 256, 0, stream>>>(tc, pflag);
  }

  const int nb = cdiv(Nn, 256);  // 98 scan blocks

  auto run_branch = [&](int i, const int* src, const int* dst, const int* gid,
                        const void* nf, const void* ef, float* bout_i) {
    // CSR by dst (deterministic after sortseg)
    hipMemsetAsync(cnt, 0, (size_t)Nn * 4, stream);
    count_kernel<<<cdiv(Ne, 256), 256, 0, stream>>>(dst, cnt, Ne);
    scan1_kernel<<<nb, 256, 0, stream>>>(cnt, incl, bsum, Nn);
    scan2_kernel<<<1, 256, 0, stream>>>(bsum, nb);
    scan3_kernel<<<nb, 256, 0, stream>>>(cnt, incl, bsum, offs, cursor, Nn);
    fill_kernel<<<cdiv(Ne, 256), 256, 0, stream>>>(dst, cursor, perm, Ne);
    sortseg_kernel<<<cdiv(Nn, 64), 64, 0, stream>>>(offs, perm, Nn);
    // input projections
    proj_nf_kernel<<<cdiv(Nn, 4), 256, 0, stream>>>(
        nf, fflag, p_Wn, (size_t)i * 64 * 64, p_bn, (size_t)i * 64, pflag, hn, Nn);
    proj_ef_kernel<<<cdiv(Ne, 16), 256, 0, stream>>>(
        ef, fflag, p_We, (size_t)i * 16 * 16, p_be, (size_t)i * 16, pflag, he, Ne);
    // EdgeGraphConv
    edgeconv_kernel<<<Nn, 128, 0, stream>>>(offs, perm, src, hn, he, xsum, Nn);
    mfma_split_gemm<1, 0><<<dim3(cdiv(Nn, 128), 1), 256, 0, stream>>>(
        xsum, (const u16*)(WctH + (size_t)i * 80 * 80), (const u16*)(WctL + (size_t)i * 80 * 80),
        p_bc, (size_t)i * 80, pflag, xc, Nn, 80, 80);
    // GAT 1
    mfma_split_gemm<0, 2><<<dim3(cdiv(Nn, 128), 4), 256, 0, stream>>>(
        xc, (const u16*)(fc1tH + (size_t)i * 512 * 80), (const u16*)(fc1tL + (size_t)i * 512 * 80),
        nullptr, 0, pflag, z, Nn, 80, 512);
    attn_lr_kernel<<<cdiv(Nn * 64, 256), 256, 0, stream>>>(
        z, p_al1, p_ar1, (size_t)i * 512, pflag, el, er, Nn);
    gat_fused_kernel<<<cdiv(Nn * 64, 256), 256, 0, stream>>>(
        offs, perm, src, z, el, er, p_gb1, (size_t)i * 512, pflag, hb, Nn);
    mfma_split_gemm<0, 0><<<dim3(cdiv(Nn, 128), 1), 256, 0, stream>>>(
        hb, (const u16*)(Wl1tH + (size_t)i * 128 * 512), (const u16*)(Wl1tL + (size_t)i * 128 * 512),
        p_bl1, (size_t)i * 128, pflag, x1, Nn, 512, 128);
    // GAT 2
    mfma_split_gemm<0, 2><<<dim3(cdiv(Nn, 128), 4), 256, 0, stream>>>(
        x1, (const u16*)(fc2tH + (size_t)i * 512 * 128), (const u16*)(fc2tL + (size_t)i * 512 * 128),
        nullptr, 0, pflag, z, Nn, 128, 512);
    attn_lr_kernel<<<cdiv(Nn * 64, 256), 256, 0, stream>>>(
        z, p_al2, p_ar2, (size_t)i * 512, pflag, el, er, Nn);
    gat_fused_kernel<<<cdiv(Nn * 64, 256), 256, 0, stream>>>(
        offs, perm, src, z, el, er, p_gb2, (size_t)i * 512, pflag, hb, Nn);
    mfma_split_gemm<0, 0><<<dim3(cdiv(Nn, 128), 1), 256, 0, stream>>>(
        hb, (const u16*)(Wl2tH + (size_t)i * 128 * 512), (const u16*)(Wl2tL + (size_t)i * 128 * 512),
        p_bl2, (size_t)i * 128, pflag, x2, Nn, 512, 128);
    // readout
    wnode_kernel<<<cdiv(Nn * 64, 256), 256, 0, stream>>>(
        x2, p_ws_w, (size_t)i * 128, p_ws_b, (size_t)i, pflag, wn, Nn);
    readout_p1_kernel<<<Bg * 16, 128, 0, stream>>>(x2, wn, gid, Nn, psum, pmax);
    readout_p2_kernel<<<Bg, 128, 0, stream>>>(psum, pmax, hsb, hmb);
    pool_kernel<<<Bg, 128, 0, stream>>>(
        hsb, hmb, p_Wp, (size_t)i * 256 * 128, p_bp, (size_t)i * 128, pflag, bout_i);
  };

  run_branch(0, srcA, dstA, gidA, nfA, efA, bout);
  run_branch(1, srcB, dstB, gidB, nfB, efB, bout + (size_t)Bg * 128);

  head_kernel<<<Bg, 128, 0, stream>>>(bout, bout + (size_t)Bg * 128, Wo1, bo1, Wo2, bo2,
                                      pflag, fflag, d_out);
}

// Round 8
// 1453.562 us; speedup vs baseline: 2.1263x; 1.1622x over previous
//
#include <hip/hip_runtime.h>
#include <hip/hip_bf16.h>
#include <hip/hip_fp16.h>

typedef __hip_bfloat16 bf16;
typedef unsigned short u16;
typedef __attribute__((ext_vector_type(8))) short short8;
typedef __attribute__((ext_vector_type(4))) float floatx4;

static constexpr int Nn = 25000;   // nodes
static constexpr int Ne = 400000;  // edges
static constexpr int Bg = 64;      // graphs

// flag-aware element load: b16 ? bf16[i] : f32[i]
__device__ __forceinline__ float ldf(const void* p, size_t i, bool b16) {
  return b16 ? __bfloat162float(((const bf16*)p)[i]) : ((const float*)p)[i];
}

// ---------------- dtype detection ----------------
__global__ void detect_kernel(const u16* a, int n, const u16* b, int m, int* flags) {
  __shared__ int c0, c1;
  if (threadIdx.x == 0) { c0 = 0; c1 = 0; }
  __syncthreads();
  int t = threadIdx.x;
  int l0 = 0, l1 = 0;
  for (int i = t; i < n; i += 256) {
    unsigned e = (a[i] >> 7) & 0xFF;
    if (e >= 140) l0++;
  }
  for (int i = t; i < m; i += 256) {
    unsigned e = (b[i] >> 7) & 0xFF;
    if (e >= 140) l1++;
  }
  atomicAdd(&c0, l0);
  atomicAdd(&c1, l1);
  __syncthreads();
  if (t == 0) {
    flags[0] = (c0 < n / 16) ? 1 : 0;  // 1 = features are bf16
    flags[1] = (c1 < m / 16) ? 1 : 0;  // 1 = params are bf16
  }
}

// ------- fused transpose+convert: all big weights -> hi/lo bf16 planes [N][K] ----------
struct TC { const void* W; size_t off; bf16* H; bf16* L; int K; int N; int start; };
struct TCAll { TC t[10]; int total; };

__global__ void transconv_all_kernel(TCAll a, const int* __restrict__ pflag) {
  const bool pb = (*pflag != 0);
  int idx = blockIdx.x * 256 + threadIdx.x;
  if (idx >= a.total) return;
  int s = 0;
  while (s + 1 < 10 && idx >= a.t[s + 1].start) s++;
  int li = idx - a.t[s].start;
  int K = a.t[s].K, N = a.t[s].N;
  int k = li / N, n = li - k * N;
  float w = ldf(a.t[s].W, a.t[s].off + li, pb);
  bf16 h = __float2bfloat16(w);
  a.t[s].H[(size_t)n * K + k] = h;
  a.t[s].L[(size_t)n * K + k] = __float2bfloat16(w - __bfloat162float(h));
}

// ---------------- split-precision MFMA GEMM: C = act(A[M,K]f32 @ B^T + bias) -----------
// A and B both decomposed into bf16 hi+lo planes; 3 MFMAs per fragment.
// OUT: 0 -> fp32 C, 2 -> fp16 C. ACT: 0 none, 1 relu.
template <int ACT, int OUT>
__global__ __launch_bounds__(256) void mfma_split_gemm(const float* __restrict__ A,
                                                       const u16* __restrict__ Bh,
                                                       const u16* __restrict__ Bl,
                                                       const void* __restrict__ bias, size_t boff,
                                                       const int* __restrict__ pflag,
                                                       void* __restrict__ C,
                                                       int M, int K, int N) {
  __shared__ short Ahs[128 * 40];
  __shared__ short Als[128 * 40];
  __shared__ short Bhs[128 * 40];
  __shared__ short Bls[128 * 40];
  const int bm = blockIdx.x * 128;
  const int bn = blockIdx.y * 128;
  const int tid = threadIdx.x;
  const int lane = tid & 63;
  const int wave = tid >> 6;
  const int wm = wave >> 1, wn = wave & 1;
  const int lm = lane & 15, quad = lane >> 4;
  const int srow = tid >> 1;   // 0..127
  const int sseg = tid & 1;    // 16-elem half of the 32-k chunk
  floatx4 acc[4][4] = {};
  for (int k0 = 0; k0 < K; k0 += 32) {
    bool kv = (k0 + sseg * 16) < K;
    // ---- stage A tile [128 x 32] fp32 -> hi/lo bf16 planes ----
    {
      int gr = bm + srow;
      short hv[16], lv[16];
      if (gr < M && kv) {
        const float4* gp = (const float4*)(A + (size_t)gr * K + k0 + sseg * 16);
#pragma unroll
        for (int v = 0; v < 4; v++) {
          float4 f = gp[v];
          float xs[4] = {f.x, f.y, f.z, f.w};
#pragma unroll
          for (int q = 0; q < 4; q++) {
            bf16 h = __float2bfloat16(xs[q]);
            float hf = __bfloat162float(h);
            bf16 l = __float2bfloat16(xs[q] - hf);
            hv[v * 4 + q] = *(short*)&h;
            lv[v * 4 + q] = *(short*)&l;
          }
        }
      } else {
#pragma unroll
        for (int q = 0; q < 16; q++) { hv[q] = 0; lv[q] = 0; }
      }
      *(short8*)&Ahs[srow * 40 + sseg * 16] = *(short8*)&hv[0];
      *(short8*)&Ahs[srow * 40 + sseg * 16 + 8] = *(short8*)&hv[8];
      *(short8*)&Als[srow * 40 + sseg * 16] = *(short8*)&lv[0];
      *(short8*)&Als[srow * 40 + sseg * 16 + 8] = *(short8*)&lv[8];
    }
    // ---- stage B hi/lo tiles (rows of B* = output cols) ----
    {
      int gc = bn + srow;
      short8 h0 = {}, h1 = {}, l0 = {}, l1 = {};
      if (gc < N && kv) {
        const short8* hp = (const short8*)(Bh + (size_t)gc * K + k0 + sseg * 16);
        const short8* lp = (const short8*)(Bl + (size_t)gc * K + k0 + sseg * 16);
        h0 = hp[0]; h1 = hp[1];
        l0 = lp[0]; l1 = lp[1];
      }
      *(short8*)&Bhs[srow * 40 + sseg * 16] = h0;
      *(short8*)&Bhs[srow * 40 + sseg * 16 + 8] = h1;
      *(short8*)&Bls[srow * 40 + sseg * 16] = l0;
      *(short8*)&Bls[srow * 40 + sseg * 16 + 8] = l1;
    }
    __syncthreads();
    short8 ah[4], al[4], bh[4], bl[4];
#pragma unroll
    for (int f = 0; f < 4; f++) {
      ah[f] = *(const short8*)&Ahs[(wm * 64 + f * 16 + lm) * 40 + quad * 8];
      al[f] = *(const short8*)&Als[(wm * 64 + f * 16 + lm) * 40 + quad * 8];
      bh[f] = *(const short8*)&Bhs[(wn * 64 + f * 16 + lm) * 40 + quad * 8];
      bl[f] = *(const short8*)&Bls[(wn * 64 + f * 16 + lm) * 40 + quad * 8];
    }
#pragma unroll
    for (int i = 0; i < 4; i++)
#pragma unroll
      for (int j = 0; j < 4; j++) {
        acc[i][j] = __builtin_amdgcn_mfma_f32_16x16x32_bf16(al[i], bh[j], acc[i][j], 0, 0, 0);
        acc[i][j] = __builtin_amdgcn_mfma_f32_16x16x32_bf16(ah[i], bl[j], acc[i][j], 0, 0, 0);
        acc[i][j] = __builtin_amdgcn_mfma_f32_16x16x32_bf16(ah[i], bh[j], acc[i][j], 0, 0, 0);
      }
    __syncthreads();
  }
  // ---- epilogue: C/D layout col=lane&15, row=quad*4+reg ----
  const bool pb = (*pflag != 0);
#pragma unroll
  for (int i = 0; i < 4; i++) {
#pragma unroll
    for (int j = 0; j < 4; j++) {
      int col = bn + wn * 64 + j * 16 + lm;
      if (col >= N) continue;
#pragma unroll
      for (int r = 0; r < 4; r++) {
        int row = bm + wm * 64 + i * 16 + quad * 4 + r;
        if (row >= M) continue;
        float v = acc[i][j][r];
        if (bias) v += ldf(bias, boff + col, pb);
        if (ACT == 1) v = v > 0.f ? v : 0.f;
        if (OUT == 0)
          ((float*)C)[(size_t)row * N + col] = v;
        else
          ((__half*)C)[(size_t)row * N + col] = __float2half(v);
      }
    }
  }
}

// ---------------- input projection (both branches): hn[n][64] fp16 ----------------
__global__ __launch_bounds__(256) void proj_nf_kernel(const void* __restrict__ nfA,
                                                      const void* __restrict__ nfB,
                                                      const int* __restrict__ fflag,
                                                      const void* __restrict__ Wn,
                                                      const void* __restrict__ bn,
                                                      const int* __restrict__ pflag,
                                                      __half* __restrict__ hn, int N) {
  __shared__ float Ws[64 * 65];
  __shared__ float bs[64];
  __shared__ float rowbuf[4][64];
  const bool fb = (*fflag != 0), pb = (*pflag != 0);
  const int b = blockIdx.y;
  const void* nf = b ? nfB : nfA;
  size_t woff = (size_t)b * 64 * 64, boff = (size_t)b * 64;
  int t = threadIdx.x;
  for (int i = t; i < 4096; i += 256) {
    int k = i >> 6, c = i & 63;
    Ws[k * 65 + c] = ldf(Wn, woff + i, pb);
  }
  if (t < 64) bs[t] = ldf(bn, boff + t, pb);
  __syncthreads();
  int wave = t >> 6, lane = t & 63;
  int n = blockIdx.x * 4 + wave;
  if (n >= N) return;
  rowbuf[wave][lane] = ldf(nf, (size_t)n * 64 + lane, fb);
  float acc = bs[lane];
#pragma unroll 8
  for (int k = 0; k < 64; k++) acc += rowbuf[wave][k] * Ws[k * 65 + lane];
  hn[(size_t)b * N * 64 + (size_t)n * 64 + lane] = __float2half(acc);
}

// ---------------- input projection (both branches): he[e][16] fp16 ----------------
__global__ __launch_bounds__(256) void proj_ef_kernel(const void* __restrict__ efA,
                                                      const void* __restrict__ efB,
                                                      const int* __restrict__ fflag,
                                                      const void* __restrict__ We,
                                                      const void* __restrict__ be,
                                                      const int* __restrict__ pflag,
                                                      __half* __restrict__ he, int E) {
  __shared__ float Ws[16 * 17];
  __shared__ float bs[16];
  __shared__ float efs[16][17];
  const bool fb = (*fflag != 0), pb = (*pflag != 0);
  const int b = blockIdx.y;
  const void* ef = b ? efB : efA;
  size_t woff = (size_t)b * 256, boff = (size_t)b * 16;
  int t = threadIdx.x;
  Ws[(t >> 4) * 17 + (t & 15)] = ldf(We, woff + t, pb);
  if (t < 16) bs[t] = ldf(be, boff + t, pb);
  int el = t >> 4, k = t & 15;
  int e = blockIdx.x * 16 + el;
  float v = 0.f;
  if (e < E) v = ldf(ef, (size_t)e * 16 + k, fb);
  efs[el][k] = v;
  __syncthreads();
  if (e < E) {
    float acc = bs[k];
#pragma unroll
    for (int kk = 0; kk < 16; kk++) acc += efs[el][kk] * Ws[kk * 17 + k];
    he[(size_t)b * E * 16 + (size_t)e * 16 + k] = __float2half(acc);
  }
}

// ---------------- CSR build (both branches) ----------------
__global__ void count_kernel(const int* __restrict__ dA, const int* __restrict__ dB,
                             int* __restrict__ cnt, int E, int N) {
  int b = blockIdx.y;
  const int* dst = b ? dB : dA;
  int e = blockIdx.x * 256 + threadIdx.x;
  if (e < E) atomicAdd(&cnt[b * N + dst[e]], 1);
}

__global__ void scan1_kernel(const int* __restrict__ cnt, int* __restrict__ incl,
                             int* __restrict__ bsum, int n) {
  __shared__ int buf[256];
  int b = blockIdx.y;
  int t = threadIdx.x;
  int i = blockIdx.x * 256 + t;
  int v = (i < n) ? cnt[b * n + i] : 0;
  buf[t] = v;
  __syncthreads();
  for (int d = 1; d < 256; d <<= 1) {
    int add = (t >= d) ? buf[t - d] : 0;
    __syncthreads();
    buf[t] += add;
    __syncthreads();
  }
  if (i < n) incl[b * n + i] = buf[t];
  if (t == 255) bsum[b * 256 + blockIdx.x] = buf[255];
}

__global__ void scan2_kernel(int* __restrict__ bsum, int nb) {
  __shared__ int buf[256];
  int b = blockIdx.x;
  int t = threadIdx.x;
  int v = (t < nb) ? bsum[b * 256 + t] : 0;
  buf[t] = v;
  __syncthreads();
  for (int d = 1; d < 256; d <<= 1) {
    int add = (t >= d) ? buf[t - d] : 0;
    __syncthreads();
    buf[t] += add;
    __syncthreads();
  }
  if (t < nb) bsum[b * 256 + t] = buf[t] - v;
}

__global__ void scan3_kernel(const int* __restrict__ cnt, const int* __restrict__ incl,
                             const int* __restrict__ bsum, int* __restrict__ offs,
                             int* __restrict__ cursor, int n) {
  int b = blockIdx.y;
  int i = blockIdx.x * 256 + threadIdx.x;
  if (i < n) {
    int e = incl[b * n + i] - cnt[b * n + i] + bsum[b * 256 + blockIdx.x];
    offs[b * (n + 1) + i] = e;
    cursor[b * n + i] = e;
    if (i == n - 1) offs[b * (n + 1) + n] = incl[b * n + i] + bsum[b * 256 + blockIdx.x];
  }
}

__global__ void fill_kernel(const int* __restrict__ dA, const int* __restrict__ dB,
                            int* __restrict__ cursor, int* __restrict__ perm, int E, int N) {
  int b = blockIdx.y;
  const int* dst = b ? dB : dA;
  int e = blockIdx.x * 256 + threadIdx.x;
  if (e < E) {
    int p = atomicAdd(&cursor[b * N + dst[e]], 1);
    perm[(size_t)b * E + p] = e;
  }
}

// ------- sort each node's segment by edge id (LDS scratch), both branches -------------
__global__ __launch_bounds__(64) void sortseg_kernel(const int* __restrict__ off,
                                                     int* __restrict__ perm, int N, int E) {
  __shared__ int loc[64 * 64];  // 16 KB
  int b = blockIdx.y;
  const int* offb = off + b * (N + 1);
  int* permb = perm + (size_t)b * E;
  int t = threadIdx.x;
  int n = blockIdx.x * 64 + t;
  if (n >= N) return;
  int e0 = offb[n], e1 = offb[n + 1];
  int d = e1 - e0;
  if (d <= 1) return;
  if (d <= 64) {
    for (int i = 0; i < d; i++) loc[i * 64 + t] = permb[e0 + i];
    for (int i = 1; i < d; i++) {
      int v = loc[i * 64 + t];
      int j = i - 1;
      while (j >= 0 && loc[j * 64 + t] > v) { loc[(j + 1) * 64 + t] = loc[j * 64 + t]; j--; }
      loc[(j + 1) * 64 + t] = v;
    }
    for (int i = 0; i < d; i++) permb[e0 + i] = loc[i * 64 + t];
  } else {
    for (int i = 0; i < d - 1; i++) {
      int mi = i;
      for (int j = i + 1; j < d; j++)
        if (permb[e0 + j] < permb[e0 + mi]) mi = j;
      int tmp = permb[e0 + i];
      permb[e0 + i] = permb[e0 + mi];
      permb[e0 + mi] = tmp;
    }
  }
}

// ---------------- src_csr[eg] = src[perm[eg]] (both branches) ----------------
__global__ void srccsr_kernel(const int* __restrict__ sA, const int* __restrict__ sB,
                              const int* __restrict__ perm, int* __restrict__ src_csr, int E) {
  int b = blockIdx.y;
  const int* src = b ? sB : sA;
  int i = blockIdx.x * 256 + threadIdx.x;
  if (i < E) src_csr[(size_t)b * E + i] = src[perm[(size_t)b * E + i]];
}

// ---------------- EdgeGraphConv gather-sum (both branches) ----------------
__global__ __launch_bounds__(128) void edgeconv_kernel(const int* __restrict__ off,
                                                       const int* __restrict__ perm,
                                                       const int* __restrict__ src_csr,
                                                       const __half* __restrict__ hn,
                                                       const __half* __restrict__ he,
                                                       float* __restrict__ xsum, int N, int E) {
  int b = blockIdx.y;
  const int* offb = off + b * (N + 1);
  const int* permb = perm + (size_t)b * E;
  const int* scb = src_csr + (size_t)b * E;
  const __half* hnb = hn + (size_t)b * N * 64;
  const __half* heb = he + (size_t)b * E * 16;
  int n = blockIdx.x;
  int f = threadIdx.x;
  if (n >= N || f >= 80) return;
  int e0 = offb[n], e1 = offb[n + 1];
  float acc = 0.f;
  if (f < 64) {
    int eg = e0;
    for (; eg + 2 <= e1; eg += 2) {
      int sa = scb[eg], sb = scb[eg + 1];
      float va = __half2float(hnb[(size_t)sa * 64 + f]);
      float vb = __half2float(hnb[(size_t)sb * 64 + f]);
      acc += va;
      acc += vb;
    }
    if (eg < e1) acc += __half2float(hnb[(size_t)scb[eg] * 64 + f]);
  } else {
    int c = f - 64;
    for (int eg = e0; eg < e1; eg++) acc += __half2float(heb[(size_t)permb[eg] * 16 + c]);
  }
  xsum[(size_t)b * N * 80 + (size_t)n * 80 + f] = acc;
}

// ---------------- attention el/er (fp16 z) ----------------
__global__ __launch_bounds__(256) void attn_lr_kernel(const __half* __restrict__ z,
                                                      const void* __restrict__ al,
                                                      const void* __restrict__ ar, size_t off,
                                                      const int* __restrict__ pflag,
                                                      float* __restrict__ el,
                                                      float* __restrict__ er, int N) {
  const bool pb = (*pflag != 0);
  int n = (blockIdx.x * blockDim.x + threadIdx.x) >> 6;
  int lane = threadIdx.x & 63;
  if (n >= N) return;
  union { uint4 q; __half s[8]; } u;
  u.q = *(const uint4*)(z + (size_t)n * 512 + lane * 8);
  float sl = 0.f, sr = 0.f;
#pragma unroll
  for (int q = 0; q < 8; q++) {
    int idx = lane * 8 + q;
    float zv = __half2float(u.s[q]);
    sl += zv * ldf(al, off + idx, pb);
    sr += zv * ldf(ar, off + idx, pb);
  }
#pragma unroll
  for (int o = 1; o < 16; o <<= 1) {
    sl += __shfl_xor(sl, o);
    sr += __shfl_xor(sr, o);
  }
  if ((lane & 15) == 0) {
    int h = lane >> 4;
    el[n * 4 + h] = sl;
    er[n * 4 + h] = sr;
  }
}

// ------- per-node attn exp in CSR order + denominator (deterministic) -----------------
__global__ void attn_sden_kernel(const int* __restrict__ off, const int* __restrict__ src_csr,
                                 const float* __restrict__ el, const float* __restrict__ er,
                                 float* __restrict__ ecsr, float* __restrict__ sden, int N) {
  int idx = blockIdx.x * 256 + threadIdx.x;
  int n = idx >> 2, h = idx & 3;
  if (n >= N) return;
  int e0 = off[n], e1 = off[n + 1];
  float ern = er[n * 4 + h];
  float s = 0.f;
  for (int eg = e0; eg < e1; eg++) {
    float v = el[src_csr[eg] * 4 + h] + ern;
    v = v > 0.f ? v : 0.2f * v;
    v = fminf(v, 60.f);
    float ev = expf(v);
    ecsr[eg * 4 + h] = ev;
    s += ev;
  }
  sden[n * 4 + h] = s;
}

// ---------------- lean GAT gather: sequential ecsr/src_csr, random z rows -------------
__global__ __launch_bounds__(256) void gat_gather_kernel(const int* __restrict__ off,
                                                         const int* __restrict__ src_csr,
                                                         const __half* __restrict__ z,
                                                         const float* __restrict__ ecsr,
                                                         const float* __restrict__ sden,
                                                         const void* __restrict__ gb, size_t goff,
                                                         const int* __restrict__ pflag,
                                                         float* __restrict__ out, int N) {
  const bool pb = (*pflag != 0);
  int n = (blockIdx.x * blockDim.x + threadIdx.x) >> 6;
  int lane = threadIdx.x & 63;
  if (n >= N) return;
  int h = lane >> 4;
  float sd = sden[n * 4 + h];
  float sinv = sd > 0.f ? 1.f / sd : 0.f;
  float acc[8] = {0.f, 0.f, 0.f, 0.f, 0.f, 0.f, 0.f, 0.f};
  int e0 = off[n], e1 = off[n + 1];
  int eg = e0;
  for (; eg + 4 <= e1; eg += 4) {
    int s0 = src_csr[eg], s1 = src_csr[eg + 1], s2 = src_csr[eg + 2], s3 = src_csr[eg + 3];
    float a0 = ecsr[(eg) * 4 + h] * sinv;
    float a1 = ecsr[(eg + 1) * 4 + h] * sinv;
    float a2 = ecsr[(eg + 2) * 4 + h] * sinv;
    float a3 = ecsr[(eg + 3) * 4 + h] * sinv;
    union { uint4 q; __half s[8]; } u0, u1, u2, u3;
    u0.q = *(const uint4*)(z + (size_t)s0 * 512 + lane * 8);
    u1.q = *(const uint4*)(z + (size_t)s1 * 512 + lane * 8);
    u2.q = *(const uint4*)(z + (size_t)s2 * 512 + lane * 8);
    u3.q = *(const uint4*)(z + (size_t)s3 * 512 + lane * 8);
#pragma unroll
    for (int q = 0; q < 8; q++) acc[q] += a0 * __half2float(u0.s[q]);
#pragma unroll
    for (int q = 0; q < 8; q++) acc[q] += a1 * __half2float(u1.s[q]);
#pragma unroll
    for (int q = 0; q < 8; q++) acc[q] += a2 * __half2float(u2.s[q]);
#pragma unroll
    for (int q = 0; q < 8; q++) acc[q] += a3 * __half2float(u3.s[q]);
  }
  for (; eg < e1; eg++) {
    int s0 = src_csr[eg];
    float a0 = ecsr[eg * 4 + h] * sinv;
    union { uint4 q; __half s[8]; } u0;
    u0.q = *(const uint4*)(z + (size_t)s0 * 512 + lane * 8);
#pragma unroll
    for (int q = 0; q < 8; q++) acc[q] += a0 * __half2float(u0.s[q]);
  }
  float* o = out + (size_t)n * 512 + lane * 8;
#pragma unroll
  for (int q = 0; q < 8; q++) {
    float v = acc[q] + ldf(gb, goff + lane * 8 + q, pb);
    o[q] = v > 0.f ? v : 0.01f * v;
  }
}

// ---------------- node weight ----------------
__global__ __launch_bounds__(256) void wnode_kernel(const float* __restrict__ x,
                                                    const void* __restrict__ wsw, size_t woff,
                                                    const void* __restrict__ wsb, size_t boff,
                                                    const int* __restrict__ pflag,
                                                    float* __restrict__ w, int N) {
  const bool pb = (*pflag != 0);
  int n = (blockIdx.x * blockDim.x + threadIdx.x) >> 6;
  int lane = threadIdx.x & 63;
  if (n >= N) return;
  float s = x[(size_t)n * 128 + lane] * ldf(wsw, woff + lane, pb) +
            x[(size_t)n * 128 + 64 + lane] * ldf(wsw, woff + 64 + lane, pb);
#pragma unroll
  for (int o = 1; o < 64; o <<= 1) s += __shfl_xor(s, o);
  if (lane == 0) {
    float t = s + ldf(wsb, boff, pb);
    t = fmaxf(fminf(t, 60.f), -60.f);
    w[n] = 1.f / (1.f + expf(-t));
  }
}

__device__ __forceinline__ int lower_bound_dev(const int* a, int n, int v) {
  int lo = 0, hi = n;
  while (lo < hi) {
    int mid = (lo + hi) >> 1;
    if (a[mid] < v) lo = mid + 1; else hi = mid;
  }
  return lo;
}

// ---------------- readout phase 1: 16 chunks per graph, double partials ----------------
__global__ __launch_bounds__(128) void readout_p1_kernel(const float* __restrict__ x,
                                                         const float* __restrict__ w,
                                                         const int* __restrict__ gid, int N,
                                                         double* __restrict__ psum,
                                                         float* __restrict__ pmax) {
  int g = blockIdx.x >> 4;
  int c = blockIdx.x & 15;
  int d = threadIdx.x;
  __shared__ int ss, se;
  if (d == 0) {
    ss = lower_bound_dev(gid, N, g);
    se = lower_bound_dev(gid, N, g + 1);
  }
  __syncthreads();
  int len = se - ss;
  int a = ss + (int)(((long)len * c) >> 4);
  int b = ss + (int)(((long)len * (c + 1)) >> 4);
  double s = 0.0;
  float m = -1e30f;
  for (int n = a; n < b; n++) {
    float v = x[(size_t)n * 128 + d];
    s += (double)v * (double)w[n];
    m = fmaxf(m, v);
  }
  psum[(size_t)blockIdx.x * 128 + d] = s;
  pmax[(size_t)blockIdx.x * 128 + d] = m;
}

// ---------------- readout phase 2: combine 16 partials ----------------
__global__ __launch_bounds__(128) void readout_p2_kernel(const double* __restrict__ psum,
                                                         const float* __restrict__ pmax,
                                                         float* __restrict__ hs,
                                                         float* __restrict__ hm) {
  int g = blockIdx.x, d = threadIdx.x;
  double s = 0.0;
  float m = -1e30f;
#pragma unroll
  for (int c = 0; c < 16; c++) {
    s += psum[(size_t)(g * 16 + c) * 128 + d];
    m = fmaxf(m, pmax[(size_t)(g * 16 + c) * 128 + d]);
  }
  hs[g * 128 + d] = (float)s;
  hm[g * 128 + d] = m;
}

// ---------------- pool linear ----------------
__global__ __launch_bounds__(128) void pool_kernel(const float* __restrict__ hs,
                                                   const float* __restrict__ hm,
                                                   const void* __restrict__ Wp, size_t woff,
                                                   const void* __restrict__ bp, size_t boff,
                                                   const int* __restrict__ pflag,
                                                   float* __restrict__ bout) {
  const bool pb = (*pflag != 0);
  int g = blockIdx.x, j = threadIdx.x;
  __shared__ float hg[256];
  hg[j] = hs[g * 128 + j];
  hg[128 + j] = hm[g * 128 + j];
  __syncthreads();
  double acc = (double)ldf(bp, boff + j, pb);
  for (int k = 0; k < 256; k++) acc += (double)hg[k] * (double)ldf(Wp, woff + (size_t)k * 128 + j, pb);
  bout[g * 128 + j] = (float)acc;
}

// ---------------- final head ----------------
__global__ __launch_bounds__(128) void head_kernel(const float* __restrict__ bA,
                                                   const float* __restrict__ bB,
                                                   const void* __restrict__ Wo1,
                                                   const void* __restrict__ bo1,
                                                   const void* __restrict__ Wo2,
                                                   const void* __restrict__ bo2,
                                                   const int* __restrict__ pflag,
                                                   const int* __restrict__ oflag,
                                                   void* __restrict__ out) {
  const bool pb = (*pflag != 0);
  int g = blockIdx.x, j = threadIdx.x;
  __shared__ float zr[256];
  __shared__ double t[128];
  zr[j] = bA[g * 128 + j];
  zr[128 + j] = bB[g * 128 + j];
  __syncthreads();
  double acc = (double)ldf(bo1, j, pb);
  for (int k = 0; k < 256; k++) acc += (double)zr[k] * (double)ldf(Wo1, (size_t)k * 128 + j, pb);
  if (acc < 0.0) acc *= 0.01;
  t[j] = acc * (double)ldf(Wo2, j, pb);
  __syncthreads();
  for (int sdt = 64; sdt > 0; sdt >>= 1) {
    if (j < sdt) t[j] += t[j + sdt];
    __syncthreads();
  }
  if (j == 0) {
    float v = (float)(t[0] + (double)ldf(bo2, 0, pb));
    if (*oflag) ((bf16*)out)[g] = __float2bfloat16(v);
    else ((float*)out)[g] = v;
  }
}

extern "C" void kernel_launch(void* const* d_in, const int* in_sizes, int n_in,
                              void* d_out, int out_size, void* d_ws, size_t ws_size,
                              hipStream_t stream) {
  const int* srcA = (const int*)d_in[0];
  const int* dstA = (const int*)d_in[1];
  const int* gidA = (const int*)d_in[2];
  const void* nfA = d_in[3];
  const void* efA = d_in[4];
  const int* srcB = (const int*)d_in[5];
  const int* dstB = (const int*)d_in[6];
  const int* gidB = (const int*)d_in[7];
  const void* nfB = d_in[8];
  const void* efB = d_in[9];
  const void* p_Wn = d_in[10];
  const void* p_bn = d_in[11];
  const void* p_We = d_in[12];
  const void* p_be = d_in[13];
  const void* p_Wc = d_in[14];
  const void* p_bc = d_in[15];
  const void* p_fc1 = d_in[16];
  const void* p_al1 = d_in[17];
  const void* p_ar1 = d_in[18];
  const void* p_gb1 = d_in[19];
  const void* p_Wl1 = d_in[20];
  const void* p_bl1 = d_in[21];
  const void* p_fc2 = d_in[22];
  const void* p_al2 = d_in[23];
  const void* p_ar2 = d_in[24];
  const void* p_gb2 = d_in[25];
  const void* p_Wl2 = d_in[26];
  const void* p_bl2 = d_in[27];
  const void* p_ws_w = d_in[28];
  const void* p_ws_b = d_in[29];
  const void* p_Wp = d_in[30];
  const void* p_bp = d_in[31];
  const void* Wo1 = d_in[32];
  const void* bo1 = d_in[33];
  const void* Wo2 = d_in[34];
  const void* bo2 = d_in[35];

  // workspace carve-up (~155 MB)
  char* wp = (char*)d_ws;
  auto alloc = [&](size_t bytes) -> char* {
    char* p = wp;
    wp += (bytes + 255) & ~(size_t)255;
    return p;
  };
  int* flags = (int*)alloc(2 * 4);
  int* cnt = (int*)alloc((size_t)2 * Nn * 4);
  int* incl = (int*)alloc((size_t)2 * Nn * 4);
  int* bsum = (int*)alloc(2 * 256 * 4);
  int* offs = (int*)alloc((size_t)2 * (Nn + 1) * 4);
  int* cursor = (int*)alloc((size_t)2 * Nn * 4);
  int* perm = (int*)alloc((size_t)2 * Ne * 4);
  int* src_csr = (int*)alloc((size_t)2 * Ne * 4);
  float* ecsr = (float*)alloc((size_t)Ne * 4 * 4);
  float* sden = (float*)alloc((size_t)Nn * 4 * 4);
  float* el = (float*)alloc((size_t)Nn * 4 * 4);
  float* er = (float*)alloc((size_t)Nn * 4 * 4);
  float* wn = (float*)alloc((size_t)Nn * 4);
  double* psum = (double*)alloc((size_t)Bg * 16 * 128 * 8);
  float* pmax = (float*)alloc((size_t)Bg * 16 * 128 * 4);
  float* hsb = (float*)alloc((size_t)Bg * 128 * 4);
  float* hmb = (float*)alloc((size_t)Bg * 128 * 4);
  float* bout = (float*)alloc((size_t)2 * Bg * 128 * 4);
  // transposed bf16 hi/lo weight planes
  bf16* WctH = (bf16*)alloc((size_t)2 * 80 * 80 * 2);
  bf16* WctL = (bf16*)alloc((size_t)2 * 80 * 80 * 2);
  bf16* fc1tH = (bf16*)alloc((size_t)2 * 512 * 80 * 2);
  bf16* fc1tL = (bf16*)alloc((size_t)2 * 512 * 80 * 2);
  bf16* Wl1tH = (bf16*)alloc((size_t)2 * 128 * 512 * 2);
  bf16* Wl1tL = (bf16*)alloc((size_t)2 * 128 * 512 * 2);
  bf16* fc2tH = (bf16*)alloc((size_t)2 * 512 * 128 * 2);
  bf16* fc2tL = (bf16*)alloc((size_t)2 * 512 * 128 * 2);
  bf16* Wl2tH = (bf16*)alloc((size_t)2 * 128 * 512 * 2);
  bf16* Wl2tL = (bf16*)alloc((size_t)2 * 128 * 512 * 2);
  // dedicated per-branch front-end buffers
  __half* hn = (__half*)alloc((size_t)2 * Nn * 64 * 2);   // 6.4 MB
  __half* he = (__half*)alloc((size_t)2 * Ne * 16 * 2);   // 25.6 MB
  float* xsum = (float*)alloc((size_t)2 * Nn * 80 * 4);   // 16 MB
  // shared big buffers (per-branch sequential)
  char* zreg = alloc((size_t)Nn * 512 * 2);               // z fp16 25.6 MB; x2 f32 overlays
  float* hb = (float*)alloc((size_t)Nn * 512 * 4);        // 51.2 MB
  float* xcx1 = (float*)alloc((size_t)Nn * 128 * 4);      // 12.8 MB
  __half* z = (__half*)zreg;
  float* x2 = (float*)zreg;   // Nn*128 f32 = 12.8 MB, overlays z after last gather
  float* xc = xcx1;
  float* x1 = xcx1;

  auto cdiv = [](int a, int b) { return (a + b - 1) / b; };

  detect_kernel<<<1, 256, 0, stream>>>((const u16*)nfA, 8192, (const u16*)p_fc1, 8192, flags);
  int* fflag = &flags[0];
  int* pflag = &flags[1];

  // prep: fused transpose+convert of all hi/lo weight planes (both branches)
  {
    TCAll tc;
    int segK[5] = {80, 80, 512, 128, 512};
    int segN[5] = {80, 512, 128, 512, 128};
    const void* segW[5] = {p_Wc, p_fc1, p_Wl1, p_fc2, p_Wl2};
    bf16* segH[5] = {WctH, fc1tH, Wl1tH, fc2tH, Wl2tH};
    bf16* segL[5] = {WctL, fc1tL, Wl1tL, fc2tL, Wl2tL};
    int start = 0, s = 0;
    for (int i = 0; i < 2; i++)
      for (int m = 0; m < 5; m++) {
        int sz = segK[m] * segN[m];
        tc.t[s].W = segW[m];
        tc.t[s].off = (size_t)i * sz;
        tc.t[s].H = segH[m] + (size_t)i * sz;
        tc.t[s].L = segL[m] + (size_t)i * sz;
        tc.t[s].K = segK[m];
        tc.t[s].N = segN[m];
        tc.t[s].start = start;
        start += sz;
        s++;
      }
    tc.total = start;
    transconv_all_kernel<<<cdiv(start, 256), 256, 0, stream>>>(tc, pflag);
  }

  const int nb = cdiv(Nn, 256);  // 98 scan blocks per branch

  // ---- merged front-end: CSR + projections + edgeconv for BOTH branches ----
  hipMemsetAsync(cnt, 0, (size_t)2 * Nn * 4, stream);
  count_kernel<<<dim3(cdiv(Ne, 256), 2), 256, 0, stream>>>(dstA, dstB, cnt, Ne, Nn);
  scan1_kernel<<<dim3(nb, 2), 256, 0, stream>>>(cnt, incl, bsum, Nn);
  scan2_kernel<<<2, 256, 0, stream>>>(bsum, nb);
  scan3_kernel<<<dim3(nb, 2), 256, 0, stream>>>(cnt, incl, bsum, offs, cursor, Nn);
  fill_kernel<<<dim3(cdiv(Ne, 256), 2), 256, 0, stream>>>(dstA, dstB, cursor, perm, Ne, Nn);
  sortseg_kernel<<<dim3(cdiv(Nn, 64), 2), 64, 0, stream>>>(offs, perm, Nn, Ne);
  srccsr_kernel<<<dim3(cdiv(Ne, 256), 2), 256, 0, stream>>>(srcA, srcB, perm, src_csr, Ne);
  proj_nf_kernel<<<dim3(cdiv(Nn, 4), 2), 256, 0, stream>>>(
      nfA, nfB, fflag, p_Wn, p_bn, pflag, hn, Nn);
  proj_ef_kernel<<<dim3(cdiv(Ne, 16), 2), 256, 0, stream>>>(
      efA, efB, fflag, p_We, p_be, pflag, he, Ne);
  edgeconv_kernel<<<dim3(Nn, 2), 128, 0, stream>>>(offs, perm, src_csr, hn, he, xsum, Nn, Ne);

  auto run_branch = [&](int i, const int* gid, float* bout_i) {
    const int* offb = offs + i * (Nn + 1);
    const int* scb = src_csr + (size_t)i * Ne;
    // EdgeGraphConv linear
    mfma_split_gemm<1, 0><<<dim3(cdiv(Nn, 128), 1), 256, 0, stream>>>(
        xsum + (size_t)i * Nn * 80,
        (const u16*)(WctH + (size_t)i * 80 * 80), (const u16*)(WctL + (size_t)i * 80 * 80),
        p_bc, (size_t)i * 80, pflag, xc, Nn, 80, 80);
    // GAT 1
    mfma_split_gemm<0, 2><<<dim3(cdiv(Nn, 128), 4), 256, 0, stream>>>(
        xc, (const u16*)(fc1tH + (size_t)i * 512 * 80), (const u16*)(fc1tL + (size_t)i * 512 * 80),
        nullptr, 0, pflag, z, Nn, 80, 512);
    attn_lr_kernel<<<cdiv(Nn * 64, 256), 256, 0, stream>>>(
        z, p_al1, p_ar1, (size_t)i * 512, pflag, el, er, Nn);
    attn_sden_kernel<<<cdiv(Nn * 4, 256), 256, 0, stream>>>(offb, scb, el, er, ecsr, sden, Nn);
    gat_gather_kernel<<<cdiv(Nn * 64, 256), 256, 0, stream>>>(
        offb, scb, z, ecsr, sden, p_gb1, (size_t)i * 512, pflag, hb, Nn);
    mfma_split_gemm<0, 0><<<dim3(cdiv(Nn, 128), 1), 256, 0, stream>>>(
        hb, (const u16*)(Wl1tH + (size_t)i * 128 * 512), (const u16*)(Wl1tL + (size_t)i * 128 * 512),
        p_bl1, (size_t)i * 128, pflag, x1, Nn, 512, 128);
    // GAT 2
    mfma_split_gemm<0, 2><<<dim3(cdiv(Nn, 128), 4), 256, 0, stream>>>(
        x1, (const u16*)(fc2tH + (size_t)i * 512 * 128), (const u16*)(fc2tL + (size_t)i * 512 * 128),
        nullptr, 0, pflag, z, Nn, 128, 512);
    attn_lr_kernel<<<cdiv(Nn * 64, 256), 256, 0, stream>>>(
        z, p_al2, p_ar2, (size_t)i * 512, pflag, el, er, Nn);
    attn_sden_kernel<<<cdiv(Nn * 4, 256), 256, 0, stream>>>(offb, scb, el, er, ecsr, sden, Nn);
    gat_gather_kernel<<<cdiv(Nn * 64, 256), 256, 0, stream>>>(
        offb, scb, z, ecsr, sden, p_gb2, (size_t)i * 512, pflag, hb, Nn);
    mfma_split_gemm<0, 0><<<dim3(cdiv(Nn, 128), 1), 256, 0, stream>>>(
        hb, (const u16*)(Wl2tH + (size_t)i * 128 * 512), (const u16*)(Wl2tL + (size_t)i * 128 * 512),
        p_bl2, (size_t)i * 128, pflag, x2, Nn, 512, 128);
    // readout
    wnode_kernel<<<cdiv(Nn * 64, 256), 256, 0, stream>>>(
        x2, p_ws_w, (size_t)i * 128, p_ws_b, (size_t)i, pflag, wn, Nn);
    readout_p1_kernel<<<Bg * 16, 128, 0, stream>>>(x2, wn, gid, Nn, psum, pmax);
    readout_p2_kernel<<<Bg, 128, 0, stream>>>(psum, pmax, hsb, hmb);
    pool_kernel<<<Bg, 128, 0, stream>>>(
        hsb, hmb, p_Wp, (size_t)i * 256 * 128, p_bp, (size_t)i * 128, pflag, bout_i);
  };

  run_branch(0, gidA, bout);
  run_branch(1, gidB, bout + (size_t)Bg * 128);

  head_kernel<<<Bg, 128, 0, stream>>>(bout, bout + (size_t)Bg * 128, Wo1, bo1, Wo2, bo2,
                                      pflag, fflag, d_out);
}

// Round 9
// 1298.773 us; speedup vs baseline: 2.3797x; 1.1192x over previous
//
#include <hip/hip_runtime.h>
#include <hip/hip_bf16.h>
#include <hip/hip_fp16.h>

typedef __hip_bfloat16 bf16;
typedef unsigned short u16;
typedef __attribute__((ext_vector_type(8))) short short8;
typedef __attribute__((ext_vector_type(4))) float floatx4;
typedef _Float16 half8 __attribute__((ext_vector_type(8)));

static constexpr int Nn = 25000;   // nodes
static constexpr int Ne = 400000;  // edges
static constexpr int Bg = 64;      // graphs

// flag-aware element load: b16 ? bf16[i] : f32[i]
__device__ __forceinline__ float ldf(const void* p, size_t i, bool b16) {
  return b16 ? __bfloat162float(((const bf16*)p)[i]) : ((const float*)p)[i];
}

// ---------------- dtype detection ----------------
__global__ void detect_kernel(const u16* a, int n, const u16* b, int m, int* flags) {
  __shared__ int c0, c1;
  if (threadIdx.x == 0) { c0 = 0; c1 = 0; }
  __syncthreads();
  int t = threadIdx.x;
  int l0 = 0, l1 = 0;
  for (int i = t; i < n; i += 256) {
    unsigned e = (a[i] >> 7) & 0xFF;
    if (e >= 140) l0++;
  }
  for (int i = t; i < m; i += 256) {
    unsigned e = (b[i] >> 7) & 0xFF;
    if (e >= 140) l1++;
  }
  atomicAdd(&c0, l0);
  atomicAdd(&c1, l1);
  __syncthreads();
  if (t == 0) {
    flags[0] = (c0 < n / 16) ? 1 : 0;  // 1 = features are bf16
    flags[1] = (c1 < m / 16) ? 1 : 0;  // 1 = params are bf16
  }
}

// ------- fused transpose+convert: all big weights -> fp16 plane [N][K] ----------------
struct TC { const void* W; size_t off; __half* H; int K; int N; int start; };
struct TCAll { TC t[10]; int total; };

__global__ void transconv_all_kernel(TCAll a, const int* __restrict__ pflag) {
  const bool pb = (*pflag != 0);
  int idx = blockIdx.x * 256 + threadIdx.x;
  if (idx >= a.total) return;
  int s = 0;
  while (s + 1 < 10 && idx >= a.t[s + 1].start) s++;
  int li = idx - a.t[s].start;
  int K = a.t[s].K, N = a.t[s].N;
  int k = li / N, n = li - k * N;
  float w = ldf(a.t[s].W, a.t[s].off + li, pb);
  a.t[s].H[(size_t)n * K + k] = __float2half(w);
}

// ---------------- fp16 MFMA GEMM: C = act(A[M,K]h @ Bt[N,K]h^T + bias) ----------------
// Single MFMA pass. OUT: 0 -> fp32 C, 2 -> fp16 C. ACT: 0 none, 1 relu.
template <int ACT, int OUT>
__global__ __launch_bounds__(256) void mfma_f16_gemm(const __half* __restrict__ A,
                                                     const __half* __restrict__ Bt,
                                                     const void* __restrict__ bias, size_t boff,
                                                     const int* __restrict__ pflag,
                                                     void* __restrict__ C,
                                                     int M, int K, int N) {
  __shared__ short As[128 * 40];
  __shared__ short Bs[128 * 40];
  const int bm = blockIdx.x * 128;
  const int bn = blockIdx.y * 128;
  const int tid = threadIdx.x;
  const int lane = tid & 63;
  const int wave = tid >> 6;
  const int wm = wave >> 1, wn = wave & 1;
  const int lm = lane & 15, quad = lane >> 4;
  const int srow = tid >> 1;   // 0..127
  const int sseg = tid & 1;    // 16-elem half of the 32-k chunk
  floatx4 acc[4][4] = {};
  for (int k0 = 0; k0 < K; k0 += 32) {
    bool kv = (k0 + sseg * 16) < K;
    // ---- stage A tile [128 x 32] fp16 ----
    {
      int gr = bm + srow;
      short8 a0 = {}, a1 = {};
      if (gr < M && kv) {
        const short8* gp = (const short8*)(A + (size_t)gr * K + k0 + sseg * 16);
        a0 = gp[0];
        a1 = gp[1];
      }
      *(short8*)&As[srow * 40 + sseg * 16] = a0;
      *(short8*)&As[srow * 40 + sseg * 16 + 8] = a1;
    }
    // ---- stage B tile (rows of Bt = output cols) ----
    {
      int gc = bn + srow;
      short8 b0 = {}, b1 = {};
      if (gc < N && kv) {
        const short8* gp = (const short8*)(Bt + (size_t)gc * K + k0 + sseg * 16);
        b0 = gp[0];
        b1 = gp[1];
      }
      *(short8*)&Bs[srow * 40 + sseg * 16] = b0;
      *(short8*)&Bs[srow * 40 + sseg * 16 + 8] = b1;
    }
    __syncthreads();
    half8 af[4], bfv[4];
#pragma unroll
    for (int f = 0; f < 4; f++) {
      af[f] = *(const half8*)&As[(wm * 64 + f * 16 + lm) * 40 + quad * 8];
      bfv[f] = *(const half8*)&Bs[(wn * 64 + f * 16 + lm) * 40 + quad * 8];
    }
#pragma unroll
    for (int i = 0; i < 4; i++)
#pragma unroll
      for (int j = 0; j < 4; j++)
        acc[i][j] = __builtin_amdgcn_mfma_f32_16x16x32_f16(af[i], bfv[j], acc[i][j], 0, 0, 0);
    __syncthreads();
  }
  // ---- epilogue: C/D layout col=lane&15, row=quad*4+reg ----
  const bool pb = (*pflag != 0);
#pragma unroll
  for (int i = 0; i < 4; i++) {
#pragma unroll
    for (int j = 0; j < 4; j++) {
      int col = bn + wn * 64 + j * 16 + lm;
      if (col >= N) continue;
#pragma unroll
      for (int r = 0; r < 4; r++) {
        int row = bm + wm * 64 + i * 16 + quad * 4 + r;
        if (row >= M) continue;
        float v = acc[i][j][r];
        if (bias) v += ldf(bias, boff + col, pb);
        if (ACT == 1) v = v > 0.f ? v : 0.f;
        if (OUT == 0)
          ((float*)C)[(size_t)row * N + col] = v;
        else
          ((__half*)C)[(size_t)row * N + col] = __float2half(v);
      }
    }
  }
}

// ---------------- input projection (both branches): hn[n][64] fp16 ----------------
__global__ __launch_bounds__(256) void proj_nf_kernel(const void* __restrict__ nfA,
                                                      const void* __restrict__ nfB,
                                                      const int* __restrict__ fflag,
                                                      const void* __restrict__ Wn,
                                                      const void* __restrict__ bn,
                                                      const int* __restrict__ pflag,
                                                      __half* __restrict__ hn, int N) {
  __shared__ float Ws[64 * 65];
  __shared__ float bs[64];
  __shared__ float rowbuf[4][64];
  const bool fb = (*fflag != 0), pb = (*pflag != 0);
  const int b = blockIdx.y;
  const void* nf = b ? nfB : nfA;
  size_t woff = (size_t)b * 64 * 64, boff = (size_t)b * 64;
  int t = threadIdx.x;
  for (int i = t; i < 4096; i += 256) {
    int k = i >> 6, c = i & 63;
    Ws[k * 65 + c] = ldf(Wn, woff + i, pb);
  }
  if (t < 64) bs[t] = ldf(bn, boff + t, pb);
  __syncthreads();
  int wave = t >> 6, lane = t & 63;
  int n = blockIdx.x * 4 + wave;
  if (n >= N) return;
  rowbuf[wave][lane] = ldf(nf, (size_t)n * 64 + lane, fb);
  float acc = bs[lane];
#pragma unroll 8
  for (int k = 0; k < 64; k++) acc += rowbuf[wave][k] * Ws[k * 65 + lane];
  hn[(size_t)b * N * 64 + (size_t)n * 64 + lane] = __float2half(acc);
}

// ---------------- input projection (both branches): he[e][16] fp16 ----------------
__global__ __launch_bounds__(256) void proj_ef_kernel(const void* __restrict__ efA,
                                                      const void* __restrict__ efB,
                                                      const int* __restrict__ fflag,
                                                      const void* __restrict__ We,
                                                      const void* __restrict__ be,
                                                      const int* __restrict__ pflag,
                                                      __half* __restrict__ he, int E) {
  __shared__ float Ws[16 * 17];
  __shared__ float bs[16];
  __shared__ float efs[16][17];
  const bool fb = (*fflag != 0), pb = (*pflag != 0);
  const int b = blockIdx.y;
  const void* ef = b ? efB : efA;
  size_t woff = (size_t)b * 256, boff = (size_t)b * 16;
  int t = threadIdx.x;
  Ws[(t >> 4) * 17 + (t & 15)] = ldf(We, woff + t, pb);
  if (t < 16) bs[t] = ldf(be, boff + t, pb);
  int el = t >> 4, k = t & 15;
  int e = blockIdx.x * 16 + el;
  float v = 0.f;
  if (e < E) v = ldf(ef, (size_t)e * 16 + k, fb);
  efs[el][k] = v;
  __syncthreads();
  if (e < E) {
    float acc = bs[k];
#pragma unroll
    for (int kk = 0; kk < 16; kk++) acc += efs[el][kk] * Ws[kk * 17 + k];
    he[(size_t)b * E * 16 + (size_t)e * 16 + k] = __float2half(acc);
  }
}

// ---------------- CSR build (both branches) ----------------
__global__ void count_kernel(const int* __restrict__ dA, const int* __restrict__ dB,
                             int* __restrict__ cnt, int E, int N) {
  int b = blockIdx.y;
  const int* dst = b ? dB : dA;
  int e = blockIdx.x * 256 + threadIdx.x;
  if (e < E) atomicAdd(&cnt[b * N + dst[e]], 1);
}

__global__ void scan1_kernel(const int* __restrict__ cnt, int* __restrict__ incl,
                             int* __restrict__ bsum, int n) {
  __shared__ int buf[256];
  int b = blockIdx.y;
  int t = threadIdx.x;
  int i = blockIdx.x * 256 + t;
  int v = (i < n) ? cnt[b * n + i] : 0;
  buf[t] = v;
  __syncthreads();
  for (int d = 1; d < 256; d <<= 1) {
    int add = (t >= d) ? buf[t - d] : 0;
    __syncthreads();
    buf[t] += add;
    __syncthreads();
  }
  if (i < n) incl[b * n + i] = buf[t];
  if (t == 255) bsum[b * 256 + blockIdx.x] = buf[255];
}

__global__ void scan2_kernel(int* __restrict__ bsum, int nb) {
  __shared__ int buf[256];
  int b = blockIdx.x;
  int t = threadIdx.x;
  int v = (t < nb) ? bsum[b * 256 + t] : 0;
  buf[t] = v;
  __syncthreads();
  for (int d = 1; d < 256; d <<= 1) {
    int add = (t >= d) ? buf[t - d] : 0;
    __syncthreads();
    buf[t] += add;
    __syncthreads();
  }
  if (t < nb) bsum[b * 256 + t] = buf[t] - v;
}

__global__ void scan3_kernel(const int* __restrict__ cnt, const int* __restrict__ incl,
                             const int* __restrict__ bsum, int* __restrict__ offs,
                             int* __restrict__ cursor, int n) {
  int b = blockIdx.y;
  int i = blockIdx.x * 256 + threadIdx.x;
  if (i < n) {
    int e = incl[b * n + i] - cnt[b * n + i] + bsum[b * 256 + blockIdx.x];
    offs[b * (n + 1) + i] = e;
    cursor[b * n + i] = e;
    if (i == n - 1) offs[b * (n + 1) + n] = incl[b * n + i] + bsum[b * 256 + blockIdx.x];
  }
}

__global__ void fill_kernel(const int* __restrict__ dA, const int* __restrict__ dB,
                            int* __restrict__ cursor, int* __restrict__ perm, int E, int N) {
  int b = blockIdx.y;
  const int* dst = b ? dB : dA;
  int e = blockIdx.x * 256 + threadIdx.x;
  if (e < E) {
    int p = atomicAdd(&cursor[b * N + dst[e]], 1);
    perm[(size_t)b * E + p] = e;
  }
}

// ------- sort each node's segment by edge id (LDS scratch), both branches -------------
__global__ __launch_bounds__(64) void sortseg_kernel(const int* __restrict__ off,
                                                     int* __restrict__ perm, int N, int E) {
  __shared__ int loc[64 * 64];  // 16 KB
  int b = blockIdx.y;
  const int* offb = off + b * (N + 1);
  int* permb = perm + (size_t)b * E;
  int t = threadIdx.x;
  int n = blockIdx.x * 64 + t;
  if (n >= N) return;
  int e0 = offb[n], e1 = offb[n + 1];
  int d = e1 - e0;
  if (d <= 1) return;
  if (d <= 64) {
    for (int i = 0; i < d; i++) loc[i * 64 + t] = permb[e0 + i];
    for (int i = 1; i < d; i++) {
      int v = loc[i * 64 + t];
      int j = i - 1;
      while (j >= 0 && loc[j * 64 + t] > v) { loc[(j + 1) * 64 + t] = loc[j * 64 + t]; j--; }
      loc[(j + 1) * 64 + t] = v;
    }
    for (int i = 0; i < d; i++) permb[e0 + i] = loc[i * 64 + t];
  } else {
    for (int i = 0; i < d - 1; i++) {
      int mi = i;
      for (int j = i + 1; j < d; j++)
        if (permb[e0 + j] < permb[e0 + mi]) mi = j;
      int tmp = permb[e0 + i];
      permb[e0 + i] = permb[e0 + mi];
      permb[e0 + mi] = tmp;
    }
  }
}

// ---------------- src_csr[eg] = src[perm[eg]] (both branches) ----------------
__global__ void srccsr_kernel(const int* __restrict__ sA, const int* __restrict__ sB,
                              const int* __restrict__ perm, int* __restrict__ src_csr, int E) {
  int b = blockIdx.y;
  const int* src = b ? sB : sA;
  int i = blockIdx.x * 256 + threadIdx.x;
  if (i < E) src_csr[(size_t)b * E + i] = src[perm[(size_t)b * E + i]];
}

// ---------------- EdgeGraphConv gather-sum (both branches), fp16 out ----------------
__global__ __launch_bounds__(128) void edgeconv_kernel(const int* __restrict__ off,
                                                       const int* __restrict__ perm,
                                                       const int* __restrict__ src_csr,
                                                       const __half* __restrict__ hn,
                                                       const __half* __restrict__ he,
                                                       __half* __restrict__ xsum, int N, int E) {
  int b = blockIdx.y;
  const int* offb = off + b * (N + 1);
  const int* permb = perm + (size_t)b * E;
  const int* scb = src_csr + (size_t)b * E;
  const __half* hnb = hn + (size_t)b * N * 64;
  const __half* heb = he + (size_t)b * E * 16;
  int n = blockIdx.x;
  int f = threadIdx.x;
  if (n >= N || f >= 80) return;
  int e0 = offb[n], e1 = offb[n + 1];
  float acc = 0.f;
  if (f < 64) {
    int eg = e0;
    for (; eg + 4 <= e1; eg += 4) {
      int s0 = scb[eg], s1 = scb[eg + 1], s2 = scb[eg + 2], s3 = scb[eg + 3];
      float v0 = __half2float(hnb[(size_t)s0 * 64 + f]);
      float v1 = __half2float(hnb[(size_t)s1 * 64 + f]);
      float v2 = __half2float(hnb[(size_t)s2 * 64 + f]);
      float v3 = __half2float(hnb[(size_t)s3 * 64 + f]);
      acc += v0; acc += v1; acc += v2; acc += v3;
    }
    for (; eg < e1; eg++) acc += __half2float(hnb[(size_t)scb[eg] * 64 + f]);
  } else {
    int c = f - 64;
    for (int eg = e0; eg < e1; eg++) acc += __half2float(heb[(size_t)permb[eg] * 16 + c]);
  }
  xsum[(size_t)b * N * 80 + (size_t)n * 80 + f] = __float2half(acc);
}

// ---------------- attention el/er (fp16 z) ----------------
__global__ __launch_bounds__(256) void attn_lr_kernel(const __half* __restrict__ z,
                                                      const void* __restrict__ al,
                                                      const void* __restrict__ ar, size_t off,
                                                      const int* __restrict__ pflag,
                                                      float* __restrict__ el,
                                                      float* __restrict__ er, int N) {
  const bool pb = (*pflag != 0);
  int n = (blockIdx.x * blockDim.x + threadIdx.x) >> 6;
  int lane = threadIdx.x & 63;
  if (n >= N) return;
  union { uint4 q; __half s[8]; } u;
  u.q = *(const uint4*)(z + (size_t)n * 512 + lane * 8);
  float sl = 0.f, sr = 0.f;
#pragma unroll
  for (int q = 0; q < 8; q++) {
    int idx = lane * 8 + q;
    float zv = __half2float(u.s[q]);
    sl += zv * ldf(al, off + idx, pb);
    sr += zv * ldf(ar, off + idx, pb);
  }
#pragma unroll
  for (int o = 1; o < 16; o <<= 1) {
    sl += __shfl_xor(sl, o);
    sr += __shfl_xor(sr, o);
  }
  if ((lane & 15) == 0) {
    int h = lane >> 4;
    el[n * 4 + h] = sl;
    er[n * 4 + h] = sr;
  }
}

// ------- per-node attn exp in CSR order + denominator (deterministic) -----------------
__global__ void attn_sden_kernel(const int* __restrict__ off, const int* __restrict__ src_csr,
                                 const float* __restrict__ el, const float* __restrict__ er,
                                 float* __restrict__ ecsr, float* __restrict__ sden, int N) {
  int idx = blockIdx.x * 256 + threadIdx.x;
  int n = idx >> 2, h = idx & 3;
  if (n >= N) return;
  int e0 = off[n], e1 = off[n + 1];
  float ern = er[n * 4 + h];
  float s = 0.f;
  for (int eg = e0; eg < e1; eg++) {
    float v = el[src_csr[eg] * 4 + h] + ern;
    v = v > 0.f ? v : 0.2f * v;
    v = fminf(v, 60.f);
    float ev = expf(v);
    ecsr[eg * 4 + h] = ev;
    s += ev;
  }
  sden[n * 4 + h] = s;
}

// ---------------- lean GAT gather: sequential ecsr/src_csr, random z rows, fp16 out ---
__global__ __launch_bounds__(256) void gat_gather_kernel(const int* __restrict__ off,
                                                         const int* __restrict__ src_csr,
                                                         const __half* __restrict__ z,
                                                         const float* __restrict__ ecsr,
                                                         const float* __restrict__ sden,
                                                         const void* __restrict__ gb, size_t goff,
                                                         const int* __restrict__ pflag,
                                                         __half* __restrict__ out, int N) {
  const bool pb = (*pflag != 0);
  int n = (blockIdx.x * blockDim.x + threadIdx.x) >> 6;
  int lane = threadIdx.x & 63;
  if (n >= N) return;
  int h = lane >> 4;
  float sd = sden[n * 4 + h];
  float sinv = sd > 0.f ? 1.f / sd : 0.f;
  float acc[8] = {0.f, 0.f, 0.f, 0.f, 0.f, 0.f, 0.f, 0.f};
  int e0 = off[n], e1 = off[n + 1];
  int eg = e0;
  for (; eg + 4 <= e1; eg += 4) {
    int s0 = src_csr[eg], s1 = src_csr[eg + 1], s2 = src_csr[eg + 2], s3 = src_csr[eg + 3];
    float a0 = ecsr[(eg) * 4 + h] * sinv;
    float a1 = ecsr[(eg + 1) * 4 + h] * sinv;
    float a2 = ecsr[(eg + 2) * 4 + h] * sinv;
    float a3 = ecsr[(eg + 3) * 4 + h] * sinv;
    union { uint4 q; __half s[8]; } u0, u1, u2, u3;
    u0.q = *(const uint4*)(z + (size_t)s0 * 512 + lane * 8);
    u1.q = *(const uint4*)(z + (size_t)s1 * 512 + lane * 8);
    u2.q = *(const uint4*)(z + (size_t)s2 * 512 + lane * 8);
    u3.q = *(const uint4*)(z + (size_t)s3 * 512 + lane * 8);
#pragma unroll
    for (int q = 0; q < 8; q++) acc[q] += a0 * __half2float(u0.s[q]);
#pragma unroll
    for (int q = 0; q < 8; q++) acc[q] += a1 * __half2float(u1.s[q]);
#pragma unroll
    for (int q = 0; q < 8; q++) acc[q] += a2 * __half2float(u2.s[q]);
#pragma unroll
    for (int q = 0; q < 8; q++) acc[q] += a3 * __half2float(u3.s[q]);
  }
  for (; eg < e1; eg++) {
    int s0 = src_csr[eg];
    float a0 = ecsr[eg * 4 + h] * sinv;
    union { uint4 q; __half s[8]; } u0;
    u0.q = *(const uint4*)(z + (size_t)s0 * 512 + lane * 8);
#pragma unroll
    for (int q = 0; q < 8; q++) acc[q] += a0 * __half2float(u0.s[q]);
  }
  union { uint4 q; __half s[8]; } w;
#pragma unroll
  for (int q = 0; q < 8; q++) {
    float v = acc[q] + ldf(gb, goff + lane * 8 + q, pb);
    w.s[q] = __float2half(v > 0.f ? v : 0.01f * v);
  }
  *(uint4*)(out + (size_t)n * 512 + lane * 8) = w.q;
}

// ---------------- node weight ----------------
__global__ __launch_bounds__(256) void wnode_kernel(const float* __restrict__ x,
                                                    const void* __restrict__ wsw, size_t woff,
                                                    const void* __restrict__ wsb, size_t boff,
                                                    const int* __restrict__ pflag,
                                                    float* __restrict__ w, int N) {
  const bool pb = (*pflag != 0);
  int n = (blockIdx.x * blockDim.x + threadIdx.x) >> 6;
  int lane = threadIdx.x & 63;
  if (n >= N) return;
  float s = x[(size_t)n * 128 + lane] * ldf(wsw, woff + lane, pb) +
            x[(size_t)n * 128 + 64 + lane] * ldf(wsw, woff + 64 + lane, pb);
#pragma unroll
  for (int o = 1; o < 64; o <<= 1) s += __shfl_xor(s, o);
  if (lane == 0) {
    float t = s + ldf(wsb, boff, pb);
    t = fmaxf(fminf(t, 60.f), -60.f);
    w[n] = 1.f / (1.f + expf(-t));
  }
}

__device__ __forceinline__ int lower_bound_dev(const int* a, int n, int v) {
  int lo = 0, hi = n;
  while (lo < hi) {
    int mid = (lo + hi) >> 1;
    if (a[mid] < v) lo = mid + 1; else hi = mid;
  }
  return lo;
}

// ---------------- readout phase 1: 16 chunks per graph, double partials ----------------
__global__ __launch_bounds__(128) void readout_p1_kernel(const float* __restrict__ x,
                                                         const float* __restrict__ w,
                                                         const int* __restrict__ gid, int N,
                                                         double* __restrict__ psum,
                                                         float* __restrict__ pmax) {
  int g = blockIdx.x >> 4;
  int c = blockIdx.x & 15;
  int d = threadIdx.x;
  __shared__ int ss, se;
  if (d == 0) {
    ss = lower_bound_dev(gid, N, g);
    se = lower_bound_dev(gid, N, g + 1);
  }
  __syncthreads();
  int len = se - ss;
  int a = ss + (int)(((long)len * c) >> 4);
  int b = ss + (int)(((long)len * (c + 1)) >> 4);
  double s = 0.0;
  float m = -1e30f;
  for (int n = a; n < b; n++) {
    float v = x[(size_t)n * 128 + d];
    s += (double)v * (double)w[n];
    m = fmaxf(m, v);
  }
  psum[(size_t)blockIdx.x * 128 + d] = s;
  pmax[(size_t)blockIdx.x * 128 + d] = m;
}

// ---------------- readout phase 2: combine 16 partials ----------------
__global__ __launch_bounds__(128) void readout_p2_kernel(const double* __restrict__ psum,
                                                         const float* __restrict__ pmax,
                                                         float* __restrict__ hs,
                                                         float* __restrict__ hm) {
  int g = blockIdx.x, d = threadIdx.x;
  double s = 0.0;
  float m = -1e30f;
#pragma unroll
  for (int c = 0; c < 16; c++) {
    s += psum[(size_t)(g * 16 + c) * 128 + d];
    m = fmaxf(m, pmax[(size_t)(g * 16 + c) * 128 + d]);
  }
  hs[g * 128 + d] = (float)s;
  hm[g * 128 + d] = m;
}

// ---------------- pool linear ----------------
__global__ __launch_bounds__(128) void pool_kernel(const float* __restrict__ hs,
                                                   const float* __restrict__ hm,
                                                   const void* __restrict__ Wp, size_t woff,
                                                   const void* __restrict__ bp, size_t boff,
                                                   const int* __restrict__ pflag,
                                                   float* __restrict__ bout) {
  const bool pb = (*pflag != 0);
  int g = blockIdx.x, j = threadIdx.x;
  __shared__ float hg[256];
  hg[j] = hs[g * 128 + j];
  hg[128 + j] = hm[g * 128 + j];
  __syncthreads();
  double acc = (double)ldf(bp, boff + j, pb);
  for (int k = 0; k < 256; k++) acc += (double)hg[k] * (double)ldf(Wp, woff + (size_t)k * 128 + j, pb);
  bout[g * 128 + j] = (float)acc;
}

// ---------------- final head ----------------
__global__ __launch_bounds__(128) void head_kernel(const float* __restrict__ bA,
                                                   const float* __restrict__ bB,
                                                   const void* __restrict__ Wo1,
                                                   const void* __restrict__ bo1,
                                                   const void* __restrict__ Wo2,
                                                   const void* __restrict__ bo2,
                                                   const int* __restrict__ pflag,
                                                   const int* __restrict__ oflag,
                                                   void* __restrict__ out) {
  const bool pb = (*pflag != 0);
  int g = blockIdx.x, j = threadIdx.x;
  __shared__ float zr[256];
  __shared__ double t[128];
  zr[j] = bA[g * 128 + j];
  zr[128 + j] = bB[g * 128 + j];
  __syncthreads();
  double acc = (double)ldf(bo1, j, pb);
  for (int k = 0; k < 256; k++) acc += (double)zr[k] * (double)ldf(Wo1, (size_t)k * 128 + j, pb);
  if (acc < 0.0) acc *= 0.01;
  t[j] = acc * (double)ldf(Wo2, j, pb);
  __syncthreads();
  for (int sdt = 64; sdt > 0; sdt >>= 1) {
    if (j < sdt) t[j] += t[j + sdt];
    __syncthreads();
  }
  if (j == 0) {
    float v = (float)(t[0] + (double)ldf(bo2, 0, pb));
    if (*oflag) ((bf16*)out)[g] = __float2bfloat16(v);
    else ((float*)out)[g] = v;
  }
}

extern "C" void kernel_launch(void* const* d_in, const int* in_sizes, int n_in,
                              void* d_out, int out_size, void* d_ws, size_t ws_size,
                              hipStream_t stream) {
  const int* srcA = (const int*)d_in[0];
  const int* dstA = (const int*)d_in[1];
  const int* gidA = (const int*)d_in[2];
  const void* nfA = d_in[3];
  const void* efA = d_in[4];
  const int* srcB = (const int*)d_in[5];
  const int* dstB = (const int*)d_in[6];
  const int* gidB = (const int*)d_in[7];
  const void* nfB = d_in[8];
  const void* efB = d_in[9];
  const void* p_Wn = d_in[10];
  const void* p_bn = d_in[11];
  const void* p_We = d_in[12];
  const void* p_be = d_in[13];
  const void* p_Wc = d_in[14];
  const void* p_bc = d_in[15];
  const void* p_fc1 = d_in[16];
  const void* p_al1 = d_in[17];
  const void* p_ar1 = d_in[18];
  const void* p_gb1 = d_in[19];
  const void* p_Wl1 = d_in[20];
  const void* p_bl1 = d_in[21];
  const void* p_fc2 = d_in[22];
  const void* p_al2 = d_in[23];
  const void* p_ar2 = d_in[24];
  const void* p_gb2 = d_in[25];
  const void* p_Wl2 = d_in[26];
  const void* p_bl2 = d_in[27];
  const void* p_ws_w = d_in[28];
  const void* p_ws_b = d_in[29];
  const void* p_Wp = d_in[30];
  const void* p_bp = d_in[31];
  const void* Wo1 = d_in[32];
  const void* bo1 = d_in[33];
  const void* Wo2 = d_in[34];
  const void* bo2 = d_in[35];

  // workspace carve-up (~120 MB)
  char* wp = (char*)d_ws;
  auto alloc = [&](size_t bytes) -> char* {
    char* p = wp;
    wp += (bytes + 255) & ~(size_t)255;
    return p;
  };
  int* flags = (int*)alloc(2 * 4);
  int* cnt = (int*)alloc((size_t)2 * Nn * 4);
  int* incl = (int*)alloc((size_t)2 * Nn * 4);
  int* bsum = (int*)alloc(2 * 256 * 4);
  int* offs = (int*)alloc((size_t)2 * (Nn + 1) * 4);
  int* cursor = (int*)alloc((size_t)2 * Nn * 4);
  int* perm = (int*)alloc((size_t)2 * Ne * 4);
  int* src_csr = (int*)alloc((size_t)2 * Ne * 4);
  float* ecsr = (float*)alloc((size_t)Ne * 4 * 4);
  float* sden = (float*)alloc((size_t)Nn * 4 * 4);
  float* el = (float*)alloc((size_t)Nn * 4 * 4);
  float* er = (float*)alloc((size_t)Nn * 4 * 4);
  float* wn = (float*)alloc((size_t)Nn * 4);
  double* psum = (double*)alloc((size_t)Bg * 16 * 128 * 8);
  float* pmax = (float*)alloc((size_t)Bg * 16 * 128 * 4);
  float* hsb = (float*)alloc((size_t)Bg * 128 * 4);
  float* hmb = (float*)alloc((size_t)Bg * 128 * 4);
  float* bout = (float*)alloc((size_t)2 * Bg * 128 * 4);
  // transposed fp16 weight planes
  __half* Wct = (__half*)alloc((size_t)2 * 80 * 80 * 2);
  __half* fc1t = (__half*)alloc((size_t)2 * 512 * 80 * 2);
  __half* Wl1t = (__half*)alloc((size_t)2 * 128 * 512 * 2);
  __half* fc2t = (__half*)alloc((size_t)2 * 512 * 128 * 2);
  __half* Wl2t = (__half*)alloc((size_t)2 * 128 * 512 * 2);
  // per-branch front-end buffers
  __half* hn = (__half*)alloc((size_t)2 * Nn * 64 * 2);   // 6.4 MB
  __half* he = (__half*)alloc((size_t)2 * Ne * 16 * 2);   // 25.6 MB
  __half* xsum = (__half*)alloc((size_t)2 * Nn * 80 * 2); // 8 MB
  // shared big buffers (per-branch sequential)
  char* zreg = alloc((size_t)Nn * 512 * 2);               // z fp16 25.6 MB; x2 f32 overlays
  __half* hb = (__half*)alloc((size_t)Nn * 512 * 2);      // 25.6 MB
  __half* xcx1 = (__half*)alloc((size_t)Nn * 128 * 2);    // 6.4 MB (xc 80 cols / x1 128 cols)
  __half* z = (__half*)zreg;
  float* x2 = (float*)zreg;   // Nn*128 f32 = 12.8 MB, overlays z after last gather
  __half* xc = xcx1;
  __half* x1 = xcx1;

  auto cdiv = [](int a, int b) { return (a + b - 1) / b; };

  detect_kernel<<<1, 256, 0, stream>>>((const u16*)nfA, 8192, (const u16*)p_fc1, 8192, flags);
  int* fflag = &flags[0];
  int* pflag = &flags[1];

  // prep: fused transpose+convert of all fp16 weight planes (both branches)
  {
    TCAll tc;
    int segK[5] = {80, 80, 512, 128, 512};
    int segN[5] = {80, 512, 128, 512, 128};
    const void* segW[5] = {p_Wc, p_fc1, p_Wl1, p_fc2, p_Wl2};
    __half* segH[5] = {Wct, fc1t, Wl1t, fc2t, Wl2t};
    int start = 0, s = 0;
    for (int i = 0; i < 2; i++)
      for (int m = 0; m < 5; m++) {
        int sz = segK[m] * segN[m];
        tc.t[s].W = segW[m];
        tc.t[s].off = (size_t)i * sz;
        tc.t[s].H = segH[m] + (size_t)i * sz;
        tc.t[s].K = segK[m];
        tc.t[s].N = segN[m];
        tc.t[s].start = start;
        start += sz;
        s++;
      }
    tc.total = start;
    transconv_all_kernel<<<cdiv(start, 256), 256, 0, stream>>>(tc, pflag);
  }

  const int nb = cdiv(Nn, 256);  // 98 scan blocks per branch

  // ---- merged front-end: CSR + projections + edgeconv for BOTH branches ----
  hipMemsetAsync(cnt, 0, (size_t)2 * Nn * 4, stream);
  count_kernel<<<dim3(cdiv(Ne, 256), 2), 256, 0, stream>>>(dstA, dstB, cnt, Ne, Nn);
  scan1_kernel<<<dim3(nb, 2), 256, 0, stream>>>(cnt, incl, bsum, Nn);
  scan2_kernel<<<2, 256, 0, stream>>>(bsum, nb);
  scan3_kernel<<<dim3(nb, 2), 256, 0, stream>>>(cnt, incl, bsum, offs, cursor, Nn);
  fill_kernel<<<dim3(cdiv(Ne, 256), 2), 256, 0, stream>>>(dstA, dstB, cursor, perm, Ne, Nn);
  sortseg_kernel<<<dim3(cdiv(Nn, 64), 2), 64, 0, stream>>>(offs, perm, Nn, Ne);
  srccsr_kernel<<<dim3(cdiv(Ne, 256), 2), 256, 0, stream>>>(srcA, srcB, perm, src_csr, Ne);
  proj_nf_kernel<<<dim3(cdiv(Nn, 4), 2), 256, 0, stream>>>(
      nfA, nfB, fflag, p_Wn, p_bn, pflag, hn, Nn);
  proj_ef_kernel<<<dim3(cdiv(Ne, 16), 2), 256, 0, stream>>>(
      efA, efB, fflag, p_We, p_be, pflag, he, Ne);
  edgeconv_kernel<<<dim3(Nn, 2), 128, 0, stream>>>(offs, perm, src_csr, hn, he, xsum, Nn, Ne);

  auto run_branch = [&](int i, const int* gid, float* bout_i) {
    const int* offb = offs + i * (Nn + 1);
    const int* scb = src_csr + (size_t)i * Ne;
    // EdgeGraphConv linear
    mfma_f16_gemm<1, 2><<<dim3(cdiv(Nn, 128), 1), 256, 0, stream>>>(
        xsum + (size_t)i * Nn * 80, Wct + (size_t)i * 80 * 80,
        p_bc, (size_t)i * 80, pflag, xc, Nn, 80, 80);
    // GAT 1
    mfma_f16_gemm<0, 2><<<dim3(cdiv(Nn, 128), 4), 256, 0, stream>>>(
        xc, fc1t + (size_t)i * 512 * 80, nullptr, 0, pflag, z, Nn, 80, 512);
    attn_lr_kernel<<<cdiv(Nn * 64, 256), 256, 0, stream>>>(
        z, p_al1, p_ar1, (size_t)i * 512, pflag, el, er, Nn);
    attn_sden_kernel<<<cdiv(Nn * 4, 256), 256, 0, stream>>>(offb, scb, el, er, ecsr, sden, Nn);
    gat_gather_kernel<<<cdiv(Nn * 64, 256), 256, 0, stream>>>(
        offb, scb, z, ecsr, sden, p_gb1, (size_t)i * 512, pflag, hb, Nn);
    mfma_f16_gemm<0, 2><<<dim3(cdiv(Nn, 128), 1), 256, 0, stream>>>(
        hb, Wl1t + (size_t)i * 128 * 512, p_bl1, (size_t)i * 128, pflag, x1, Nn, 512, 128);
    // GAT 2
    mfma_f16_gemm<0, 2><<<dim3(cdiv(Nn, 128), 4), 256, 0, stream>>>(
        x1, fc2t + (size_t)i * 512 * 128, nullptr, 0, pflag, z, Nn, 128, 512);
    attn_lr_kernel<<<cdiv(Nn * 64, 256), 256, 0, stream>>>(
        z, p_al2, p_ar2, (size_t)i * 512, pflag, el, er, Nn);
    attn_sden_kernel<<<cdiv(Nn * 4, 256), 256, 0, stream>>>(offb, scb, el, er, ecsr, sden, Nn);
    gat_gather_kernel<<<cdiv(Nn * 64, 256), 256, 0, stream>>>(
        offb, scb, z, ecsr, sden, p_gb2, (size_t)i * 512, pflag, hb, Nn);
    mfma_f16_gemm<0, 0><<<dim3(cdiv(Nn, 128), 1), 256, 0, stream>>>(
        hb, Wl2t + (size_t)i * 128 * 512, p_bl2, (size_t)i * 128, pflag, x2, Nn, 512, 128);
    // readout
    wnode_kernel<<<cdiv(Nn * 64, 256), 256, 0, stream>>>(
        x2, p_ws_w, (size_t)i * 128, p_ws_b, (size_t)i, pflag, wn, Nn);
    readout_p1_kernel<<<Bg * 16, 128, 0, stream>>>(x2, wn, gid, Nn, psum, pmax);
    readout_p2_kernel<<<Bg, 128, 0, stream>>>(psum, pmax, hsb, hmb);
    pool_kernel<<<Bg, 128, 0, stream>>>(
        hsb, hmb, p_Wp, (size_t)i * 256 * 128, p_bp, (size_t)i * 128, pflag, bout_i);
  };

  run_branch(0, gidA, bout);
  run_branch(1, gidB, bout + (size_t)Bg * 128);

  head_kernel<<<Bg, 128, 0, stream>>>(bout, bout + (size_t)Bg * 128, Wo1, bo1, Wo2, bo2,
                                      pflag, fflag, d_out);
}

// Round 10
// 1122.695 us; speedup vs baseline: 2.7529x; 1.1568x over previous
//
#include <hip/hip_runtime.h>
#include <hip/hip_bf16.h>
#include <hip/hip_fp16.h>

typedef __hip_bfloat16 bf16;
typedef unsigned short u16;
typedef __attribute__((ext_vector_type(8))) short short8;
typedef __attribute__((ext_vector_type(4))) float floatx4;
typedef _Float16 half8 __attribute__((ext_vector_type(8)));

static constexpr int Nn = 25000;   // nodes
static constexpr int Ne = 400000;  // edges
static constexpr int Bg = 64;      // graphs

__device__ __forceinline__ float ldf(const void* p, size_t i, bool b16) {
  return b16 ? __bfloat162float(((const bf16*)p)[i]) : ((const float*)p)[i];
}

// ---------------- dtype detection ----------------
__global__ void detect_kernel(const u16* a, int n, const u16* b, int m, int* flags) {
  __shared__ int c0, c1;
  if (threadIdx.x == 0) { c0 = 0; c1 = 0; }
  __syncthreads();
  int t = threadIdx.x;
  int l0 = 0, l1 = 0;
  for (int i = t; i < n; i += 256) {
    unsigned e = (a[i] >> 7) & 0xFF;
    if (e >= 140) l0++;
  }
  for (int i = t; i < m; i += 256) {
    unsigned e = (b[i] >> 7) & 0xFF;
    if (e >= 140) l1++;
  }
  atomicAdd(&c0, l0);
  atomicAdd(&c1, l1);
  __syncthreads();
  if (t == 0) {
    flags[0] = (c0 < n / 16) ? 1 : 0;
    flags[1] = (c1 < m / 16) ? 1 : 0;
  }
}

// ------- fused transpose+convert: all big weights -> fp16 plane [N][K] ----------------
struct TC { const void* W; size_t off; __half* H; int K; int N; int start; };
struct TCAll { TC t[10]; int total; };

__global__ void transconv_all_kernel(TCAll a, const int* __restrict__ pflag) {
  const bool pb = (*pflag != 0);
  int idx = blockIdx.x * 256 + threadIdx.x;
  if (idx >= a.total) return;
  int s = 0;
  while (s + 1 < 10 && idx >= a.t[s + 1].start) s++;
  int li = idx - a.t[s].start;
  int K = a.t[s].K, N = a.t[s].N;
  int k = li / N, n = li - k * N;
  float w = ldf(a.t[s].W, a.t[s].off + li, pb);
  a.t[s].H[(size_t)n * K + k] = __float2half(w);
}

// ---------------- fp16 MFMA GEMM (branch dim = blockIdx.z) ----------------
template <int ACT, int OUT>
__global__ __launch_bounds__(256) void mfma_f16_gemm(const __half* __restrict__ A, size_t Abs,
                                                     const __half* __restrict__ Bt, size_t Bbs,
                                                     const void* __restrict__ bias, size_t bstr,
                                                     const int* __restrict__ pflag,
                                                     void* __restrict__ C, size_t Cbs,
                                                     int M, int K, int N) {
  const int br = blockIdx.z;
  A += (size_t)br * Abs;
  Bt += (size_t)br * Bbs;
  const size_t boff = (size_t)br * bstr;
  __shared__ short As[128 * 40];
  __shared__ short Bs[128 * 40];
  const int bm = blockIdx.x * 128;
  const int bn = blockIdx.y * 128;
  const int tid = threadIdx.x;
  const int lane = tid & 63;
  const int wave = tid >> 6;
  const int wm = wave >> 1, wn = wave & 1;
  const int lm = lane & 15, quad = lane >> 4;
  const int srow = tid >> 1;
  const int sseg = tid & 1;
  floatx4 acc[4][4] = {};
  for (int k0 = 0; k0 < K; k0 += 32) {
    bool kv = (k0 + sseg * 16) < K;
    {
      int gr = bm + srow;
      short8 a0 = {}, a1 = {};
      if (gr < M && kv) {
        const short8* gp = (const short8*)(A + (size_t)gr * K + k0 + sseg * 16);
        a0 = gp[0];
        a1 = gp[1];
      }
      *(short8*)&As[srow * 40 + sseg * 16] = a0;
      *(short8*)&As[srow * 40 + sseg * 16 + 8] = a1;
    }
    {
      int gc = bn + srow;
      short8 b0 = {}, b1 = {};
      if (gc < N && kv) {
        const short8* gp = (const short8*)(Bt + (size_t)gc * K + k0 + sseg * 16);
        b0 = gp[0];
        b1 = gp[1];
      }
      *(short8*)&Bs[srow * 40 + sseg * 16] = b0;
      *(short8*)&Bs[srow * 40 + sseg * 16 + 8] = b1;
    }
    __syncthreads();
    half8 af[4], bfv[4];
#pragma unroll
    for (int f = 0; f < 4; f++) {
      af[f] = *(const half8*)&As[(wm * 64 + f * 16 + lm) * 40 + quad * 8];
      bfv[f] = *(const half8*)&Bs[(wn * 64 + f * 16 + lm) * 40 + quad * 8];
    }
#pragma unroll
    for (int i = 0; i < 4; i++)
#pragma unroll
      for (int j = 0; j < 4; j++)
        acc[i][j] = __builtin_amdgcn_mfma_f32_16x16x32_f16(af[i], bfv[j], acc[i][j], 0, 0, 0);
    __syncthreads();
  }
  const bool pb = (*pflag != 0);
#pragma unroll
  for (int i = 0; i < 4; i++) {
#pragma unroll
    for (int j = 0; j < 4; j++) {
      int col = bn + wn * 64 + j * 16 + lm;
      if (col >= N) continue;
#pragma unroll
      for (int r = 0; r < 4; r++) {
        int row = bm + wm * 64 + i * 16 + quad * 4 + r;
        if (row >= M) continue;
        float v = acc[i][j][r];
        if (bias) v += ldf(bias, boff + col, pb);
        if (ACT == 1) v = v > 0.f ? v : 0.f;
        if (OUT == 0)
          ((float*)C)[(size_t)br * Cbs + (size_t)row * N + col] = v;
        else
          ((__half*)C)[(size_t)br * Cbs + (size_t)row * N + col] = __float2half(v);
      }
    }
  }
}

// ---------------- input projection: hn[n][64] fp16 (both branches) ----------------
__global__ __launch_bounds__(256) void proj_nf_kernel(const void* __restrict__ nfA,
                                                      const void* __restrict__ nfB,
                                                      const int* __restrict__ fflag,
                                                      const void* __restrict__ Wn,
                                                      const void* __restrict__ bn,
                                                      const int* __restrict__ pflag,
                                                      __half* __restrict__ hn, int N) {
  __shared__ float Ws[64 * 65];
  __shared__ float bs[64];
  __shared__ float rowbuf[4][64];
  const bool fb = (*fflag != 0), pb = (*pflag != 0);
  const int b = blockIdx.y;
  const void* nf = b ? nfB : nfA;
  size_t woff = (size_t)b * 64 * 64, boff = (size_t)b * 64;
  int t = threadIdx.x;
  for (int i = t; i < 4096; i += 256) {
    int k = i >> 6, c = i & 63;
    Ws[k * 65 + c] = ldf(Wn, woff + i, pb);
  }
  if (t < 64) bs[t] = ldf(bn, boff + t, pb);
  __syncthreads();
  int wave = t >> 6, lane = t & 63;
  int n = blockIdx.x * 4 + wave;
  if (n >= N) return;
  rowbuf[wave][lane] = ldf(nf, (size_t)n * 64 + lane, fb);
  float acc = bs[lane];
#pragma unroll 8
  for (int k = 0; k < 64; k++) acc += rowbuf[wave][k] * Ws[k * 65 + lane];
  hn[(size_t)b * N * 64 + (size_t)n * 64 + lane] = __float2half(acc);
}

// -------- input projection: he in CSR order via ipos (both branches) ----------------
__global__ __launch_bounds__(256) void proj_ef_kernel(const void* __restrict__ efA,
                                                      const void* __restrict__ efB,
                                                      const int* __restrict__ fflag,
                                                      const void* __restrict__ We,
                                                      const void* __restrict__ be,
                                                      const int* __restrict__ pflag,
                                                      const int* __restrict__ ipos,
                                                      __half* __restrict__ he_csr, int E) {
  __shared__ float Ws[16 * 17];
  __shared__ float bs[16];
  __shared__ float efs[16][17];
  const bool fb = (*fflag != 0), pb = (*pflag != 0);
  const int b = blockIdx.y;
  const void* ef = b ? efB : efA;
  size_t woff = (size_t)b * 256, boff = (size_t)b * 16;
  int t = threadIdx.x;
  Ws[(t >> 4) * 17 + (t & 15)] = ldf(We, woff + t, pb);
  if (t < 16) bs[t] = ldf(be, boff + t, pb);
  int el = t >> 4, k = t & 15;
  int e = blockIdx.x * 16 + el;
  float v = 0.f;
  if (e < E) v = ldf(ef, (size_t)e * 16 + k, fb);
  efs[el][k] = v;
  __syncthreads();
  if (e < E) {
    float acc = bs[k];
#pragma unroll
    for (int kk = 0; kk < 16; kk++) acc += efs[el][kk] * Ws[kk * 17 + k];
    int pos = ipos[(size_t)b * E + e];
    he_csr[(size_t)b * E * 16 + (size_t)pos * 16 + k] = __float2half(acc);
  }
}

// ---------------- CSR build (both branches) ----------------
__global__ void count_kernel(const int* __restrict__ dA, const int* __restrict__ dB,
                             int* __restrict__ cnt, int E, int N) {
  int b = blockIdx.y;
  const int* dst = b ? dB : dA;
  int e = blockIdx.x * 256 + threadIdx.x;
  if (e < E) atomicAdd(&cnt[b * N + dst[e]], 1);
}

__global__ void scan1_kernel(const int* __restrict__ cnt, int* __restrict__ incl,
                             int* __restrict__ bsum, int n) {
  __shared__ int buf[256];
  int b = blockIdx.y;
  int t = threadIdx.x;
  int i = blockIdx.x * 256 + t;
  int v = (i < n) ? cnt[b * n + i] : 0;
  buf[t] = v;
  __syncthreads();
  for (int d = 1; d < 256; d <<= 1) {
    int add = (t >= d) ? buf[t - d] : 0;
    __syncthreads();
    buf[t] += add;
    __syncthreads();
  }
  if (i < n) incl[b * n + i] = buf[t];
  if (t == 255) bsum[b * 256 + blockIdx.x] = buf[255];
}

__global__ void scan2_kernel(int* __restrict__ bsum, int nb) {
  __shared__ int buf[256];
  int b = blockIdx.x;
  int t = threadIdx.x;
  int v = (t < nb) ? bsum[b * 256 + t] : 0;
  buf[t] = v;
  __syncthreads();
  for (int d = 1; d < 256; d <<= 1) {
    int add = (t >= d) ? buf[t - d] : 0;
    __syncthreads();
    buf[t] += add;
    __syncthreads();
  }
  if (t < nb) bsum[b * 256 + t] = buf[t] - v;
}

__global__ void scan3_kernel(const int* __restrict__ cnt, const int* __restrict__ incl,
                             const int* __restrict__ bsum, int* __restrict__ offs,
                             int* __restrict__ cursor, int n) {
  int b = blockIdx.y;
  int i = blockIdx.x * 256 + threadIdx.x;
  if (i < n) {
    int e = incl[b * n + i] - cnt[b * n + i] + bsum[b * 256 + blockIdx.x];
    offs[b * (n + 1) + i] = e;
    cursor[b * n + i] = e;
    if (i == n - 1) offs[b * (n + 1) + n] = incl[b * n + i] + bsum[b * 256 + blockIdx.x];
  }
}

__global__ void fill_kernel(const int* __restrict__ dA, const int* __restrict__ dB,
                            int* __restrict__ cursor, int* __restrict__ perm, int E, int N) {
  int b = blockIdx.y;
  const int* dst = b ? dB : dA;
  int e = blockIdx.x * 256 + threadIdx.x;
  if (e < E) {
    int p = atomicAdd(&cursor[b * N + dst[e]], 1);
    perm[(size_t)b * E + p] = e;
  }
}

// ------- sort each node's segment by edge id (LDS scratch), both branches -------------
__global__ __launch_bounds__(64) void sortseg_kernel(const int* __restrict__ off,
                                                     int* __restrict__ perm, int N, int E) {
  __shared__ int loc[64 * 64];
  int b = blockIdx.y;
  const int* offb = off + b * (N + 1);
  int* permb = perm + (size_t)b * E;
  int t = threadIdx.x;
  int n = blockIdx.x * 64 + t;
  if (n >= N) return;
  int e0 = offb[n], e1 = offb[n + 1];
  int d = e1 - e0;
  if (d <= 1) return;
  if (d <= 64) {
    for (int i = 0; i < d; i++) loc[i * 64 + t] = permb[e0 + i];
    for (int i = 1; i < d; i++) {
      int v = loc[i * 64 + t];
      int j = i - 1;
      while (j >= 0 && loc[j * 64 + t] > v) { loc[(j + 1) * 64 + t] = loc[j * 64 + t]; j--; }
      loc[(j + 1) * 64 + t] = v;
    }
    for (int i = 0; i < d; i++) permb[e0 + i] = loc[i * 64 + t];
  } else {
    for (int i = 0; i < d - 1; i++) {
      int mi = i;
      for (int j = i + 1; j < d; j++)
        if (permb[e0 + j] < permb[e0 + mi]) mi = j;
      int tmp = permb[e0 + i];
      permb[e0 + i] = permb[e0 + mi];
      permb[e0 + mi] = tmp;
    }
  }
}

// -------- src_csr[i] = src[perm[i]]; ipos[perm[i]] = i (both branches) ----------------
__global__ void srccsr_kernel(const int* __restrict__ sA, const int* __restrict__ sB,
                              const int* __restrict__ perm, int* __restrict__ src_csr,
                              int* __restrict__ ipos, int E) {
  int b = blockIdx.y;
  const int* src = b ? sB : sA;
  int i = blockIdx.x * 256 + threadIdx.x;
  if (i < E) {
    int e = perm[(size_t)b * E + i];
    src_csr[(size_t)b * E + i] = src[e];
    ipos[(size_t)b * E + e] = i;
  }
}

// ------- EdgeGraphConv: wave-per-node; hn random rows, he_csr sequential -------------
__global__ __launch_bounds__(256) void edgeconv_kernel(const int* __restrict__ off,
                                                       const int* __restrict__ src_csr,
                                                       const __half* __restrict__ hn,
                                                       const __half* __restrict__ he_csr,
                                                       __half* __restrict__ xsum, int N, int E) {
  int b = blockIdx.y;
  const int* offb = off + b * (N + 1);
  const int* scb = src_csr + (size_t)b * E;
  const __half* hnb = hn + (size_t)b * N * 64;
  const __half* heb = he_csr + (size_t)b * E * 16;
  int wave = threadIdx.x >> 6, lane = threadIdx.x & 63;
  int n = blockIdx.x * 4 + wave;
  if (n >= N) return;
  int e0 = offb[n], e1 = offb[n + 1];
  // hn part: lane = feature
  float acc = 0.f;
  int eg = e0;
  for (; eg + 4 <= e1; eg += 4) {
    int s0 = scb[eg], s1 = scb[eg + 1], s2 = scb[eg + 2], s3 = scb[eg + 3];
    float v0 = __half2float(hnb[(size_t)s0 * 64 + lane]);
    float v1 = __half2float(hnb[(size_t)s1 * 64 + lane]);
    float v2 = __half2float(hnb[(size_t)s2 * 64 + lane]);
    float v3 = __half2float(hnb[(size_t)s3 * 64 + lane]);
    acc += v0; acc += v1; acc += v2; acc += v3;
  }
  for (; eg < e1; eg++) acc += __half2float(hnb[(size_t)scb[eg] * 64 + lane]);
  // he part: lane = grp*16+f; grp strides edges; sequential he_csr reads
  int grp = lane >> 4, f = lane & 15;
  float hacc = 0.f;
  for (int e = e0 + grp; e < e1; e += 4) hacc += __half2float(heb[(size_t)e * 16 + f]);
  hacc += __shfl_xor(hacc, 16);
  hacc += __shfl_xor(hacc, 32);
  __half* xr = xsum + (size_t)b * N * 80 + (size_t)n * 80;
  xr[lane < 64 ? lane : 0] = __float2half(lane < 64 ? acc : acc);  // (all lanes <64) keep simple
  xr[lane] = __float2half(acc);
  if (lane < 16) xr[64 + lane] = __float2half(hacc);
}

// ---------------- attention el/er (both branches) ----------------
__global__ __launch_bounds__(256) void attn_lr_kernel(const __half* __restrict__ z,
                                                      const void* __restrict__ al,
                                                      const void* __restrict__ ar, size_t astr,
                                                      const int* __restrict__ pflag,
                                                      float* __restrict__ el,
                                                      float* __restrict__ er, int N) {
  const bool pb = (*pflag != 0);
  const int b = blockIdx.y;
  const size_t off = (size_t)b * astr;
  const __half* zb = z + (size_t)b * N * 512;
  int n = (blockIdx.x * blockDim.x + threadIdx.x) >> 6;
  int lane = threadIdx.x & 63;
  if (n >= N) return;
  union { uint4 q; __half s[8]; } u;
  u.q = *(const uint4*)(zb + (size_t)n * 512 + lane * 8);
  float sl = 0.f, sr = 0.f;
#pragma unroll
  for (int q = 0; q < 8; q++) {
    int idx = lane * 8 + q;
    float zv = __half2float(u.s[q]);
    sl += zv * ldf(al, off + idx, pb);
    sr += zv * ldf(ar, off + idx, pb);
  }
#pragma unroll
  for (int o = 1; o < 16; o <<= 1) {
    sl += __shfl_xor(sl, o);
    sr += __shfl_xor(sr, o);
  }
  if ((lane & 15) == 0) {
    int h = lane >> 4;
    el[(size_t)b * N * 4 + n * 4 + h] = sl;
    er[(size_t)b * N * 4 + n * 4 + h] = sr;
  }
}

// ------- per-node attn exp in CSR order + denominator (both branches) -----------------
__global__ void attn_sden_kernel(const int* __restrict__ off, const int* __restrict__ src_csr,
                                 const float* __restrict__ el, const float* __restrict__ er,
                                 float* __restrict__ ecsr, float* __restrict__ sden, int N, int E) {
  int b = blockIdx.y;
  const int* offb = off + b * (N + 1);
  const int* scb = src_csr + (size_t)b * E;
  const float* elb = el + (size_t)b * N * 4;
  float* ecb = ecsr + (size_t)b * E * 4;
  int idx = blockIdx.x * 256 + threadIdx.x;
  int n = idx >> 2, h = idx & 3;
  if (n >= N) return;
  int e0 = offb[n], e1 = offb[n + 1];
  float ern = er[(size_t)b * N * 4 + n * 4 + h];
  float s = 0.f;
  for (int eg = e0; eg < e1; eg++) {
    float v = elb[scb[eg] * 4 + h] + ern;
    v = v > 0.f ? v : 0.2f * v;
    v = fminf(v, 60.f);
    float ev = expf(v);
    ecb[eg * 4 + h] = ev;
    s += ev;
  }
  sden[(size_t)b * N * 4 + n * 4 + h] = s;
}

// ---------------- lean GAT gather (both branches), fp16 out ----------------
__global__ __launch_bounds__(256) void gat_gather_kernel(const int* __restrict__ off,
                                                         const int* __restrict__ src_csr,
                                                         const __half* __restrict__ z,
                                                         const float* __restrict__ ecsr,
                                                         const float* __restrict__ sden,
                                                         const void* __restrict__ gb, size_t gstr,
                                                         const int* __restrict__ pflag,
                                                         __half* __restrict__ out, int N, int E) {
  const bool pb = (*pflag != 0);
  int b = blockIdx.y;
  const int* offb = off + b * (N + 1);
  const int* scb = src_csr + (size_t)b * E;
  const __half* zb = z + (size_t)b * N * 512;
  const float* ecb = ecsr + (size_t)b * E * 4;
  const size_t goff = (size_t)b * gstr;
  int n = (blockIdx.x * blockDim.x + threadIdx.x) >> 6;
  int lane = threadIdx.x & 63;
  if (n >= N) return;
  int h = lane >> 4;
  float sd = sden[(size_t)b * N * 4 + n * 4 + h];
  float sinv = sd > 0.f ? 1.f / sd : 0.f;
  float acc[8] = {0.f, 0.f, 0.f, 0.f, 0.f, 0.f, 0.f, 0.f};
  int e0 = offb[n], e1 = offb[n + 1];
  int eg = e0;
  for (; eg + 4 <= e1; eg += 4) {
    int s0 = scb[eg], s1 = scb[eg + 1], s2 = scb[eg + 2], s3 = scb[eg + 3];
    float a0 = ecb[(eg) * 4 + h] * sinv;
    float a1 = ecb[(eg + 1) * 4 + h] * sinv;
    float a2 = ecb[(eg + 2) * 4 + h] * sinv;
    float a3 = ecb[(eg + 3) * 4 + h] * sinv;
    union { uint4 q; __half s[8]; } u0, u1, u2, u3;
    u0.q = *(const uint4*)(zb + (size_t)s0 * 512 + lane * 8);
    u1.q = *(const uint4*)(zb + (size_t)s1 * 512 + lane * 8);
    u2.q = *(const uint4*)(zb + (size_t)s2 * 512 + lane * 8);
    u3.q = *(const uint4*)(zb + (size_t)s3 * 512 + lane * 8);
#pragma unroll
    for (int q = 0; q < 8; q++) acc[q] += a0 * __half2float(u0.s[q]);
#pragma unroll
    for (int q = 0; q < 8; q++) acc[q] += a1 * __half2float(u1.s[q]);
#pragma unroll
    for (int q = 0; q < 8; q++) acc[q] += a2 * __half2float(u2.s[q]);
#pragma unroll
    for (int q = 0; q < 8; q++) acc[q] += a3 * __half2float(u3.s[q]);
  }
  for (; eg < e1; eg++) {
    int s0 = scb[eg];
    float a0 = ecb[eg * 4 + h] * sinv;
    union { uint4 q; __half s[8]; } u0;
    u0.q = *(const uint4*)(zb + (size_t)s0 * 512 + lane * 8);
#pragma unroll
    for (int q = 0; q < 8; q++) acc[q] += a0 * __half2float(u0.s[q]);
  }
  union { uint4 q; __half s[8]; } w;
#pragma unroll
  for (int q = 0; q < 8; q++) {
    float v = acc[q] + ldf(gb, goff + lane * 8 + q, pb);
    w.s[q] = __float2half(v > 0.f ? v : 0.01f * v);
  }
  *(uint4*)(out + (size_t)b * N * 512 + (size_t)n * 512 + lane * 8) = w.q;
}

// ---------------- node weight (both branches) ----------------
__global__ __launch_bounds__(256) void wnode_kernel(const float* __restrict__ x,
                                                    const void* __restrict__ wsw,
                                                    const void* __restrict__ wsb,
                                                    const int* __restrict__ pflag,
                                                    float* __restrict__ w, int N) {
  const bool pb = (*pflag != 0);
  int b = blockIdx.y;
  const float* xb = x + (size_t)b * N * 128;
  size_t woff = (size_t)b * 128, boff = (size_t)b;
  int n = (blockIdx.x * blockDim.x + threadIdx.x) >> 6;
  int lane = threadIdx.x & 63;
  if (n >= N) return;
  float s = xb[(size_t)n * 128 + lane] * ldf(wsw, woff + lane, pb) +
            xb[(size_t)n * 128 + 64 + lane] * ldf(wsw, woff + 64 + lane, pb);
#pragma unroll
  for (int o = 1; o < 64; o <<= 1) s += __shfl_xor(s, o);
  if (lane == 0) {
    float t = s + ldf(wsb, boff, pb);
    t = fmaxf(fminf(t, 60.f), -60.f);
    w[(size_t)b * N + n] = 1.f / (1.f + expf(-t));
  }
}

__device__ __forceinline__ int lower_bound_dev(const int* a, int n, int v) {
  int lo = 0, hi = n;
  while (lo < hi) {
    int mid = (lo + hi) >> 1;
    if (a[mid] < v) lo = mid + 1; else hi = mid;
  }
  return lo;
}

// ---------------- readout phase 1 (both branches) ----------------
__global__ __launch_bounds__(128) void readout_p1_kernel(const float* __restrict__ x,
                                                         const float* __restrict__ w,
                                                         const int* __restrict__ gidA,
                                                         const int* __restrict__ gidB, int N,
                                                         double* __restrict__ psum,
                                                         float* __restrict__ pmax) {
  int b = blockIdx.y;
  const int* gid = b ? gidB : gidA;
  const float* xb = x + (size_t)b * N * 128;
  const float* wb = w + (size_t)b * N;
  int g = blockIdx.x >> 4;
  int c = blockIdx.x & 15;
  int d = threadIdx.x;
  __shared__ int ss, se;
  if (d == 0) {
    ss = lower_bound_dev(gid, N, g);
    se = lower_bound_dev(gid, N, g + 1);
  }
  __syncthreads();
  int len = se - ss;
  int a = ss + (int)(((long)len * c) >> 4);
  int bb = ss + (int)(((long)len * (c + 1)) >> 4);
  double s = 0.0;
  float m = -1e30f;
  for (int n = a; n < bb; n++) {
    float v = xb[(size_t)n * 128 + d];
    s += (double)v * (double)wb[n];
    m = fmaxf(m, v);
  }
  psum[((size_t)b * Bg * 16 + blockIdx.x) * 128 + d] = s;
  pmax[((size_t)b * Bg * 16 + blockIdx.x) * 128 + d] = m;
}

// ---------------- readout phase 2 (both branches) ----------------
__global__ __launch_bounds__(128) void readout_p2_kernel(const double* __restrict__ psum,
                                                         const float* __restrict__ pmax,
                                                         float* __restrict__ hs,
                                                         float* __restrict__ hm) {
  int b = blockIdx.y;
  int g = blockIdx.x, d = threadIdx.x;
  double s = 0.0;
  float m = -1e30f;
#pragma unroll
  for (int c = 0; c < 16; c++) {
    s += psum[((size_t)b * Bg * 16 + g * 16 + c) * 128 + d];
    m = fmaxf(m, pmax[((size_t)b * Bg * 16 + g * 16 + c) * 128 + d]);
  }
  hs[(size_t)b * Bg * 128 + g * 128 + d] = (float)s;
  hm[(size_t)b * Bg * 128 + g * 128 + d] = m;
}

// ---------------- pool linear (both branches) ----------------
__global__ __launch_bounds__(128) void pool_kernel(const float* __restrict__ hs,
                                                   const float* __restrict__ hm,
                                                   const void* __restrict__ Wp,
                                                   const void* __restrict__ bp,
                                                   const int* __restrict__ pflag,
                                                   float* __restrict__ bout) {
  const bool pb = (*pflag != 0);
  int b = blockIdx.y;
  size_t woff = (size_t)b * 256 * 128, boff = (size_t)b * 128;
  int g = blockIdx.x, j = threadIdx.x;
  __shared__ float hg[256];
  hg[j] = hs[(size_t)b * Bg * 128 + g * 128 + j];
  hg[128 + j] = hm[(size_t)b * Bg * 128 + g * 128 + j];
  __syncthreads();
  double acc = (double)ldf(bp, boff + j, pb);
  for (int k = 0; k < 256; k++) acc += (double)hg[k] * (double)ldf(Wp, woff + (size_t)k * 128 + j, pb);
  bout[(size_t)b * Bg * 128 + g * 128 + j] = (float)acc;
}

// ---------------- final head ----------------
__global__ __launch_bounds__(128) void head_kernel(const float* __restrict__ bA,
                                                   const float* __restrict__ bB,
                                                   const void* __restrict__ Wo1,
                                                   const void* __restrict__ bo1,
                                                   const void* __restrict__ Wo2,
                                                   const void* __restrict__ bo2,
                                                   const int* __restrict__ pflag,
                                                   const int* __restrict__ oflag,
                                                   void* __restrict__ out) {
  const bool pb = (*pflag != 0);
  int g = blockIdx.x, j = threadIdx.x;
  __shared__ float zr[256];
  __shared__ double t[128];
  zr[j] = bA[g * 128 + j];
  zr[128 + j] = bB[g * 128 + j];
  __syncthreads();
  double acc = (double)ldf(bo1, j, pb);
  for (int k = 0; k < 256; k++) acc += (double)zr[k] * (double)ldf(Wo1, (size_t)k * 128 + j, pb);
  if (acc < 0.0) acc *= 0.01;
  t[j] = acc * (double)ldf(Wo2, j, pb);
  __syncthreads();
  for (int sdt = 64; sdt > 0; sdt >>= 1) {
    if (j < sdt) t[j] += t[j + sdt];
    __syncthreads();
  }
  if (j == 0) {
    float v = (float)(t[0] + (double)ldf(bo2, 0, pb));
    if (*oflag) ((bf16*)out)[g] = __float2bfloat16(v);
    else ((float*)out)[g] = v;
  }
}

extern "C" void kernel_launch(void* const* d_in, const int* in_sizes, int n_in,
                              void* d_out, int out_size, void* d_ws, size_t ws_size,
                              hipStream_t stream) {
  const int* srcA = (const int*)d_in[0];
  const int* dstA = (const int*)d_in[1];
  const int* gidA = (const int*)d_in[2];
  const void* nfA = d_in[3];
  const void* efA = d_in[4];
  const int* srcB = (const int*)d_in[5];
  const int* dstB = (const int*)d_in[6];
  const int* gidB = (const int*)d_in[7];
  const void* nfB = d_in[8];
  const void* efB = d_in[9];
  const void* p_Wn = d_in[10];
  const void* p_bn = d_in[11];
  const void* p_We = d_in[12];
  const void* p_be = d_in[13];
  const void* p_Wc = d_in[14];
  const void* p_bc = d_in[15];
  const void* p_fc1 = d_in[16];
  const void* p_al1 = d_in[17];
  const void* p_ar1 = d_in[18];
  const void* p_gb1 = d_in[19];
  const void* p_Wl1 = d_in[20];
  const void* p_bl1 = d_in[21];
  const void* p_fc2 = d_in[22];
  const void* p_al2 = d_in[23];
  const void* p_ar2 = d_in[24];
  const void* p_gb2 = d_in[25];
  const void* p_Wl2 = d_in[26];
  const void* p_bl2 = d_in[27];
  const void* p_ws_w = d_in[28];
  const void* p_ws_b = d_in[29];
  const void* p_Wp = d_in[30];
  const void* p_bp = d_in[31];
  const void* Wo1 = d_in[32];
  const void* bo1 = d_in[33];
  const void* Wo2 = d_in[34];
  const void* bo2 = d_in[35];

  // workspace carve-up (~146 MB)
  char* wp = (char*)d_ws;
  auto alloc = [&](size_t bytes) -> char* {
    char* p = wp;
    wp += (bytes + 255) & ~(size_t)255;
    return p;
  };
  int* flags = (int*)alloc(2 * 4);
  int* cnt = (int*)alloc((size_t)2 * Nn * 4);
  int* incl = (int*)alloc((size_t)2 * Nn * 4);
  int* bsum = (int*)alloc(2 * 256 * 4);
  int* offs = (int*)alloc((size_t)2 * (Nn + 1) * 4);
  int* cursor = (int*)alloc((size_t)2 * Nn * 4);
  int* perm = (int*)alloc((size_t)2 * Ne * 4);
  int* src_csr = (int*)alloc((size_t)2 * Ne * 4);
  int* ipos = (int*)alloc((size_t)2 * Ne * 4);
  float* ecsr = (float*)alloc((size_t)2 * Ne * 4 * 4);
  float* sden = (float*)alloc((size_t)2 * Nn * 4 * 4);
  float* el = (float*)alloc((size_t)2 * Nn * 4 * 4);
  float* er = (float*)alloc((size_t)2 * Nn * 4 * 4);
  float* wn = (float*)alloc((size_t)2 * Nn * 4);
  double* psum = (double*)alloc((size_t)2 * Bg * 16 * 128 * 8);
  float* pmax = (float*)alloc((size_t)2 * Bg * 16 * 128 * 4);
  float* hsb = (float*)alloc((size_t)2 * Bg * 128 * 4);
  float* hmb = (float*)alloc((size_t)2 * Bg * 128 * 4);
  float* bout = (float*)alloc((size_t)2 * Bg * 128 * 4);
  // transposed fp16 weight planes
  __half* Wct = (__half*)alloc((size_t)2 * 80 * 80 * 2);
  __half* fc1t = (__half*)alloc((size_t)2 * 512 * 80 * 2);
  __half* Wl1t = (__half*)alloc((size_t)2 * 128 * 512 * 2);
  __half* fc2t = (__half*)alloc((size_t)2 * 512 * 128 * 2);
  __half* Wl2t = (__half*)alloc((size_t)2 * 128 * 512 * 2);
  // big overlaid regions
  char* R = alloc((size_t)2 * Nn * 512 * 2);   // 51.2 MB: he_csr+hn early -> z -> x2
  char* H = alloc((size_t)2 * Nn * 512 * 2);   // 51.2 MB: xsum early -> hb
  __half* xcx1 = (__half*)alloc((size_t)2 * Nn * 128 * 2);  // xc (stride Nn*80) / x1 (stride Nn*128)
  // overlays
  __half* he_csr = (__half*)R;                            // 2*Ne*16 fp16 = 25.6 MB
  __half* hn = (__half*)(R + (size_t)2 * Ne * 16 * 2);    // 2*Nn*64 fp16 = 6.4 MB
  __half* z = (__half*)R;                                 // 2*Nn*512 fp16
  float* x2 = (float*)R;                                  // 2*Nn*128 f32
  __half* xsum = (__half*)H;                              // 2*Nn*80 fp16
  __half* hb = (__half*)H;                                // 2*Nn*512 fp16
  __half* xc = xcx1;                                      // stride Nn*80
  __half* x1 = xcx1;                                      // stride Nn*128

  auto cdiv = [](int a, int b) { return (a + b - 1) / b; };

  detect_kernel<<<1, 256, 0, stream>>>((const u16*)nfA, 8192, (const u16*)p_fc1, 8192, flags);
  int* fflag = &flags[0];
  int* pflag = &flags[1];

  // prep: fused transpose+convert of all fp16 weight planes (both branches)
  {
    TCAll tc;
    int segK[5] = {80, 80, 512, 128, 512};
    int segN[5] = {80, 512, 128, 512, 128};
    const void* segW[5] = {p_Wc, p_fc1, p_Wl1, p_fc2, p_Wl2};
    __half* segH[5] = {Wct, fc1t, Wl1t, fc2t, Wl2t};
    int start = 0, s = 0;
    for (int i = 0; i < 2; i++)
      for (int m = 0; m < 5; m++) {
        int sz = segK[m] * segN[m];
        tc.t[s].W = segW[m];
        tc.t[s].off = (size_t)i * sz;
        tc.t[s].H = segH[m] + (size_t)i * sz;
        tc.t[s].K = segK[m];
        tc.t[s].N = segN[m];
        tc.t[s].start = start;
        start += sz;
        s++;
      }
    tc.total = start;
    transconv_all_kernel<<<cdiv(start, 256), 256, 0, stream>>>(tc, pflag);
  }

  const int nb = cdiv(Nn, 256);

  // ---- merged front-end (both branches in every dispatch) ----
  hipMemsetAsync(cnt, 0, (size_t)2 * Nn * 4, stream);
  count_kernel<<<dim3(cdiv(Ne, 256), 2), 256, 0, stream>>>(dstA, dstB, cnt, Ne, Nn);
  scan1_kernel<<<dim3(nb, 2), 256, 0, stream>>>(cnt, incl, bsum, Nn);
  scan2_kernel<<<2, 256, 0, stream>>>(bsum, nb);
  scan3_kernel<<<dim3(nb, 2), 256, 0, stream>>>(cnt, incl, bsum, offs, cursor, Nn);
  fill_kernel<<<dim3(cdiv(Ne, 256), 2), 256, 0, stream>>>(dstA, dstB, cursor, perm, Ne, Nn);
  sortseg_kernel<<<dim3(cdiv(Nn, 64), 2), 64, 0, stream>>>(offs, perm, Nn, Ne);
  srccsr_kernel<<<dim3(cdiv(Ne, 256), 2), 256, 0, stream>>>(srcA, srcB, perm, src_csr, ipos, Ne);
  proj_nf_kernel<<<dim3(cdiv(Nn, 4), 2), 256, 0, stream>>>(
      nfA, nfB, fflag, p_Wn, p_bn, pflag, hn, Nn);
  proj_ef_kernel<<<dim3(cdiv(Ne, 16), 2), 256, 0, stream>>>(
      efA, efB, fflag, p_We, p_be, pflag, ipos, he_csr, Ne);
  edgeconv_kernel<<<dim3(cdiv(Nn, 4), 2), 256, 0, stream>>>(
      offs, src_csr, hn, he_csr, xsum, Nn, Ne);

  const int gm = cdiv(Nn, 128);  // 196 M-tiles

  // ---- main pipeline, both branches per dispatch ----
  // EdgeGraphConv linear: xsum -> xc
  mfma_f16_gemm<1, 2><<<dim3(gm, 1, 2), 256, 0, stream>>>(
      xsum, (size_t)Nn * 80, Wct, 6400, p_bc, 80, pflag, xc, (size_t)Nn * 80, Nn, 80, 80);
  // GAT 1
  mfma_f16_gemm<0, 2><<<dim3(gm, 4, 2), 256, 0, stream>>>(
      xc, (size_t)Nn * 80, fc1t, (size_t)512 * 80, nullptr, 0, pflag, z, (size_t)Nn * 512,
      Nn, 80, 512);
  attn_lr_kernel<<<dim3(cdiv(Nn * 64, 256), 2), 256, 0, stream>>>(
      z, p_al1, p_ar1, 512, pflag, el, er, Nn);
  attn_sden_kernel<<<dim3(cdiv(Nn * 4, 256), 2), 256, 0, stream>>>(
      offs, src_csr, el, er, ecsr, sden, Nn, Ne);
  gat_gather_kernel<<<dim3(cdiv(Nn * 64, 256), 2), 256, 0, stream>>>(
      offs, src_csr, z, ecsr, sden, p_gb1, 512, pflag, hb, Nn, Ne);
  mfma_f16_gemm<0, 2><<<dim3(gm, 1, 2), 256, 0, stream>>>(
      hb, (size_t)Nn * 512, Wl1t, (size_t)128 * 512, p_bl1, 128, pflag, x1, (size_t)Nn * 128,
      Nn, 512, 128);
  // GAT 2
  mfma_f16_gemm<0, 2><<<dim3(gm, 4, 2), 256, 0, stream>>>(
      x1, (size_t)Nn * 128, fc2t, (size_t)512 * 128, nullptr, 0, pflag, z, (size_t)Nn * 512,
      Nn, 128, 512);
  attn_lr_kernel<<<dim3(cdiv(Nn * 64, 256), 2), 256, 0, stream>>>(
      z, p_al2, p_ar2, 512, pflag, el, er, Nn);
  attn_sden_kernel<<<dim3(cdiv(Nn * 4, 256), 2), 256, 0, stream>>>(
      offs, src_csr, el, er, ecsr, sden, Nn, Ne);
  gat_gather_kernel<<<dim3(cdiv(Nn * 64, 256), 2), 256, 0, stream>>>(
      offs, src_csr, z, ecsr, sden, p_gb2, 512, pflag, hb, Nn, Ne);
  mfma_f16_gemm<0, 0><<<dim3(gm, 1, 2), 256, 0, stream>>>(
      hb, (size_t)Nn * 512, Wl2t, (size_t)128 * 512, p_bl2, 128, pflag, x2, (size_t)Nn * 128,
      Nn, 512, 128);
  // readout
  wnode_kernel<<<dim3(cdiv(Nn * 64, 256), 2), 256, 0, stream>>>(
      x2, p_ws_w, p_ws_b, pflag, wn, Nn);
  readout_p1_kernel<<<dim3(Bg * 16, 2), 128, 0, stream>>>(x2, wn, gidA, gidB, Nn, psum, pmax);
  readout_p2_kernel<<<dim3(Bg, 2), 128, 0, stream>>>(psum, pmax, hsb, hmb);
  pool_kernel<<<dim3(Bg, 2), 128, 0, stream>>>(hsb, hmb, p_Wp, p_bp, pflag, bout);

  head_kernel<<<Bg, 128, 0, stream>>>(bout, bout + (size_t)Bg * 128, Wo1, bo1, Wo2, bo2,
                                      pflag, fflag, d_out);
}